// Round 23
// baseline (262.593 us; speedup 1.0000x reference)
//
#include <hip/hip_runtime.h>
#include <hip/hip_bf16.h>

#define KD 128
#define NANF __int_as_float(0x7fc00000)

typedef __attribute__((ext_vector_type(8))) short bf16x8;
typedef __attribute__((ext_vector_type(4))) float f32x4;

__device__ __forceinline__ unsigned short f2b(float x) {  // fp32 -> bf16 RNE
  unsigned u = __float_as_uint(x);
  return (unsigned short)((u + 0x7fffu + ((u >> 16) & 1u)) >> 16);
}
__device__ __forceinline__ int swz(int row, int kbyte) {  // LDS byte addr, G4 XOR swizzle
  return (row * 256 + kbyte) ^ ((row & 7) << 4);
}

// ---------------- one-shot: transpose+convert six 128x128 W to bf16 Wt[n][k] ----------------
// order: 0=W1_u 1=W1_b 2=W_u2 3=W_us2w 4=W_b2 5=W_bs2w
__global__ __launch_bounds__(256) void wsplit6(
    const float* __restrict__ w0, const float* __restrict__ w1,
    const float* __restrict__ w2, const float* __restrict__ w3,
    const float* __restrict__ w4, const float* __restrict__ w5,
    unsigned short* __restrict__ oh)
{
  int m = blockIdx.x >> 6;
  int idx = (blockIdx.x & 63) * 256 + threadIdx.x;   // n*128 + k
  const float* ws;
  switch (m) { case 0: ws = w0; break; case 1: ws = w1; break; case 2: ws = w2; break;
               case 3: ws = w3; break; case 4: ws = w4; break; default: ws = w5; }
  int n = idx >> 7, k = idx & 127;
  oh[(long)m * 16384 + idx] = f2b(ws[k * 128 + n]);
}

// ---------------- one-shot: transpose+convert two 128x64 W3 to bf16 Wt[n][k] (n<64) ----------
__global__ __launch_bounds__(256) void w3split(
    const float* __restrict__ w0, const float* __restrict__ w1,
    unsigned short* __restrict__ oh)
{
  int m = blockIdx.x >> 5;
  int idx = (blockIdx.x & 31) * 256 + threadIdx.x;   // n*128 + k, n<64
  const float* ws = m ? w1 : w0;
  int n = idx >> 7, k = idx & 127;
  oh[(long)m * 8192 + idx] = f2b(ws[k * 64 + n]);
}

// ---------------- gemm1: dual-grid bf16 MFMA, both operands LDS (swizzled) ----------------
__global__ __launch_bounds__(256, 3) void mfma1_dual(
    int split,
    const float* __restrict__ Aa, const unsigned short* __restrict__ Wta, int Ma,
    unsigned short* __restrict__ Ca,
    const float* __restrict__ a_sa, const float* __restrict__ a_na,
    float* __restrict__ as_oa, float* __restrict__ an_oa, const unsigned char* __restrict__ fla,
    const float* __restrict__ Ab, const unsigned short* __restrict__ Wtb, int Mb,
    unsigned short* __restrict__ Cb,
    const float* __restrict__ a_sb, const float* __restrict__ a_nb,
    float* __restrict__ as_ob, float* __restrict__ an_ob, const unsigned char* __restrict__ flb)
{
  const bool sB = (int)blockIdx.x >= split;
  const float* A = sB ? Ab : Aa;
  const unsigned short* Wt = sB ? Wtb : Wta;
  const int M = sB ? Mb : Ma;
  unsigned short* C = sB ? Cb : Ca;
  const float* a_s = sB ? a_sb : a_sa;  const float* a_n = sB ? a_nb : a_na;
  float* as_o = sB ? as_ob : as_oa;     float* an_o = sB ? an_ob : an_oa;
  const unsigned char* fl = sB ? flb : fla;
  const int bid = sB ? ((int)blockIdx.x - split) : (int)blockIdx.x;

  __shared__ unsigned short sW[16384];   // 32KB
  __shared__ unsigned short sA[8192];    // 16KB
  __shared__ float pp[4][64][2];         // 2KB

  const int t = threadIdx.x;
  const int w = t >> 6, l = t & 63;
  const int lr = l & 15, lk = l >> 4;
  const int row0 = bid * 64;
  char* sWc = reinterpret_cast<char*>(sW);
  char* sAc = reinterpret_cast<char*>(sA);

  #pragma unroll
  for (int q = 0; q < 8; ++q) {
    int p = t + 256 * q;
    int n = p >> 4, c16 = p & 15;
    bf16x8 v = *reinterpret_cast<const bf16x8*>(Wt + n * 128 + c16 * 8);
    *reinterpret_cast<bf16x8*>(sWc + swz(n, c16 * 16)) = v;
  }
  #pragma unroll
  for (int q = 0; q < 4; ++q) {
    int p = t + 256 * q;
    int r = p >> 4, c16 = p & 15;
    int gr = row0 + r;
    bf16x8 hv;
    if (gr < M) {
      const float4* ap = reinterpret_cast<const float4*>(A + (long)gr * KD + c16 * 8);
      float4 v0 = ap[0], v1 = ap[1];
      hv[0]=(short)f2b(v0.x); hv[1]=(short)f2b(v0.y); hv[2]=(short)f2b(v0.z); hv[3]=(short)f2b(v0.w);
      hv[4]=(short)f2b(v1.x); hv[5]=(short)f2b(v1.y); hv[6]=(short)f2b(v1.z); hv[7]=(short)f2b(v1.w);
    } else {
      #pragma unroll
      for (int j = 0; j < 8; ++j) hv[j] = 0;
    }
    *reinterpret_cast<bf16x8*>(sAc + swz(r, c16 * 16)) = hv;
  }
  __syncthreads();

  f32x4 acc[4][2];
  #pragma unroll
  for (int i = 0; i < 4; ++i)
    #pragma unroll
    for (int tt = 0; tt < 2; ++tt) acc[i][tt] = (f32x4){0.f, 0.f, 0.f, 0.f};

  #pragma unroll
  for (int kc = 0; kc < 4; ++kc) {
    const int kb = (kc * 32 + lk * 8) * 2;
    bf16x8 af[4];
    #pragma unroll
    for (int i = 0; i < 4; ++i)
      af[i] = *reinterpret_cast<const bf16x8*>(sAc + swz(i * 16 + lr, kb));
    #pragma unroll
    for (int tt = 0; tt < 2; ++tt) {
      int n = (w * 2 + tt) * 16 + lr;
      bf16x8 bfr = *reinterpret_cast<const bf16x8*>(sWc + swz(n, kb));
      #pragma unroll
      for (int i = 0; i < 4; ++i)
        acc[i][tt] = __builtin_amdgcn_mfma_f32_16x16x32_bf16(af[i], bfr, acc[i][tt], 0, 0, 0);
    }
  }

  float asv[2], anv[2];
  #pragma unroll
  for (int tt = 0; tt < 2; ++tt) {
    int col = (w * 2 + tt) * 16 + lr;
    asv[tt] = a_s[col]; anv[tt] = a_n[col];
  }
  #pragma unroll
  for (int i = 0; i < 4; ++i) {
    #pragma unroll
    for (int r = 0; r < 4; ++r) {
      float ds = acc[i][0][r] * asv[0] + acc[i][1][r] * asv[1];
      float dn = acc[i][0][r] * anv[0] + acc[i][1][r] * anv[1];
      #pragma unroll
      for (int o = 1; o < 16; o <<= 1) { ds += __shfl_xor(ds, o, 64); dn += __shfl_xor(dn, o, 64); }
      if (lr == 0) {
        int row = i * 16 + lk * 4 + r;
        pp[w][row][0] = ds; pp[w][row][1] = dn;
      }
    }
  }
  #pragma unroll
  for (int i = 0; i < 4; ++i) {
    #pragma unroll
    for (int r = 0; r < 4; ++r) {
      int gr = row0 + i * 16 + lk * 4 + r;
      if (gr >= M) continue;
      #pragma unroll
      for (int tt = 0; tt < 2; ++tt) {
        int col = (w * 2 + tt) * 16 + lr;
        C[(long)gr * 128 + col] = f2b(acc[i][tt][r]);
      }
    }
  }
  __syncthreads();
  if (t < 64) {
    int gr = row0 + t;
    if (gr < M) {
      float ds = pp[0][t][0] + pp[1][t][0] + pp[2][t][0] + pp[3][t][0];
      float dn = pp[0][t][1] + pp[1][t][1] + pp[2][t][1] + pp[3][t][1];
      as_o[gr] = fl[gr] ? ds : NANF;
      an_o[gr] = dn;
    }
  }
}

// ---------------- gemm2: dual-grid bf16 MFMA, 2 accumulate passes, gathered A ----------------
__global__ __launch_bounds__(256, 3) void mfma2_dual(
    int split,
    const float* __restrict__ A1a, const unsigned short* __restrict__ W1ta,
    const float* __restrict__ A2a, const unsigned short* __restrict__ W2ta,
    const float* __restrict__ biasa, const int* __restrict__ aidxa,
    const int* __restrict__ map1a, int Ma, float* __restrict__ Ca,
    const float* __restrict__ A1b, const unsigned short* __restrict__ W1tb,
    const float* __restrict__ A2b, const unsigned short* __restrict__ W2tb,
    const float* __restrict__ biasb, const int* __restrict__ aidxb,
    const int* __restrict__ map1b, int Mb, float* __restrict__ Cb)
{
  const bool sB = (int)blockIdx.x >= split;
  const float* A1 = sB ? A1b : A1a;  const unsigned short* W1t = sB ? W1tb : W1ta;
  const float* A2 = sB ? A2b : A2a;  const unsigned short* W2t = sB ? W2tb : W2ta;
  const float* bias = sB ? biasb : biasa;
  const int* aidx = sB ? aidxb : aidxa;  const int* map1 = sB ? map1b : map1a;
  const int M = sB ? Mb : Ma;  float* C = sB ? Cb : Ca;
  const int bid = sB ? ((int)blockIdx.x - split) : (int)blockIdx.x;

  __shared__ unsigned short sW[16384];   // 32KB
  __shared__ unsigned short sA[8192];    // 16KB

  const int t = threadIdx.x;
  const int w = t >> 6, l = t & 63;
  const int lr = l & 15, lk = l >> 4;
  const int row0 = bid * 64;
  char* sWc = reinterpret_cast<char*>(sW);
  char* sAc = reinterpret_cast<char*>(sA);

  f32x4 acc[4][2];
  #pragma unroll
  for (int i = 0; i < 4; ++i)
    #pragma unroll
    for (int tt = 0; tt < 2; ++tt) acc[i][tt] = (f32x4){0.f, 0.f, 0.f, 0.f};

  #pragma unroll
  for (int pass = 0; pass < 2; ++pass) {
    const float* Am = pass ? A2 : A1;
    const unsigned short* Wt = pass ? W2t : W1t;
    if (pass) __syncthreads();
    #pragma unroll
    for (int q = 0; q < 8; ++q) {
      int p = t + 256 * q;
      int n = p >> 4, c16 = p & 15;
      bf16x8 v = *reinterpret_cast<const bf16x8*>(Wt + n * 128 + c16 * 8);
      *reinterpret_cast<bf16x8*>(sWc + swz(n, c16 * 16)) = v;
    }
    #pragma unroll
    for (int q = 0; q < 4; ++q) {
      int p = t + 256 * q;
      int r = p >> 4, c16 = p & 15;
      int gr = row0 + r;
      bf16x8 hv;
      if (gr < M) {
        long grow = (long)aidx[gr];
        if (pass == 0) grow = map1[grow];
        const float4* ap = reinterpret_cast<const float4*>(Am + grow * KD + c16 * 8);
        float4 v0 = ap[0], v1 = ap[1];
        hv[0]=(short)f2b(v0.x); hv[1]=(short)f2b(v0.y); hv[2]=(short)f2b(v0.z); hv[3]=(short)f2b(v0.w);
        hv[4]=(short)f2b(v1.x); hv[5]=(short)f2b(v1.y); hv[6]=(short)f2b(v1.z); hv[7]=(short)f2b(v1.w);
      } else {
        #pragma unroll
        for (int j = 0; j < 8; ++j) hv[j] = 0;
      }
      *reinterpret_cast<bf16x8*>(sAc + swz(r, c16 * 16)) = hv;
    }
    __syncthreads();
    #pragma unroll
    for (int kc = 0; kc < 4; ++kc) {
      const int kb = (kc * 32 + lk * 8) * 2;
      bf16x8 af[4];
      #pragma unroll
      for (int i = 0; i < 4; ++i)
        af[i] = *reinterpret_cast<const bf16x8*>(sAc + swz(i * 16 + lr, kb));
      #pragma unroll
      for (int tt = 0; tt < 2; ++tt) {
        int n = (w * 2 + tt) * 16 + lr;
        bf16x8 bfr = *reinterpret_cast<const bf16x8*>(sWc + swz(n, kb));
        #pragma unroll
        for (int i = 0; i < 4; ++i)
          acc[i][tt] = __builtin_amdgcn_mfma_f32_16x16x32_bf16(af[i], bfr, acc[i][tt], 0, 0, 0);
      }
    }
  }
  float bv[2];
  #pragma unroll
  for (int tt = 0; tt < 2; ++tt) bv[tt] = bias[(w * 2 + tt) * 16 + lr];
  #pragma unroll
  for (int i = 0; i < 4; ++i) {
    #pragma unroll
    for (int r = 0; r < 4; ++r) {
      int gr = row0 + i * 16 + lk * 4 + r;
      if (gr >= M) continue;
      #pragma unroll
      for (int tt = 0; tt < 2; ++tt) {
        int col = (w * 2 + tt) * 16 + lr;
        float v = acc[i][tt][r] + bv[tt];
        v = (v > 0.f) ? v : (__expf(v) - 1.f);
        C[(long)gr * 128 + col] = v;
      }
    }
  }
}

// ---------------- gemm3: dual-grid bf16 MFMA, NC=64, fused elu + gathered residual ----------
__global__ __launch_bounds__(256, 3) void mfma3_dual(
    int split,
    const float* __restrict__ Aa, const unsigned short* __restrict__ W3ta,
    const float* __restrict__ Resa, const int* __restrict__ ridxa, int Ma,
    float* __restrict__ Ca,
    const float* __restrict__ Ab, const unsigned short* __restrict__ W3tb,
    const float* __restrict__ Resb, const int* __restrict__ ridxb, int Mb,
    float* __restrict__ Cb)
{
  const bool sB = (int)blockIdx.x >= split;
  const float* A = sB ? Ab : Aa;
  const unsigned short* W3t = sB ? W3tb : W3ta;
  const float* Res = sB ? Resb : Resa;
  const int* ridx = sB ? ridxb : ridxa;
  const int M = sB ? Mb : Ma;
  float* C = sB ? Cb : Ca;
  const int bid = sB ? ((int)blockIdx.x - split) : (int)blockIdx.x;

  __shared__ unsigned short sW[8192];    // 16KB: 64 n-rows x 128 k
  __shared__ unsigned short sA[8192];    // 16KB
  const int t = threadIdx.x;
  const int w = t >> 6, l = t & 63;
  const int lr = l & 15, lk = l >> 4;
  const int row0 = bid * 64;
  char* sWc = reinterpret_cast<char*>(sW);
  char* sAc = reinterpret_cast<char*>(sA);

  #pragma unroll
  for (int q = 0; q < 4; ++q) {
    int p = t + 256 * q;
    int n = p >> 4, c16 = p & 15;
    bf16x8 v = *reinterpret_cast<const bf16x8*>(W3t + n * 128 + c16 * 8);
    *reinterpret_cast<bf16x8*>(sWc + swz(n, c16 * 16)) = v;
  }
  #pragma unroll
  for (int q = 0; q < 4; ++q) {
    int p = t + 256 * q;
    int r = p >> 4, c16 = p & 15;
    int gr = row0 + r;
    bf16x8 hv;
    if (gr < M) {
      const float4* ap = reinterpret_cast<const float4*>(A + (long)gr * KD + c16 * 8);
      float4 v0 = ap[0], v1 = ap[1];
      hv[0]=(short)f2b(v0.x); hv[1]=(short)f2b(v0.y); hv[2]=(short)f2b(v0.z); hv[3]=(short)f2b(v0.w);
      hv[4]=(short)f2b(v1.x); hv[5]=(short)f2b(v1.y); hv[6]=(short)f2b(v1.z); hv[7]=(short)f2b(v1.w);
    } else {
      #pragma unroll
      for (int j = 0; j < 8; ++j) hv[j] = 0;
    }
    *reinterpret_cast<bf16x8*>(sAc + swz(r, c16 * 16)) = hv;
  }
  __syncthreads();

  f32x4 acc[4];
  #pragma unroll
  for (int i = 0; i < 4; ++i) acc[i] = (f32x4){0.f, 0.f, 0.f, 0.f};

  #pragma unroll
  for (int kc = 0; kc < 4; ++kc) {
    const int kb = (kc * 32 + lk * 8) * 2;
    bf16x8 af[4];
    #pragma unroll
    for (int i = 0; i < 4; ++i)
      af[i] = *reinterpret_cast<const bf16x8*>(sAc + swz(i * 16 + lr, kb));
    int n = w * 16 + lr;
    bf16x8 bfr = *reinterpret_cast<const bf16x8*>(sWc + swz(n, kb));
    #pragma unroll
    for (int i = 0; i < 4; ++i)
      acc[i] = __builtin_amdgcn_mfma_f32_16x16x32_bf16(af[i], bfr, acc[i], 0, 0, 0);
  }
  // epilogue: elu + gathered residual, fp32 store (col = w*16+lr)
  const int col = w * 16 + lr;
  #pragma unroll
  for (int i = 0; i < 4; ++i) {
    #pragma unroll
    for (int r = 0; r < 4; ++r) {
      int gr = row0 + i * 16 + lk * 4 + r;
      if (gr >= M) continue;
      float v = acc[i][r];
      v = (v > 0.f) ? v : (__expf(v) - 1.f);
      v += Res[(long)ridx[gr] * 64 + col];
      C[(long)gr * 64 + col] = v;
    }
  }
}

// ---------------- needed-dst flags: byte array + 1-bit mask (L1-resident gate) ----------
__global__ void flags_kernel(const int* __restrict__ ui, const int* __restrict__ ii, int B,
                             unsigned char* __restrict__ nfu, unsigned char* __restrict__ nfb,
                             unsigned* __restrict__ mku, unsigned* __restrict__ mkb)
{
  int i = blockIdx.x * blockDim.x + threadIdx.x;
  if (i < B) {
    int u = ui[i], v = ii[i];
    nfu[u] = 1; nfb[v] = 1;
    atomicOr(&mku[u >> 5], 1u << (u & 31));
    atomicOr(&mkb[v >> 5], 1u << (v & 31));
  }
}

// ---------------- dual pass 1: 16 edges/thread; bitmask gate, gated L2 gathers ----------
__global__ __launch_bounds__(256) void edge_prep_dual(
    int split,
    const int* __restrict__ srcA, const int* __restrict__ dstA,
    const float* __restrict__ asA, const float* __restrict__ anA,
    const unsigned* __restrict__ mkA,
    int* __restrict__ degA, int4* __restrict__ cmpA, int* __restrict__ bcA, int EA,
    const int* __restrict__ srcB, const int* __restrict__ dstB,
    const float* __restrict__ asB, const float* __restrict__ anB,
    const unsigned* __restrict__ mkB,
    const float* __restrict__ gc, const float* __restrict__ omega,
    int* __restrict__ degB, int4* __restrict__ cmpB, int* __restrict__ bcB, int EB_)
{
  const bool sB = (int)blockIdx.x >= split;
  const int* src = sB ? srcB : srcA;  const int* dst = sB ? dstB : dstA;
  const float* as_ = sB ? asB : asA;  const float* an_ = sB ? anB : anA;
  const unsigned* mk = sB ? mkB : mkA;
  int* deg = sB ? degB : degA;  int4* cmp = sB ? cmpB : cmpA;
  int* blkcnt = sB ? bcB : bcA;
  const int E = sB ? EB_ : EA;
  const float* gcp = sB ? gc : nullptr;
  const int bid = sB ? ((int)blockIdx.x - split) : (int)blockIdx.x;

  __shared__ int lcnt;
  if (threadIdx.x == 0) lcnt = 0;
  __syncthreads();
  const int lane = threadIdx.x & 63;
  const long base = (long)bid * 4096;
  const int e0 = (int)base + threadIdx.x * 16;

  int d[16], s[16];
  bool act[16];
  const bool full = (e0 + 15 < E);
  if (full) {
    #pragma unroll
    for (int q = 0; q < 4; ++q) {
      int4 d4 = *reinterpret_cast<const int4*>(dst + e0 + q * 4);
      int4 s4 = *reinterpret_cast<const int4*>(src + e0 + q * 4);
      d[q*4+0]=d4.x; d[q*4+1]=d4.y; d[q*4+2]=d4.z; d[q*4+3]=d4.w;
      s[q*4+0]=s4.x; s[q*4+1]=s4.y; s[q*4+2]=s4.z; s[q*4+3]=s4.w;
    }
    #pragma unroll
    for (int j = 0; j < 16; ++j) act[j] = true;
  } else {
    #pragma unroll
    for (int j = 0; j < 16; ++j) {
      act[j] = (e0 + j < E);
      d[j] = act[j] ? dst[e0 + j] : 0;
      s[j] = act[j] ? src[e0 + j] : 0;
    }
  }
  // 1-bit mask gate: random reads into a <13KB L1-resident table
  unsigned mw[16];
  #pragma unroll
  for (int j = 0; j < 16; ++j) mw[j] = mk[d[j] >> 5];
  #pragma unroll
  for (int j = 0; j < 16; ++j) act[j] = act[j] && ((mw[j] >> (d[j] & 31)) & 1u);

  float uw[16];
  if (gcp) {
    float o0 = omega[0], o1 = omega[1], o2 = omega[2];
    if (full) {
      float g[48];
      const float4* gp = reinterpret_cast<const float4*>(gcp + (long)e0 * 3);
      #pragma unroll
      for (int q = 0; q < 12; ++q) *reinterpret_cast<float4*>(&g[q*4]) = gp[q];
      #pragma unroll
      for (int j = 0; j < 16; ++j) uw[j] = g[j*3+0]*o0 + g[j*3+1]*o1 + g[j*3+2]*o2;
    } else {
      #pragma unroll
      for (int j = 0; j < 16; ++j) {
        uw[j] = 0.f;
        if (act[j]) {
          long e = e0 + j;
          uw[j] = gcp[e*3+0]*o0 + gcp[e*3+1]*o1 + gcp[e*3+2]*o2;
        }
      }
    }
  }
  // gated L2 gathers: only active edges touch as_/an_
  float vas[16], van[16];
  #pragma unroll
  for (int j = 0; j < 16; ++j) vas[j] = act[j] ? as_[d[j]] : 0.f;
  #pragma unroll
  for (int j = 0; j < 16; ++j) van[j] = act[j] ? an_[s[j]] : 0.f;
  float sc[16];
  #pragma unroll
  for (int j = 0; j < 16; ++j) {
    float v = vas[j] + van[j];
    if (gcp) v *= uw[j];
    v = (v >= 0.f) ? v : 0.2f * v;       // leaky_relu 0.2
    sc[j] = __expf(v);                   // store exp: aggr just sums/weights
  }
  int tot = 0;
  #pragma unroll
  for (int j = 0; j < 16; ++j) tot += __popcll(__ballot(act[j]));
  int wb = 0;
  if (lane == 0) wb = atomicAdd(&lcnt, tot);
  wb = __shfl(wb, 0, 64);
  #pragma unroll
  for (int j = 0; j < 16; ++j) {
    unsigned long long m = __ballot(act[j]);
    if (act[j]) {
      int pref = __popcll(m & ((1ull << lane) - 1ull));
      int rel = atomicAdd(&deg[d[j]], 1);
      cmp[base + wb + pref] = make_int4(s[j], d[j], rel, __float_as_int(sc[j]));
    }
    wb += __popcll(m);
  }
  __syncthreads();
  if (threadIdx.x == 0) blkcnt[bid] = lcnt;
}

// ---------------- dual pass 2: compact slot + segment offsets (wave-aggregated) ----------
__global__ __launch_bounds__(256) void offset_dual(
    int split,
    const unsigned char* __restrict__ flA, const int* __restrict__ degA,
    int* __restrict__ offsA, int* __restrict__ dlA, int* __restrict__ g2cA,
    int* __restrict__ cntA, int NA,
    const unsigned char* __restrict__ flB, const int* __restrict__ degB,
    int* __restrict__ offsB, int* __restrict__ dlB, int* __restrict__ g2cB,
    int* __restrict__ cntB, int NB)
{
  const bool sB = (int)blockIdx.x >= split;
  const unsigned char* flag = sB ? flB : flA;
  const int* deg = sB ? degB : degA;
  int* offs = sB ? offsB : offsA;  int* dlist = sB ? dlB : dlA;
  int* g2c = sB ? g2cB : g2cA;     int* cnt = sB ? cntB : cntA;
  const int N = sB ? NB : NA;
  const int bid = sB ? ((int)blockIdx.x - split) : (int)blockIdx.x;
  const int lane = threadIdx.x & 63;

  int i = bid * 256 + threadIdx.x;
  bool actv = (i < N) && flag[i];
  int dg = actv ? deg[i] : 0;
  unsigned long long m = __ballot(actv);
  int nw = __popcll(m);
  if (nw == 0) return;
  int pref = __popcll(m & ((1ull << lane) - 1ull));
  int inc = dg;
  #pragma unroll
  for (int o = 1; o < 64; o <<= 1) {
    int v = __shfl_up(inc, o, 64);
    if (lane >= o) inc += v;
  }
  int tot = __shfl(inc, 63, 64);
  int exc = inc - dg;
  int baseL = 0, baseE = 0;
  if (lane == 0) {
    baseL = atomicAdd(&cnt[1], nw);
    baseE = atomicAdd(&cnt[0], tot);
  }
  baseL = __shfl(baseL, 0, 64);
  baseE = __shfl(baseE, 0, 64);
  if (actv) {
    int l = baseL + pref;
    g2c[i] = l;
    dlist[l] = i;
    if (dg > 0) offs[i] = baseE + exc;
  }
}

// ---------------- dual pass 3: place packed (src,p) — no atomics ----------
__global__ __launch_bounds__(256) void place_dual(
    int split,
    const int4* __restrict__ cmpA, const int* __restrict__ bcA,
    const int* __restrict__ offsA, int2* __restrict__ elA,
    const int4* __restrict__ cmpB, const int* __restrict__ bcB,
    const int* __restrict__ offsB, int2* __restrict__ elB)
{
  const bool sB = (int)blockIdx.x >= split;
  const int4* cmp = sB ? cmpB : cmpA;
  const int* blkcnt = sB ? bcB : bcA;
  const int* offs = sB ? offsB : offsA;
  int2* eline = sB ? elB : elA;
  const int bid = sB ? ((int)blockIdx.x - split) : (int)blockIdx.x;

  int nb = blkcnt[bid];
  const long base = (long)bid * 4096;
  for (int k = threadIdx.x; k < nb; k += 256) {
    int4 c = cmp[base + k];
    int pos = offs[c.y] + c.z;
    eline[pos] = make_int2(c.x, c.w);
  }
}

// ---------------- dual wave-per-dst softmax + aggregation (bf16 H1 reads) ----------
__global__ __launch_bounds__(256) void aggr_dual(
    int split,
    const int* __restrict__ dlA, const int* __restrict__ cntA,
    const int* __restrict__ offsA, const int* __restrict__ degA,
    const int2* __restrict__ elA, const unsigned short* __restrict__ H1A, float* __restrict__ HoA,
    const int* __restrict__ dlB, const int* __restrict__ cntB,
    const int* __restrict__ offsB, const int* __restrict__ degB,
    const int2* __restrict__ elB, const unsigned short* __restrict__ H1B, float* __restrict__ HoB)
{
  const bool sB = (int)blockIdx.x >= split;
  const int* dlist = sB ? dlB : dlA;  const int* cnt = sB ? cntB : cntA;
  const int* offs = sB ? offsB : offsA;  const int* deg = sB ? degB : degA;
  const int2* eline = sB ? elB : elA;
  const unsigned short* H1 = sB ? H1B : H1A;  float* Houtc = sB ? HoB : HoA;
  const int bid = sB ? ((int)blockIdx.x - split) : (int)blockIdx.x;

  int wid  = bid * 4 + (int)(threadIdx.x >> 6);
  int lane = threadIdx.x & 63;
  if (wid >= cnt[1]) return;
  int d = dlist[wid];
  int n = deg[d];
  float2* op = reinterpret_cast<float2*>(Houtc + (long)wid * KD) + lane;
  if (n == 0) { *op = make_float2(0.f, 0.f); return; }
  int st = offs[d];
  float ssum = 0.f;
  for (int i = lane; i < n; i += 64) ssum += __int_as_float(eline[st + i].y);
  #pragma unroll
  for (int o = 32; o; o >>= 1) ssum += __shfl_xor(ssum, o, 64);
  float inv = 1.f / ssum;
  float ax = 0.f, ay = 0.f;
  int i = 0;
  for (; i + 4 <= n; i += 4) {
    int2 e0 = eline[st + i], e1 = eline[st + i + 1], e2 = eline[st + i + 2], e3 = eline[st + i + 3];
    float a0 = __int_as_float(e0.y);
    float a1 = __int_as_float(e1.y);
    float a2 = __int_as_float(e2.y);
    float a3 = __int_as_float(e3.y);
    unsigned u0 = *reinterpret_cast<const unsigned*>(H1 + (long)e0.x * KD + lane * 2);
    unsigned u1 = *reinterpret_cast<const unsigned*>(H1 + (long)e1.x * KD + lane * 2);
    unsigned u2 = *reinterpret_cast<const unsigned*>(H1 + (long)e2.x * KD + lane * 2);
    unsigned u3 = *reinterpret_cast<const unsigned*>(H1 + (long)e3.x * KD + lane * 2);
    ax = fmaf(__uint_as_float(u0 << 16), a0, ax); ay = fmaf(__uint_as_float(u0 & 0xffff0000u), a0, ay);
    ax = fmaf(__uint_as_float(u1 << 16), a1, ax); ay = fmaf(__uint_as_float(u1 & 0xffff0000u), a1, ay);
    ax = fmaf(__uint_as_float(u2 << 16), a2, ax); ay = fmaf(__uint_as_float(u2 & 0xffff0000u), a2, ay);
    ax = fmaf(__uint_as_float(u3 << 16), a3, ax); ay = fmaf(__uint_as_float(u3 & 0xffff0000u), a3, ay);
  }
  for (; i < n; ++i) {
    int2 e0 = eline[st + i];
    float a0 = __int_as_float(e0.y);
    unsigned u0 = *reinterpret_cast<const unsigned*>(H1 + (long)e0.x * KD + lane * 2);
    ax = fmaf(__uint_as_float(u0 << 16), a0, ax); ay = fmaf(__uint_as_float(u0 & 0xffff0000u), a0, ay);
  }
  *op = make_float2(ax * inv, ay * inv);
}

// ---------------- final: dot + biases + sigmoid -------------
__global__ __launch_bounds__(256) void final_kernel(
    const float* __restrict__ Ug, const float* __restrict__ Bg,
    const int* __restrict__ ui, const int* __restrict__ ii,
    const float* __restrict__ bias_u, const float* __restrict__ bias_b,
    const float* __restrict__ bx, float* __restrict__ out, int B)
{
  int wid  = (int)((blockIdx.x * 256 + threadIdx.x) >> 6);
  int lane = threadIdx.x & 63;
  if (wid >= B) return;
  float v = Ug[(long)wid * 64 + lane] * Bg[(long)wid * 64 + lane];
  #pragma unroll
  for (int o = 32; o > 0; o >>= 1) v += __shfl_xor(v, o, 64);
  if (lane == 0) {
    float raw = v + bias_u[ui[wid]] + bias_b[ii[wid]] + bx[0];
    out[wid] = 4.f / (1.f + __expf(-raw)) + 1.f;
  }
}

extern "C" void kernel_launch(void* const* d_in, const int* in_sizes, int n_in,
                              void* d_out, int out_size, void* d_ws, size_t ws_size,
                              hipStream_t stream)
{
  const int*   ui    = (const int*)  d_in[0];
  const int*   ii    = (const int*)  d_in[1];
  const float* S_u   = (const float*)d_in[2];
  const float* S_b   = (const float*)d_in[3];
  const int*   eu    = (const int*)  d_in[4];
  const int*   eb    = (const int*)  d_in[5];
  const float* gc    = (const float*)d_in[6];
  const float* W1_u  = (const float*)d_in[7];
  const float* a_s_u = (const float*)d_in[8];
  const float* a_n_u = (const float*)d_in[9];
  const float* W1_b  = (const float*)d_in[10];
  const float* a_s_b = (const float*)d_in[11];
  const float* a_n_b = (const float*)d_in[12];
  const float* omega = (const float*)d_in[13];
  const float* W_u2  = (const float*)d_in[14];
  const float* W_us2w= (const float*)d_in[15];
  const float* W_us2b= (const float*)d_in[16];
  const float* W_b2  = (const float*)d_in[17];
  const float* W_bs2w= (const float*)d_in[18];
  const float* W_bs2b= (const float*)d_in[19];
  const float* W_u3  = (const float*)d_in[20];
  const float* W_b3  = (const float*)d_in[21];
  const float* H_u4  = (const float*)d_in[22];
  const float* H_b4  = (const float*)d_in[23];
  const float* bias_u= (const float*)d_in[24];
  const float* bias_b= (const float*)d_in[25];
  const float* b_x   = (const float*)d_in[26];
  float* out = (float*)d_out;

  const int B  = in_sizes[0];
  const int NU = in_sizes[2] / KD;
  const int NI = in_sizes[3] / KD;
  const int EU = in_sizes[4] / 2;
  const int EB = in_sizes[5] / 2;
  const int GPU_ = (EU + 4095) / 4096;
  const int GPB_ = (EB + 4095) / 4096;
  const int G1U = (NU + 63) / 64, G1I = (NI + 63) / 64;
  const int GOU = (NU + 255) / 256, GOI = (NI + 255) / 256;
  const int GAG = (B + 3) / 4;
  const int GB  = (B + 63) / 64;

  char* w = (char*)d_ws;
  auto alloc = [&](size_t bytes) -> void* {
    void* r = (void*)w;
    w += (bytes + 255) & ~(size_t)255;
    return r;
  };
  // ---- zero-initialized region (one small memset per call) ----
  int* deg_u = (int*)alloc((size_t)NU * 4);
  int* deg_b = (int*)alloc((size_t)NI * 4);
  unsigned char* nfu = (unsigned char*)alloc((size_t)NU);
  unsigned char* nfb = (unsigned char*)alloc((size_t)NI);
  unsigned* mku = (unsigned*)alloc((size_t)((NU + 31) / 32) * 4);
  unsigned* mkb = (unsigned*)alloc((size_t)((NI + 31) / 32) * 4);
  int* cnt   = (int*)alloc(16 * 4);
  size_t zbytes = (size_t)(w - (char*)d_ws);
  // ---- scratch ----
  unsigned short* wt = (unsigned short*)alloc((size_t)(6 * 16384 + 2 * 8192) * 2);
  int*   offs_u = (int*)  alloc((size_t)NU * 4);
  int*   offs_b = (int*)  alloc((size_t)NI * 4);
  int*   g2c_u  = (int*)  alloc((size_t)NU * 4);
  int*   g2c_b  = (int*)  alloc((size_t)NI * 4);
  int*   dl_u   = (int*)  alloc((size_t)B * 4);
  int*   dl_b   = (int*)  alloc((size_t)B * 4);
  int*   bc_u   = (int*)  alloc((size_t)GPU_ * 4);
  int*   bc_b   = (int*)  alloc((size_t)GPB_ * 4);
  int4*  cmp_u  = (int4*) alloc((size_t)GPU_ * 4096 * 16);
  int4*  cmp_b  = (int4*) alloc((size_t)GPB_ * 4096 * 16);
  int2*  el_u   = (int2*) alloc((size_t)EU * 8);
  int2*  el_b   = (int2*) alloc((size_t)EB * 8);
  unsigned short* H1u = (unsigned short*)alloc((size_t)NU * KD * 2);
  unsigned short* H1b = (unsigned short*)alloc((size_t)NI * KD * 2);
  float* Hu2c = (float*)alloc((size_t)B * KD * 4);
  float* Hb2c = (float*)alloc((size_t)B * KD * 4);
  float* asu  = (float*)alloc((size_t)NU * 4);
  float* anu  = (float*)alloc((size_t)NU * 4);
  float* asb  = (float*)alloc((size_t)NI * 4);
  float* anb  = (float*)alloc((size_t)NI * 4);
  float* Hu3g = (float*)alloc((size_t)B * KD * 4);
  float* Hb3g = (float*)alloc((size_t)B * KD * 4);
  float* Ug   = (float*)alloc((size_t)B * 64 * 4);
  float* Bg   = (float*)alloc((size_t)B * 64 * 4);
  (void)ws_size; (void)n_in; (void)out_size;

  hipMemsetAsync(d_ws, 0, zbytes, stream);

  wsplit6<<<384, 256, 0, stream>>>(W1_u, W1_b, W_u2, W_us2w, W_b2, W_bs2w, wt);
  w3split<<<64, 256, 0, stream>>>(W_u3, W_b3, wt + 6 * 16384);
  flags_kernel<<<(B + 255) / 256, 256, 0, stream>>>(ui, ii, B, nfu, nfb, mku, mkb);

  // H1 = S @ W1: bf16 MFMA, fused proj + NaN sentinel
  mfma1_dual<<<G1U + G1I, 256, 0, stream>>>(
      G1U,
      S_u, wt + 0 * 16384, NU, H1u, a_s_u, a_n_u, asu, anu, nfu,
      S_b, wt + 1 * 16384, NI, H1b, a_s_b, a_n_b, asb, anb, nfb);

  edge_prep_dual<<<GPU_ + GPB_, 256, 0, stream>>>(
      GPU_,
      eu, eu + EU, asu, anu, mku, deg_u, cmp_u, bc_u, EU,
      eb, eb + EB, asb, anb, mkb, gc, omega, deg_b, cmp_b, bc_b, EB);

  offset_dual<<<GOU + GOI, 256, 0, stream>>>(
      GOU,
      nfu, deg_u, offs_u, dl_u, g2c_u, cnt + 0, NU,
      nfb, deg_b, offs_b, dl_b, g2c_b, cnt + 2, NI);

  place_dual<<<GPU_ + GPB_, 256, 0, stream>>>(
      GPU_,
      cmp_u, bc_u, offs_u, el_u,
      cmp_b, bc_b, offs_b, el_b);

  aggr_dual<<<GAG * 2, 256, 0, stream>>>(
      GAG,
      dl_u, cnt + 0, offs_u, deg_u, el_u, H1u, Hu2c,
      dl_b, cnt + 2, offs_b, deg_b, el_b, H1b, Hb2c);

  // H3 = elu(Hu2c[g2c[ui]]@W_u2 + S_u[ui]@W_us2w + b): bf16 MFMA, 2 passes
  mfma2_dual<<<GB * 2, 256, 0, stream>>>(
      GB,
      Hu2c, wt + 2 * 16384, S_u, wt + 3 * 16384, W_us2b, ui, g2c_u, B, Hu3g,
      Hb2c, wt + 4 * 16384, S_b, wt + 5 * 16384, W_bs2b, ii, g2c_b, B, Hb3g);

  // U = elu(H3 @ W3) + H4[idx]: bf16 MFMA, NC=64
  mfma3_dual<<<GB * 2, 256, 0, stream>>>(
      GB,
      Hu3g, wt + 6 * 16384, H_u4, ui, B, Ug,
      Hb3g, wt + 6 * 16384 + 8192, H_b4, ii, B, Bg);

  final_kernel<<<(B + 3) / 4, 256, 0, stream>>>(Ug, Bg, ui, ii, bias_u, bias_b, b_x, out, B);
}

// Round 24
// 240.025 us; speedup vs baseline: 1.0940x; 1.0940x over previous
//
#include <hip/hip_runtime.h>
#include <hip/hip_bf16.h>

#define KD 128
#define NANF __int_as_float(0x7fc00000)

typedef __attribute__((ext_vector_type(8))) short bf16x8;
typedef __attribute__((ext_vector_type(4))) float f32x4;

__device__ __forceinline__ unsigned short f2b(float x) {  // fp32 -> bf16 RNE
  unsigned u = __float_as_uint(x);
  return (unsigned short)((u + 0x7fffu + ((u >> 16) & 1u)) >> 16);
}
__device__ __forceinline__ int swz(int row, int kbyte) {  // LDS byte addr, G4 XOR swizzle
  return (row * 256 + kbyte) ^ ((row & 7) << 4);
}

// ---------------- one-shot: transpose+convert six 128x128 W to bf16 Wt[n][k] ----------------
// order: 0=W1_u 1=W1_b 2=W_u2 3=W_us2w 4=W_b2 5=W_bs2w
__global__ __launch_bounds__(256) void wsplit6(
    const float* __restrict__ w0, const float* __restrict__ w1,
    const float* __restrict__ w2, const float* __restrict__ w3,
    const float* __restrict__ w4, const float* __restrict__ w5,
    unsigned short* __restrict__ oh)
{
  int m = blockIdx.x >> 6;
  int idx = (blockIdx.x & 63) * 256 + threadIdx.x;   // n*128 + k
  const float* ws;
  switch (m) { case 0: ws = w0; break; case 1: ws = w1; break; case 2: ws = w2; break;
               case 3: ws = w3; break; case 4: ws = w4; break; default: ws = w5; }
  int n = idx >> 7, k = idx & 127;
  oh[(long)m * 16384 + idx] = f2b(ws[k * 128 + n]);
}

// ---------------- item-graph segment boundaries (dst is sorted ascending) ----------------
__global__ __launch_bounds__(256) void segb_kernel(
    const int* __restrict__ dst, int E,
    int* __restrict__ sstart, int* __restrict__ send)
{
  int e = blockIdx.x * 256 + threadIdx.x;
  if (e >= E) return;
  int d = dst[e];
  if (e == 0 || dst[e - 1] != d) sstart[d] = e;
  if (e == E - 1 || dst[e + 1] != d) send[d] = e + 1;
}

// ---------------- gemm1: dual-grid bf16 MFMA, both operands LDS (swizzled) ----------------
__global__ __launch_bounds__(256, 3) void mfma1_dual(
    int split,
    const float* __restrict__ Aa, const unsigned short* __restrict__ Wta, int Ma,
    unsigned short* __restrict__ Ca,
    const float* __restrict__ a_sa, const float* __restrict__ a_na,
    float* __restrict__ as_oa, float* __restrict__ an_oa, const unsigned char* __restrict__ fla,
    const float* __restrict__ Ab, const unsigned short* __restrict__ Wtb, int Mb,
    unsigned short* __restrict__ Cb,
    const float* __restrict__ a_sb, const float* __restrict__ a_nb,
    float* __restrict__ as_ob, float* __restrict__ an_ob, const unsigned char* __restrict__ flb)
{
  const bool sB = (int)blockIdx.x >= split;
  const float* A = sB ? Ab : Aa;
  const unsigned short* Wt = sB ? Wtb : Wta;
  const int M = sB ? Mb : Ma;
  unsigned short* C = sB ? Cb : Ca;
  const float* a_s = sB ? a_sb : a_sa;  const float* a_n = sB ? a_nb : a_na;
  float* as_o = sB ? as_ob : as_oa;     float* an_o = sB ? an_ob : an_oa;
  const unsigned char* fl = sB ? flb : fla;
  const int bid = sB ? ((int)blockIdx.x - split) : (int)blockIdx.x;

  __shared__ unsigned short sW[16384];   // 32KB
  __shared__ unsigned short sA[8192];    // 16KB
  __shared__ float pp[4][64][2];         // 2KB

  const int t = threadIdx.x;
  const int w = t >> 6, l = t & 63;
  const int lr = l & 15, lk = l >> 4;
  const int row0 = bid * 64;
  char* sWc = reinterpret_cast<char*>(sW);
  char* sAc = reinterpret_cast<char*>(sA);

  #pragma unroll
  for (int q = 0; q < 8; ++q) {
    int p = t + 256 * q;
    int n = p >> 4, c16 = p & 15;
    bf16x8 v = *reinterpret_cast<const bf16x8*>(Wt + n * 128 + c16 * 8);
    *reinterpret_cast<bf16x8*>(sWc + swz(n, c16 * 16)) = v;
  }
  #pragma unroll
  for (int q = 0; q < 4; ++q) {
    int p = t + 256 * q;
    int r = p >> 4, c16 = p & 15;
    int gr = row0 + r;
    bf16x8 hv;
    if (gr < M) {
      const float4* ap = reinterpret_cast<const float4*>(A + (long)gr * KD + c16 * 8);
      float4 v0 = ap[0], v1 = ap[1];
      hv[0]=(short)f2b(v0.x); hv[1]=(short)f2b(v0.y); hv[2]=(short)f2b(v0.z); hv[3]=(short)f2b(v0.w);
      hv[4]=(short)f2b(v1.x); hv[5]=(short)f2b(v1.y); hv[6]=(short)f2b(v1.z); hv[7]=(short)f2b(v1.w);
    } else {
      #pragma unroll
      for (int j = 0; j < 8; ++j) hv[j] = 0;
    }
    *reinterpret_cast<bf16x8*>(sAc + swz(r, c16 * 16)) = hv;
  }
  __syncthreads();

  f32x4 acc[4][2];
  #pragma unroll
  for (int i = 0; i < 4; ++i)
    #pragma unroll
    for (int tt = 0; tt < 2; ++tt) acc[i][tt] = (f32x4){0.f, 0.f, 0.f, 0.f};

  #pragma unroll
  for (int kc = 0; kc < 4; ++kc) {
    const int kb = (kc * 32 + lk * 8) * 2;
    bf16x8 af[4];
    #pragma unroll
    for (int i = 0; i < 4; ++i)
      af[i] = *reinterpret_cast<const bf16x8*>(sAc + swz(i * 16 + lr, kb));
    #pragma unroll
    for (int tt = 0; tt < 2; ++tt) {
      int n = (w * 2 + tt) * 16 + lr;
      bf16x8 bfr = *reinterpret_cast<const bf16x8*>(sWc + swz(n, kb));
      #pragma unroll
      for (int i = 0; i < 4; ++i)
        acc[i][tt] = __builtin_amdgcn_mfma_f32_16x16x32_bf16(af[i], bfr, acc[i][tt], 0, 0, 0);
    }
  }

  float asv[2], anv[2];
  #pragma unroll
  for (int tt = 0; tt < 2; ++tt) {
    int col = (w * 2 + tt) * 16 + lr;
    asv[tt] = a_s[col]; anv[tt] = a_n[col];
  }
  #pragma unroll
  for (int i = 0; i < 4; ++i) {
    #pragma unroll
    for (int r = 0; r < 4; ++r) {
      float ds = acc[i][0][r] * asv[0] + acc[i][1][r] * asv[1];
      float dn = acc[i][0][r] * anv[0] + acc[i][1][r] * anv[1];
      #pragma unroll
      for (int o = 1; o < 16; o <<= 1) { ds += __shfl_xor(ds, o, 64); dn += __shfl_xor(dn, o, 64); }
      if (lr == 0) {
        int row = i * 16 + lk * 4 + r;
        pp[w][row][0] = ds; pp[w][row][1] = dn;
      }
    }
  }
  #pragma unroll
  for (int i = 0; i < 4; ++i) {
    #pragma unroll
    for (int r = 0; r < 4; ++r) {
      int gr = row0 + i * 16 + lk * 4 + r;
      if (gr >= M) continue;
      #pragma unroll
      for (int tt = 0; tt < 2; ++tt) {
        int col = (w * 2 + tt) * 16 + lr;
        C[(long)gr * 128 + col] = f2b(acc[i][tt][r]);
      }
    }
  }
  __syncthreads();
  if (t < 64) {
    int gr = row0 + t;
    if (gr < M) {
      float ds = pp[0][t][0] + pp[1][t][0] + pp[2][t][0] + pp[3][t][0];
      float dn = pp[0][t][1] + pp[1][t][1] + pp[2][t][1] + pp[3][t][1];
      as_o[gr] = fl[gr] ? ds : NANF;
      an_o[gr] = dn;
    }
  }
}

// ---------------- gemm2: dual-grid bf16 MFMA, 2 accumulate passes, gathered A ----------------
__global__ __launch_bounds__(256, 3) void mfma2_dual(
    int split,
    const float* __restrict__ A1a, const unsigned short* __restrict__ W1ta,
    const float* __restrict__ A2a, const unsigned short* __restrict__ W2ta,
    const float* __restrict__ biasa, const int* __restrict__ aidxa,
    const int* __restrict__ map1a, int Ma, float* __restrict__ Ca,
    const float* __restrict__ A1b, const unsigned short* __restrict__ W1tb,
    const float* __restrict__ A2b, const unsigned short* __restrict__ W2tb,
    const float* __restrict__ biasb, const int* __restrict__ aidxb,
    const int* __restrict__ map1b, int Mb, float* __restrict__ Cb)
{
  const bool sB = (int)blockIdx.x >= split;
  const float* A1 = sB ? A1b : A1a;  const unsigned short* W1t = sB ? W1tb : W1ta;
  const float* A2 = sB ? A2b : A2a;  const unsigned short* W2t = sB ? W2tb : W2ta;
  const float* bias = sB ? biasb : biasa;
  const int* aidx = sB ? aidxb : aidxa;  const int* map1 = sB ? map1b : map1a;
  const int M = sB ? Mb : Ma;  float* C = sB ? Cb : Ca;
  const int bid = sB ? ((int)blockIdx.x - split) : (int)blockIdx.x;

  __shared__ unsigned short sW[16384];   // 32KB
  __shared__ unsigned short sA[8192];    // 16KB

  const int t = threadIdx.x;
  const int w = t >> 6, l = t & 63;
  const int lr = l & 15, lk = l >> 4;
  const int row0 = bid * 64;
  char* sWc = reinterpret_cast<char*>(sW);
  char* sAc = reinterpret_cast<char*>(sA);

  f32x4 acc[4][2];
  #pragma unroll
  for (int i = 0; i < 4; ++i)
    #pragma unroll
    for (int tt = 0; tt < 2; ++tt) acc[i][tt] = (f32x4){0.f, 0.f, 0.f, 0.f};

  #pragma unroll
  for (int pass = 0; pass < 2; ++pass) {
    const float* Am = pass ? A2 : A1;
    const unsigned short* Wt = pass ? W2t : W1t;
    if (pass) __syncthreads();
    #pragma unroll
    for (int q = 0; q < 8; ++q) {
      int p = t + 256 * q;
      int n = p >> 4, c16 = p & 15;
      bf16x8 v = *reinterpret_cast<const bf16x8*>(Wt + n * 128 + c16 * 8);
      *reinterpret_cast<bf16x8*>(sWc + swz(n, c16 * 16)) = v;
    }
    #pragma unroll
    for (int q = 0; q < 4; ++q) {
      int p = t + 256 * q;
      int r = p >> 4, c16 = p & 15;
      int gr = row0 + r;
      bf16x8 hv;
      if (gr < M) {
        long grow = (long)aidx[gr];
        if (pass == 0) grow = map1[grow];
        const float4* ap = reinterpret_cast<const float4*>(Am + grow * KD + c16 * 8);
        float4 v0 = ap[0], v1 = ap[1];
        hv[0]=(short)f2b(v0.x); hv[1]=(short)f2b(v0.y); hv[2]=(short)f2b(v0.z); hv[3]=(short)f2b(v0.w);
        hv[4]=(short)f2b(v1.x); hv[5]=(short)f2b(v1.y); hv[6]=(short)f2b(v1.z); hv[7]=(short)f2b(v1.w);
      } else {
        #pragma unroll
        for (int j = 0; j < 8; ++j) hv[j] = 0;
      }
      *reinterpret_cast<bf16x8*>(sAc + swz(r, c16 * 16)) = hv;
    }
    __syncthreads();
    #pragma unroll
    for (int kc = 0; kc < 4; ++kc) {
      const int kb = (kc * 32 + lk * 8) * 2;
      bf16x8 af[4];
      #pragma unroll
      for (int i = 0; i < 4; ++i)
        af[i] = *reinterpret_cast<const bf16x8*>(sAc + swz(i * 16 + lr, kb));
      #pragma unroll
      for (int tt = 0; tt < 2; ++tt) {
        int n = (w * 2 + tt) * 16 + lr;
        bf16x8 bfr = *reinterpret_cast<const bf16x8*>(sWc + swz(n, kb));
        #pragma unroll
        for (int i = 0; i < 4; ++i)
          acc[i][tt] = __builtin_amdgcn_mfma_f32_16x16x32_bf16(af[i], bfr, acc[i][tt], 0, 0, 0);
      }
    }
  }
  float bv[2];
  #pragma unroll
  for (int tt = 0; tt < 2; ++tt) bv[tt] = bias[(w * 2 + tt) * 16 + lr];
  #pragma unroll
  for (int i = 0; i < 4; ++i) {
    #pragma unroll
    for (int r = 0; r < 4; ++r) {
      int gr = row0 + i * 16 + lk * 4 + r;
      if (gr >= M) continue;
      #pragma unroll
      for (int tt = 0; tt < 2; ++tt) {
        int col = (w * 2 + tt) * 16 + lr;
        float v = acc[i][tt][r] + bv[tt];
        v = (v > 0.f) ? v : (__expf(v) - 1.f);
        C[(long)gr * 128 + col] = v;
      }
    }
  }
}

// ---------------- gemm3: dual-grid fp32, BM=64 NC=64, elu + gathered residual ----------
template<int BM, int NC>
__global__ __launch_bounds__(256, 3) void gemm3_dual(
    int split,
    const float* __restrict__ A1a, const float* __restrict__ W1a,
    const float* __restrict__ Resa, const int* __restrict__ ridxa, int Ma,
    float* __restrict__ Ca,
    const float* __restrict__ A1b, const float* __restrict__ W1b,
    const float* __restrict__ Resb, const int* __restrict__ ridxb, int Mb,
    float* __restrict__ Cb)
{
  const bool sB = (int)blockIdx.x >= split;
  const float* A1 = sB ? A1b : A1a;  const float* W1 = sB ? W1b : W1a;
  const float* Res = sB ? Resb : Resa;
  const int* ridx = sB ? ridxb : ridxa;
  const int M = sB ? Mb : Ma;  float* C = sB ? Cb : Ca;
  const int bid = sB ? ((int)blockIdx.x - split) : (int)blockIdx.x;

  constexpr int RT = BM / 16;
  constexpr int CW = NC / 16;
  constexpr int KB = 64;
  constexpr int CPP = KD / KB;
  constexpr int F4PR = KB / 4;
  constexpr int NAF4 = BM * KB / 4 / 256;
  constexpr int NWF4 = KB * NC / 4 / 256;
  __shared__ float sA[BM][KB + 4];
  __shared__ float sW[KB][NC];
  const int t  = threadIdx.x;
  const int ty = t >> 4, tx = t & 15;
  const int row0 = bid * BM;

  float acc[RT][CW];
  #pragma unroll
  for (int i = 0; i < RT; ++i)
    #pragma unroll
    for (int j = 0; j < CW; ++j) acc[i][j] = 0.f;

  for (int cc = 0; cc < CPP; ++cc) {
    const int kc = cc;
    if (cc) __syncthreads();
    {
      const float4* Wp = reinterpret_cast<const float4*>(W1) + (long)kc * (KB * NC / 4);
      #pragma unroll
      for (int q = 0; q < NWF4; ++q)
        reinterpret_cast<float4*>(&sW[0][0])[t + 256 * q] = Wp[t + 256 * q];
    }
    #pragma unroll
    for (int q = 0; q < NAF4; ++q) {
      int p  = t + 256 * q;
      int r  = p / F4PR, c4 = p % F4PR;
      float4 v = make_float4(0.f, 0.f, 0.f, 0.f);
      int gr = row0 + r;
      if (gr < M) {
        v = reinterpret_cast<const float4*>(A1 + (long)gr * KD)[kc * F4PR + c4];
      }
      *reinterpret_cast<float4*>(&sA[r][c4 * 4]) = v;
    }
    __syncthreads();
    #pragma unroll 4
    for (int k4 = 0; k4 < KB; k4 += 4) {
      float4 a4[RT];
      #pragma unroll
      for (int i = 0; i < RT; ++i)
        a4[i] = *reinterpret_cast<const float4*>(&sA[ty + 16 * i][k4]);
      #pragma unroll
      for (int kk = 0; kk < 4; ++kk) {
        float wv[CW];
        #pragma unroll
        for (int h = 0; h < CW / 4; ++h) {
          float4 w4 = *reinterpret_cast<const float4*>(&sW[k4 + kk][tx * 4 + 64 * h]);
          wv[h*4+0] = w4.x; wv[h*4+1] = w4.y; wv[h*4+2] = w4.z; wv[h*4+3] = w4.w;
        }
        #pragma unroll
        for (int i = 0; i < RT; ++i) {
          float a = (kk == 0) ? a4[i].x : (kk == 1) ? a4[i].y : (kk == 2) ? a4[i].z : a4[i].w;
          #pragma unroll
          for (int j = 0; j < CW; ++j)
            acc[i][j] = fmaf(a, wv[j], acc[i][j]);
        }
      }
    }
  }
  #pragma unroll
  for (int i = 0; i < RT; ++i) {
    int gr = row0 + ty + 16 * i;
    if (gr >= M) continue;
    long rrow = (long)ridx[gr];
    #pragma unroll
    for (int h = 0; h < CW / 4; ++h) {
      int c = tx * 4 + 64 * h;
      float4 v = make_float4(acc[i][h*4+0], acc[i][h*4+1], acc[i][h*4+2], acc[i][h*4+3]);
      v.x = (v.x > 0.f) ? v.x : (__expf(v.x) - 1.f);
      v.y = (v.y > 0.f) ? v.y : (__expf(v.y) - 1.f);
      v.z = (v.z > 0.f) ? v.z : (__expf(v.z) - 1.f);
      v.w = (v.w > 0.f) ? v.w : (__expf(v.w) - 1.f);
      float4 rv = *reinterpret_cast<const float4*>(Res + rrow * NC + c);
      v.x += rv.x; v.y += rv.y; v.z += rv.z; v.w += rv.w;
      *reinterpret_cast<float4*>(C + (long)gr * NC + c) = v;
    }
  }
}

// ---------------- needed-dst flags: byte array + 1-bit mask (L1-resident gate) ----------
__global__ void flags_kernel(const int* __restrict__ ui, const int* __restrict__ ii, int B,
                             unsigned char* __restrict__ nfu, unsigned char* __restrict__ nfb,
                             unsigned* __restrict__ mku, unsigned* __restrict__ mkb)
{
  int i = blockIdx.x * blockDim.x + threadIdx.x;
  if (i < B) {
    int u = ui[i], v = ii[i];
    nfu[u] = 1; nfb[v] = 1;
    atomicOr(&mku[u >> 5], 1u << (u & 31));
    atomicOr(&mkb[v >> 5], 1u << (v & 31));
  }
}

// ---------------- dual pass 1: 16 edges/thread; bitmask gate; item rel from sorted segs ----
__global__ __launch_bounds__(256) void edge_prep_dual(
    int split,
    const int* __restrict__ srcA, const int* __restrict__ dstA,
    const float* __restrict__ asA, const float* __restrict__ anA,
    const unsigned* __restrict__ mkA, const int* __restrict__ ssA,
    int* __restrict__ degA, int4* __restrict__ cmpA, int* __restrict__ bcA, int EA,
    const int* __restrict__ srcB, const int* __restrict__ dstB,
    const float* __restrict__ asB, const float* __restrict__ anB,
    const unsigned* __restrict__ mkB, const int* __restrict__ ssB,
    const float* __restrict__ gc, const float* __restrict__ omega,
    int* __restrict__ degB, int4* __restrict__ cmpB, int* __restrict__ bcB, int EB_)
{
  const bool sB = (int)blockIdx.x >= split;
  const int* src = sB ? srcB : srcA;  const int* dst = sB ? dstB : dstA;
  const float* as_ = sB ? asB : asA;  const float* an_ = sB ? anB : anA;
  const unsigned* mk = sB ? mkB : mkA;
  const int* ss = sB ? ssB : ssA;      // sorted-dst segment starts (item side only)
  int* deg = sB ? degB : degA;  int4* cmp = sB ? cmpB : cmpA;
  int* blkcnt = sB ? bcB : bcA;
  const int E = sB ? EB_ : EA;
  const float* gcp = sB ? gc : nullptr;
  const int bid = sB ? ((int)blockIdx.x - split) : (int)blockIdx.x;

  __shared__ int lcnt;
  if (threadIdx.x == 0) lcnt = 0;
  __syncthreads();
  const int lane = threadIdx.x & 63;
  const long base = (long)bid * 4096;
  const int e0 = (int)base + threadIdx.x * 16;

  int d[16], s[16];
  bool act[16];
  const bool full = (e0 + 15 < E);
  if (full) {
    #pragma unroll
    for (int q = 0; q < 4; ++q) {
      int4 d4 = *reinterpret_cast<const int4*>(dst + e0 + q * 4);
      int4 s4 = *reinterpret_cast<const int4*>(src + e0 + q * 4);
      d[q*4+0]=d4.x; d[q*4+1]=d4.y; d[q*4+2]=d4.z; d[q*4+3]=d4.w;
      s[q*4+0]=s4.x; s[q*4+1]=s4.y; s[q*4+2]=s4.z; s[q*4+3]=s4.w;
    }
    #pragma unroll
    for (int j = 0; j < 16; ++j) act[j] = true;
  } else {
    #pragma unroll
    for (int j = 0; j < 16; ++j) {
      act[j] = (e0 + j < E);
      d[j] = act[j] ? dst[e0 + j] : 0;
      s[j] = act[j] ? src[e0 + j] : 0;
    }
  }
  // 1-bit mask gate: random reads into a <13KB L1-resident table
  unsigned mw[16];
  #pragma unroll
  for (int j = 0; j < 16; ++j) mw[j] = mk[d[j] >> 5];
  #pragma unroll
  for (int j = 0; j < 16; ++j) act[j] = act[j] && ((mw[j] >> (d[j] & 31)) & 1u);

  float uw[16];
  if (gcp) {
    float o0 = omega[0], o1 = omega[1], o2 = omega[2];
    if (full) {
      float g[48];
      const float4* gp = reinterpret_cast<const float4*>(gcp + (long)e0 * 3);
      #pragma unroll
      for (int q = 0; q < 12; ++q) *reinterpret_cast<float4*>(&g[q*4]) = gp[q];
      #pragma unroll
      for (int j = 0; j < 16; ++j) uw[j] = g[j*3+0]*o0 + g[j*3+1]*o1 + g[j*3+2]*o2;
    } else {
      #pragma unroll
      for (int j = 0; j < 16; ++j) {
        uw[j] = 0.f;
        if (act[j]) {
          long e = e0 + j;
          uw[j] = gcp[e*3+0]*o0 + gcp[e*3+1]*o1 + gcp[e*3+2]*o2;
        }
      }
    }
  }
  // gated L2 gathers: only active edges touch as_/an_
  float vas[16], van[16];
  #pragma unroll
  for (int j = 0; j < 16; ++j) vas[j] = act[j] ? as_[d[j]] : 0.f;
  #pragma unroll
  for (int j = 0; j < 16; ++j) van[j] = act[j] ? an_[s[j]] : 0.f;
  // sorted-dst rel: gather segment start (cacheline-local since dst sorted)
  int ssv[16];
  if (ss) {
    #pragma unroll
    for (int j = 0; j < 16; ++j) ssv[j] = act[j] ? ss[d[j]] : 0;
  }
  float sc[16];
  #pragma unroll
  for (int j = 0; j < 16; ++j) {
    float v = vas[j] + van[j];
    if (gcp) v *= uw[j];
    v = (v >= 0.f) ? v : 0.2f * v;       // leaky_relu 0.2
    sc[j] = __expf(v);
  }
  int tot = 0;
  #pragma unroll
  for (int j = 0; j < 16; ++j) tot += __popcll(__ballot(act[j]));
  int wb = 0;
  if (lane == 0) wb = atomicAdd(&lcnt, tot);
  wb = __shfl(wb, 0, 64);
  #pragma unroll
  for (int j = 0; j < 16; ++j) {
    unsigned long long m = __ballot(act[j]);
    if (act[j]) {
      int pref = __popcll(m & ((1ull << lane) - 1ull));
      int rel = ss ? (e0 + j - ssv[j]) : atomicAdd(&deg[d[j]], 1);
      cmp[base + wb + pref] = make_int4(s[j], d[j], rel, __float_as_int(sc[j]));
    }
    wb += __popcll(m);
  }
  __syncthreads();
  if (threadIdx.x == 0) blkcnt[bid] = lcnt;
}

// ---------------- dual pass 2: compact slot + segment offsets (wave-aggregated) ----------
// Side B derives deg from sorted-segment boundaries and materializes it for aggr.
__global__ __launch_bounds__(256) void offset_dual(
    int split,
    const unsigned char* __restrict__ flA, int* __restrict__ degA,
    int* __restrict__ offsA, int* __restrict__ dlA, int* __restrict__ g2cA,
    int* __restrict__ cntA, int NA,
    const unsigned char* __restrict__ flB, int* __restrict__ degB,
    const int* __restrict__ sstartB, const int* __restrict__ sendB,
    int* __restrict__ offsB, int* __restrict__ dlB, int* __restrict__ g2cB,
    int* __restrict__ cntB, int NB)
{
  const bool sB = (int)blockIdx.x >= split;
  const unsigned char* flag = sB ? flB : flA;
  int* deg = sB ? degB : degA;
  int* offs = sB ? offsB : offsA;  int* dlist = sB ? dlB : dlA;
  int* g2c = sB ? g2cB : g2cA;     int* cnt = sB ? cntB : cntA;
  const int N = sB ? NB : NA;
  const int bid = sB ? ((int)blockIdx.x - split) : (int)blockIdx.x;
  const int lane = threadIdx.x & 63;

  int i = bid * 256 + threadIdx.x;
  bool actv = (i < N) && flag[i];
  int dg = 0;
  if (actv) {
    if (sB) { dg = sendB[i] - sstartB[i]; deg[i] = dg; }
    else dg = deg[i];
  }
  unsigned long long m = __ballot(actv);
  int nw = __popcll(m);
  if (nw == 0) return;
  int pref = __popcll(m & ((1ull << lane) - 1ull));
  int inc = dg;
  #pragma unroll
  for (int o = 1; o < 64; o <<= 1) {
    int v = __shfl_up(inc, o, 64);
    if (lane >= o) inc += v;
  }
  int tot = __shfl(inc, 63, 64);
  int exc = inc - dg;
  int baseL = 0, baseE = 0;
  if (lane == 0) {
    baseL = atomicAdd(&cnt[1], nw);
    baseE = atomicAdd(&cnt[0], tot);
  }
  baseL = __shfl(baseL, 0, 64);
  baseE = __shfl(baseE, 0, 64);
  if (actv) {
    int l = baseL + pref;
    g2c[i] = l;
    dlist[l] = i;
    if (dg > 0) offs[i] = baseE + exc;
  }
}

// ---------------- dual pass 3: place packed (src,p) — no atomics ----------
__global__ __launch_bounds__(256) void place_dual(
    int split,
    const int4* __restrict__ cmpA, const int* __restrict__ bcA,
    const int* __restrict__ offsA, int2* __restrict__ elA,
    const int4* __restrict__ cmpB, const int* __restrict__ bcB,
    const int* __restrict__ offsB, int2* __restrict__ elB)
{
  const bool sB = (int)blockIdx.x >= split;
  const int4* cmp = sB ? cmpB : cmpA;
  const int* blkcnt = sB ? bcB : bcA;
  const int* offs = sB ? offsB : offsA;
  int2* eline = sB ? elB : elA;
  const int bid = sB ? ((int)blockIdx.x - split) : (int)blockIdx.x;

  int nb = blkcnt[bid];
  const long base = (long)bid * 4096;
  for (int k = threadIdx.x; k < nb; k += 256) {
    int4 c = cmp[base + k];
    int pos = offs[c.y] + c.z;
    eline[pos] = make_int2(c.x, c.w);
  }
}

// ---------------- dual wave-per-dst softmax + aggregation (bf16 H1 reads) ----------
__global__ __launch_bounds__(256) void aggr_dual(
    int split,
    const int* __restrict__ dlA, const int* __restrict__ cntA,
    const int* __restrict__ offsA, const int* __restrict__ degA,
    const int2* __restrict__ elA, const unsigned short* __restrict__ H1A, float* __restrict__ HoA,
    const int* __restrict__ dlB, const int* __restrict__ cntB,
    const int* __restrict__ offsB, const int* __restrict__ degB,
    const int2* __restrict__ elB, const unsigned short* __restrict__ H1B, float* __restrict__ HoB)
{
  const bool sB = (int)blockIdx.x >= split;
  const int* dlist = sB ? dlB : dlA;  const int* cnt = sB ? cntB : cntA;
  const int* offs = sB ? offsB : offsA;  const int* deg = sB ? degB : degA;
  const int2* eline = sB ? elB : elA;
  const unsigned short* H1 = sB ? H1B : H1A;  float* Houtc = sB ? HoB : HoA;
  const int bid = sB ? ((int)blockIdx.x - split) : (int)blockIdx.x;

  int wid  = bid * 4 + (int)(threadIdx.x >> 6);
  int lane = threadIdx.x & 63;
  if (wid >= cnt[1]) return;
  int d = dlist[wid];
  int n = deg[d];
  float2* op = reinterpret_cast<float2*>(Houtc + (long)wid * KD) + lane;
  if (n == 0) { *op = make_float2(0.f, 0.f); return; }
  int st = offs[d];
  float ssum = 0.f;
  for (int i = lane; i < n; i += 64) ssum += __int_as_float(eline[st + i].y);
  #pragma unroll
  for (int o = 32; o; o >>= 1) ssum += __shfl_xor(ssum, o, 64);
  float inv = 1.f / ssum;
  float ax = 0.f, ay = 0.f;
  int i = 0;
  for (; i + 4 <= n; i += 4) {
    int2 e0 = eline[st + i], e1 = eline[st + i + 1], e2 = eline[st + i + 2], e3 = eline[st + i + 3];
    float a0 = __int_as_float(e0.y);
    float a1 = __int_as_float(e1.y);
    float a2 = __int_as_float(e2.y);
    float a3 = __int_as_float(e3.y);
    unsigned u0 = *reinterpret_cast<const unsigned*>(H1 + (long)e0.x * KD + lane * 2);
    unsigned u1 = *reinterpret_cast<const unsigned*>(H1 + (long)e1.x * KD + lane * 2);
    unsigned u2 = *reinterpret_cast<const unsigned*>(H1 + (long)e2.x * KD + lane * 2);
    unsigned u3 = *reinterpret_cast<const unsigned*>(H1 + (long)e3.x * KD + lane * 2);
    ax = fmaf(__uint_as_float(u0 << 16), a0, ax); ay = fmaf(__uint_as_float(u0 & 0xffff0000u), a0, ay);
    ax = fmaf(__uint_as_float(u1 << 16), a1, ax); ay = fmaf(__uint_as_float(u1 & 0xffff0000u), a1, ay);
    ax = fmaf(__uint_as_float(u2 << 16), a2, ax); ay = fmaf(__uint_as_float(u2 & 0xffff0000u), a2, ay);
    ax = fmaf(__uint_as_float(u3 << 16), a3, ax); ay = fmaf(__uint_as_float(u3 & 0xffff0000u), a3, ay);
  }
  for (; i < n; ++i) {
    int2 e0 = eline[st + i];
    float a0 = __int_as_float(e0.y);
    unsigned u0 = *reinterpret_cast<const unsigned*>(H1 + (long)e0.x * KD + lane * 2);
    ax = fmaf(__uint_as_float(u0 << 16), a0, ax); ay = fmaf(__uint_as_float(u0 & 0xffff0000u), a0, ay);
  }
  *op = make_float2(ax * inv, ay * inv);
}

// ---------------- final: dot + biases + sigmoid -------------
__global__ __launch_bounds__(256) void final_kernel(
    const float* __restrict__ Ug, const float* __restrict__ Bg,
    const int* __restrict__ ui, const int* __restrict__ ii,
    const float* __restrict__ bias_u, const float* __restrict__ bias_b,
    const float* __restrict__ bx, float* __restrict__ out, int B)
{
  int wid  = (int)((blockIdx.x * 256 + threadIdx.x) >> 6);
  int lane = threadIdx.x & 63;
  if (wid >= B) return;
  float v = Ug[(long)wid * 64 + lane] * Bg[(long)wid * 64 + lane];
  #pragma unroll
  for (int o = 32; o > 0; o >>= 1) v += __shfl_xor(v, o, 64);
  if (lane == 0) {
    float raw = v + bias_u[ui[wid]] + bias_b[ii[wid]] + bx[0];
    out[wid] = 4.f / (1.f + __expf(-raw)) + 1.f;
  }
}

extern "C" void kernel_launch(void* const* d_in, const int* in_sizes, int n_in,
                              void* d_out, int out_size, void* d_ws, size_t ws_size,
                              hipStream_t stream)
{
  const int*   ui    = (const int*)  d_in[0];
  const int*   ii    = (const int*)  d_in[1];
  const float* S_u   = (const float*)d_in[2];
  const float* S_b   = (const float*)d_in[3];
  const int*   eu    = (const int*)  d_in[4];
  const int*   eb    = (const int*)  d_in[5];
  const float* gc    = (const float*)d_in[6];
  const float* W1_u  = (const float*)d_in[7];
  const float* a_s_u = (const float*)d_in[8];
  const float* a_n_u = (const float*)d_in[9];
  const float* W1_b  = (const float*)d_in[10];
  const float* a_s_b = (const float*)d_in[11];
  const float* a_n_b = (const float*)d_in[12];
  const float* omega = (const float*)d_in[13];
  const float* W_u2  = (const float*)d_in[14];
  const float* W_us2w= (const float*)d_in[15];
  const float* W_us2b= (const float*)d_in[16];
  const float* W_b2  = (const float*)d_in[17];
  const float* W_bs2w= (const float*)d_in[18];
  const float* W_bs2b= (const float*)d_in[19];
  const float* W_u3  = (const float*)d_in[20];
  const float* W_b3  = (const float*)d_in[21];
  const float* H_u4  = (const float*)d_in[22];
  const float* H_b4  = (const float*)d_in[23];
  const float* bias_u= (const float*)d_in[24];
  const float* bias_b= (const float*)d_in[25];
  const float* b_x   = (const float*)d_in[26];
  float* out = (float*)d_out;

  const int B  = in_sizes[0];
  const int NU = in_sizes[2] / KD;
  const int NI = in_sizes[3] / KD;
  const int EU = in_sizes[4] / 2;
  const int EB = in_sizes[5] / 2;
  const int GPU_ = (EU + 4095) / 4096;
  const int GPB_ = (EB + 4095) / 4096;
  const int G1U = (NU + 63) / 64, G1I = (NI + 63) / 64;
  const int GOU = (NU + 255) / 256, GOI = (NI + 255) / 256;
  const int GAG = (B + 3) / 4;
  const int GB  = (B + 63) / 64;

  char* w = (char*)d_ws;
  auto alloc = [&](size_t bytes) -> void* {
    void* r = (void*)w;
    w += (bytes + 255) & ~(size_t)255;
    return r;
  };
  // ---- zero-initialized region (one small memset per call) ----
  int* deg_u = (int*)alloc((size_t)NU * 4);
  int* deg_b = (int*)alloc((size_t)NI * 4);
  unsigned char* nfu = (unsigned char*)alloc((size_t)NU);
  unsigned char* nfb = (unsigned char*)alloc((size_t)NI);
  unsigned* mku = (unsigned*)alloc((size_t)((NU + 31) / 32) * 4);
  unsigned* mkb = (unsigned*)alloc((size_t)((NI + 31) / 32) * 4);
  int* sst_b = (int*)alloc((size_t)NI * 4);
  int* snd_b = (int*)alloc((size_t)NI * 4);
  int* cnt   = (int*)alloc(16 * 4);
  size_t zbytes = (size_t)(w - (char*)d_ws);
  // ---- scratch ----
  unsigned short* wt = (unsigned short*)alloc((size_t)6 * 16384 * 2);
  int*   offs_u = (int*)  alloc((size_t)NU * 4);
  int*   offs_b = (int*)  alloc((size_t)NI * 4);
  int*   g2c_u  = (int*)  alloc((size_t)NU * 4);
  int*   g2c_b  = (int*)  alloc((size_t)NI * 4);
  int*   dl_u   = (int*)  alloc((size_t)B * 4);
  int*   dl_b   = (int*)  alloc((size_t)B * 4);
  int*   bc_u   = (int*)  alloc((size_t)GPU_ * 4);
  int*   bc_b   = (int*)  alloc((size_t)GPB_ * 4);
  int4*  cmp_u  = (int4*) alloc((size_t)GPU_ * 4096 * 16);
  int4*  cmp_b  = (int4*) alloc((size_t)GPB_ * 4096 * 16);
  int2*  el_u   = (int2*) alloc((size_t)EU * 8);
  int2*  el_b   = (int2*) alloc((size_t)EB * 8);
  unsigned short* H1u = (unsigned short*)alloc((size_t)NU * KD * 2);
  unsigned short* H1b = (unsigned short*)alloc((size_t)NI * KD * 2);
  float* Hu2c = (float*)alloc((size_t)B * KD * 4);
  float* Hb2c = (float*)alloc((size_t)B * KD * 4);
  float* asu  = (float*)alloc((size_t)NU * 4);
  float* anu  = (float*)alloc((size_t)NU * 4);
  float* asb  = (float*)alloc((size_t)NI * 4);
  float* anb  = (float*)alloc((size_t)NI * 4);
  float* Hu3g = (float*)alloc((size_t)B * KD * 4);
  float* Hb3g = (float*)alloc((size_t)B * KD * 4);
  float* Ug   = (float*)alloc((size_t)B * 64 * 4);
  float* Bg   = (float*)alloc((size_t)B * 64 * 4);
  (void)ws_size; (void)n_in; (void)out_size;

  hipMemsetAsync(d_ws, 0, zbytes, stream);

  wsplit6<<<384, 256, 0, stream>>>(W1_u, W1_b, W_u2, W_us2w, W_b2, W_bs2w, wt);
  flags_kernel<<<(B + 255) / 256, 256, 0, stream>>>(ui, ii, B, nfu, nfb, mku, mkb);
  segb_kernel<<<(EB + 255) / 256, 256, 0, stream>>>(eb + EB, EB, sst_b, snd_b);

  // H1 = S @ W1: bf16 MFMA, fused proj + NaN sentinel
  mfma1_dual<<<G1U + G1I, 256, 0, stream>>>(
      G1U,
      S_u, wt + 0 * 16384, NU, H1u, a_s_u, a_n_u, asu, anu, nfu,
      S_b, wt + 1 * 16384, NI, H1b, a_s_b, a_n_b, asb, anb, nfb);

  edge_prep_dual<<<GPU_ + GPB_, 256, 0, stream>>>(
      GPU_,
      eu, eu + EU, asu, anu, mku, nullptr, deg_u, cmp_u, bc_u, EU,
      eb, eb + EB, asb, anb, mkb, sst_b, gc, omega, deg_b, cmp_b, bc_b, EB);

  offset_dual<<<GOU + GOI, 256, 0, stream>>>(
      GOU,
      nfu, deg_u, offs_u, dl_u, g2c_u, cnt + 0, NU,
      nfb, deg_b, sst_b, snd_b, offs_b, dl_b, g2c_b, cnt + 2, NI);

  place_dual<<<GPU_ + GPB_, 256, 0, stream>>>(
      GPU_,
      cmp_u, bc_u, offs_u, el_u,
      cmp_b, bc_b, offs_b, el_b);

  aggr_dual<<<GAG * 2, 256, 0, stream>>>(
      GAG,
      dl_u, cnt + 0, offs_u, deg_u, el_u, H1u, Hu2c,
      dl_b, cnt + 2, offs_b, deg_b, el_b, H1b, Hb2c);

  // H3 = elu(Hu2c[g2c[ui]]@W_u2 + S_u[ui]@W_us2w + b): bf16 MFMA, 2 passes
  mfma2_dual<<<GB * 2, 256, 0, stream>>>(
      GB,
      Hu2c, wt + 2 * 16384, S_u, wt + 3 * 16384, W_us2b, ui, g2c_u, B, Hu3g,
      Hb2c, wt + 4 * 16384, S_b, wt + 5 * 16384, W_bs2b, ii, g2c_b, B, Hb3g);

  // U = elu(H3 @ W3) + H4[idx]: fp32, NC=64 (absmax margin)
  gemm3_dual<64,64><<<GB * 2, 256, 0, stream>>>(
      GB,
      Hu3g, W_u3, H_u4, ui, B, Ug,
      Hb3g, W_b3, H_b4, ii, B, Bg);

  final_kernel<<<(B + 3) / 4, 256, 0, stream>>>(Ug, Bg, ui, ii, bias_u, bias_b, b_x, out, B);
}

// Round 26
// 200.196 us; speedup vs baseline: 1.3117x; 1.1990x over previous
//
#include <hip/hip_runtime.h>
#include <hip/hip_bf16.h>

#define KD 128
#define NANF __int_as_float(0x7fc00000)

typedef __attribute__((ext_vector_type(8))) short bf16x8;
typedef __attribute__((ext_vector_type(4))) float f32x4;

__device__ __forceinline__ unsigned short f2b(float x) {  // fp32 -> bf16 RNE
  unsigned u = __float_as_uint(x);
  return (unsigned short)((u + 0x7fffu + ((u >> 16) & 1u)) >> 16);
}
__device__ __forceinline__ int swz(int row, int kbyte) {  // LDS byte addr, G4 XOR swizzle
  return (row * 256 + kbyte) ^ ((row & 7) << 4);
}

// ---------------- one-shot: transpose+convert six 128x128 W to bf16 Wt[n][k] ----------------
// order: 0=W1_u 1=W1_b 2=W_u2 3=W_us2w 4=W_b2 5=W_bs2w
__global__ __launch_bounds__(256) void wsplit6(
    const float* __restrict__ w0, const float* __restrict__ w1,
    const float* __restrict__ w2, const float* __restrict__ w3,
    const float* __restrict__ w4, const float* __restrict__ w5,
    unsigned short* __restrict__ oh)
{
  int m = blockIdx.x >> 6;
  int idx = (blockIdx.x & 63) * 256 + threadIdx.x;   // n*128 + k
  const float* ws;
  switch (m) { case 0: ws = w0; break; case 1: ws = w1; break; case 2: ws = w2; break;
               case 3: ws = w3; break; case 4: ws = w4; break; default: ws = w5; }
  int n = idx >> 7, k = idx & 127;
  oh[(long)m * 16384 + idx] = f2b(ws[k * 128 + n]);
}

// ---------------- item-graph segment boundaries (dst is sorted ascending) ----------------
__global__ __launch_bounds__(256) void segb_kernel(
    const int* __restrict__ dst, int E,
    int* __restrict__ sstart, int* __restrict__ send)
{
  int e = blockIdx.x * 256 + threadIdx.x;
  if (e >= E) return;
  int d = dst[e];
  if (e == 0 || dst[e - 1] != d) sstart[d] = e;
  if (e == E - 1 || dst[e + 1] != d) send[d] = e + 1;
}

// ---------------- gemm1: dual-grid bf16 MFMA, both operands LDS (swizzled) ----------------
__global__ __launch_bounds__(256, 3) void mfma1_dual(
    int split,
    const float* __restrict__ Aa, const unsigned short* __restrict__ Wta, int Ma,
    unsigned short* __restrict__ Ca,
    const float* __restrict__ a_sa, const float* __restrict__ a_na,
    float* __restrict__ as_oa, float* __restrict__ an_oa, const unsigned char* __restrict__ fla,
    const float* __restrict__ Ab, const unsigned short* __restrict__ Wtb, int Mb,
    unsigned short* __restrict__ Cb,
    const float* __restrict__ a_sb, const float* __restrict__ a_nb,
    float* __restrict__ as_ob, float* __restrict__ an_ob, const unsigned char* __restrict__ flb)
{
  const bool sB = (int)blockIdx.x >= split;
  const float* A = sB ? Ab : Aa;
  const unsigned short* Wt = sB ? Wtb : Wta;
  const int M = sB ? Mb : Ma;
  unsigned short* C = sB ? Cb : Ca;
  const float* a_s = sB ? a_sb : a_sa;  const float* a_n = sB ? a_nb : a_na;
  float* as_o = sB ? as_ob : as_oa;     float* an_o = sB ? an_ob : an_oa;
  const unsigned char* fl = sB ? flb : fla;
  const int bid = sB ? ((int)blockIdx.x - split) : (int)blockIdx.x;

  __shared__ unsigned short sW[16384];   // 32KB
  __shared__ unsigned short sA[8192];    // 16KB
  __shared__ float pp[4][64][2];         // 2KB

  const int t = threadIdx.x;
  const int w = t >> 6, l = t & 63;
  const int lr = l & 15, lk = l >> 4;
  const int row0 = bid * 64;
  char* sWc = reinterpret_cast<char*>(sW);
  char* sAc = reinterpret_cast<char*>(sA);

  #pragma unroll
  for (int q = 0; q < 8; ++q) {
    int p = t + 256 * q;
    int n = p >> 4, c16 = p & 15;
    bf16x8 v = *reinterpret_cast<const bf16x8*>(Wt + n * 128 + c16 * 8);
    *reinterpret_cast<bf16x8*>(sWc + swz(n, c16 * 16)) = v;
  }
  #pragma unroll
  for (int q = 0; q < 4; ++q) {
    int p = t + 256 * q;
    int r = p >> 4, c16 = p & 15;
    int gr = row0 + r;
    bf16x8 hv;
    if (gr < M) {
      const float4* ap = reinterpret_cast<const float4*>(A + (long)gr * KD + c16 * 8);
      float4 v0 = ap[0], v1 = ap[1];
      hv[0]=(short)f2b(v0.x); hv[1]=(short)f2b(v0.y); hv[2]=(short)f2b(v0.z); hv[3]=(short)f2b(v0.w);
      hv[4]=(short)f2b(v1.x); hv[5]=(short)f2b(v1.y); hv[6]=(short)f2b(v1.z); hv[7]=(short)f2b(v1.w);
    } else {
      #pragma unroll
      for (int j = 0; j < 8; ++j) hv[j] = 0;
    }
    *reinterpret_cast<bf16x8*>(sAc + swz(r, c16 * 16)) = hv;
  }
  __syncthreads();

  f32x4 acc[4][2];
  #pragma unroll
  for (int i = 0; i < 4; ++i)
    #pragma unroll
    for (int tt = 0; tt < 2; ++tt) acc[i][tt] = (f32x4){0.f, 0.f, 0.f, 0.f};

  #pragma unroll
  for (int kc = 0; kc < 4; ++kc) {
    const int kb = (kc * 32 + lk * 8) * 2;
    bf16x8 af[4];
    #pragma unroll
    for (int i = 0; i < 4; ++i)
      af[i] = *reinterpret_cast<const bf16x8*>(sAc + swz(i * 16 + lr, kb));
    #pragma unroll
    for (int tt = 0; tt < 2; ++tt) {
      int n = (w * 2 + tt) * 16 + lr;
      bf16x8 bfr = *reinterpret_cast<const bf16x8*>(sWc + swz(n, kb));
      #pragma unroll
      for (int i = 0; i < 4; ++i)
        acc[i][tt] = __builtin_amdgcn_mfma_f32_16x16x32_bf16(af[i], bfr, acc[i][tt], 0, 0, 0);
    }
  }

  float asv[2], anv[2];
  #pragma unroll
  for (int tt = 0; tt < 2; ++tt) {
    int col = (w * 2 + tt) * 16 + lr;
    asv[tt] = a_s[col]; anv[tt] = a_n[col];
  }
  #pragma unroll
  for (int i = 0; i < 4; ++i) {
    #pragma unroll
    for (int r = 0; r < 4; ++r) {
      float ds = acc[i][0][r] * asv[0] + acc[i][1][r] * asv[1];
      float dn = acc[i][0][r] * anv[0] + acc[i][1][r] * anv[1];
      #pragma unroll
      for (int o = 1; o < 16; o <<= 1) { ds += __shfl_xor(ds, o, 64); dn += __shfl_xor(dn, o, 64); }
      if (lr == 0) {
        int row = i * 16 + lk * 4 + r;
        pp[w][row][0] = ds; pp[w][row][1] = dn;
      }
    }
  }
  #pragma unroll
  for (int i = 0; i < 4; ++i) {
    #pragma unroll
    for (int r = 0; r < 4; ++r) {
      int gr = row0 + i * 16 + lk * 4 + r;
      if (gr >= M) continue;
      #pragma unroll
      for (int tt = 0; tt < 2; ++tt) {
        int col = (w * 2 + tt) * 16 + lr;
        C[(long)gr * 128 + col] = f2b(acc[i][tt][r]);
      }
    }
  }
  __syncthreads();
  if (t < 64) {
    int gr = row0 + t;
    if (gr < M) {
      float ds = pp[0][t][0] + pp[1][t][0] + pp[2][t][0] + pp[3][t][0];
      float dn = pp[0][t][1] + pp[1][t][1] + pp[2][t][1] + pp[3][t][1];
      as_o[gr] = fl[gr] ? ds : NANF;
      an_o[gr] = dn;
    }
  }
}

// ---------------- gemm2: dual-grid bf16 MFMA, 2 accumulate passes, gathered A ----------------
__global__ __launch_bounds__(256, 3) void mfma2_dual(
    int split,
    const float* __restrict__ A1a, const unsigned short* __restrict__ W1ta,
    const float* __restrict__ A2a, const unsigned short* __restrict__ W2ta,
    const float* __restrict__ biasa, const int* __restrict__ aidxa,
    const int* __restrict__ map1a, int Ma, float* __restrict__ Ca,
    const float* __restrict__ A1b, const unsigned short* __restrict__ W1tb,
    const float* __restrict__ A2b, const unsigned short* __restrict__ W2tb,
    const float* __restrict__ biasb, const int* __restrict__ aidxb,
    const int* __restrict__ map1b, int Mb, float* __restrict__ Cb)
{
  const bool sB = (int)blockIdx.x >= split;
  const float* A1 = sB ? A1b : A1a;  const unsigned short* W1t = sB ? W1tb : W1ta;
  const float* A2 = sB ? A2b : A2a;  const unsigned short* W2t = sB ? W2tb : W2ta;
  const float* bias = sB ? biasb : biasa;
  const int* aidx = sB ? aidxb : aidxa;  const int* map1 = sB ? map1b : map1a;
  const int M = sB ? Mb : Ma;  float* C = sB ? Cb : Ca;
  const int bid = sB ? ((int)blockIdx.x - split) : (int)blockIdx.x;

  __shared__ unsigned short sW[16384];   // 32KB
  __shared__ unsigned short sA[8192];    // 16KB

  const int t = threadIdx.x;
  const int w = t >> 6, l = t & 63;
  const int lr = l & 15, lk = l >> 4;
  const int row0 = bid * 64;
  char* sWc = reinterpret_cast<char*>(sW);
  char* sAc = reinterpret_cast<char*>(sA);

  f32x4 acc[4][2];
  #pragma unroll
  for (int i = 0; i < 4; ++i)
    #pragma unroll
    for (int tt = 0; tt < 2; ++tt) acc[i][tt] = (f32x4){0.f, 0.f, 0.f, 0.f};

  #pragma unroll
  for (int pass = 0; pass < 2; ++pass) {
    const float* Am = pass ? A2 : A1;
    const unsigned short* Wt = pass ? W2t : W1t;
    if (pass) __syncthreads();
    #pragma unroll
    for (int q = 0; q < 8; ++q) {
      int p = t + 256 * q;
      int n = p >> 4, c16 = p & 15;
      bf16x8 v = *reinterpret_cast<const bf16x8*>(Wt + n * 128 + c16 * 8);
      *reinterpret_cast<bf16x8*>(sWc + swz(n, c16 * 16)) = v;
    }
    #pragma unroll
    for (int q = 0; q < 4; ++q) {
      int p = t + 256 * q;
      int r = p >> 4, c16 = p & 15;
      int gr = row0 + r;
      bf16x8 hv;
      if (gr < M) {
        long grow = (long)aidx[gr];
        if (pass == 0) grow = map1[grow];
        const float4* ap = reinterpret_cast<const float4*>(Am + grow * KD + c16 * 8);
        float4 v0 = ap[0], v1 = ap[1];
        hv[0]=(short)f2b(v0.x); hv[1]=(short)f2b(v0.y); hv[2]=(short)f2b(v0.z); hv[3]=(short)f2b(v0.w);
        hv[4]=(short)f2b(v1.x); hv[5]=(short)f2b(v1.y); hv[6]=(short)f2b(v1.z); hv[7]=(short)f2b(v1.w);
      } else {
        #pragma unroll
        for (int j = 0; j < 8; ++j) hv[j] = 0;
      }
      *reinterpret_cast<bf16x8*>(sAc + swz(r, c16 * 16)) = hv;
    }
    __syncthreads();
    #pragma unroll
    for (int kc = 0; kc < 4; ++kc) {
      const int kb = (kc * 32 + lk * 8) * 2;
      bf16x8 af[4];
      #pragma unroll
      for (int i = 0; i < 4; ++i)
        af[i] = *reinterpret_cast<const bf16x8*>(sAc + swz(i * 16 + lr, kb));
      #pragma unroll
      for (int tt = 0; tt < 2; ++tt) {
        int n = (w * 2 + tt) * 16 + lr;
        bf16x8 bfr = *reinterpret_cast<const bf16x8*>(sWc + swz(n, kb));
        #pragma unroll
        for (int i = 0; i < 4; ++i)
          acc[i][tt] = __builtin_amdgcn_mfma_f32_16x16x32_bf16(af[i], bfr, acc[i][tt], 0, 0, 0);
      }
    }
  }
  float bv[2];
  #pragma unroll
  for (int tt = 0; tt < 2; ++tt) bv[tt] = bias[(w * 2 + tt) * 16 + lr];
  #pragma unroll
  for (int i = 0; i < 4; ++i) {
    #pragma unroll
    for (int r = 0; r < 4; ++r) {
      int gr = row0 + i * 16 + lk * 4 + r;
      if (gr >= M) continue;
      #pragma unroll
      for (int tt = 0; tt < 2; ++tt) {
        int col = (w * 2 + tt) * 16 + lr;
        float v = acc[i][tt][r] + bv[tt];
        v = (v > 0.f) ? v : (__expf(v) - 1.f);
        C[(long)gr * 128 + col] = v;
      }
    }
  }
}

// ---------------- gemm3: dual-grid fp32, BM=64 NC=64, elu + gathered residual ----------
template<int BM, int NC>
__global__ __launch_bounds__(256, 3) void gemm3_dual(
    int split,
    const float* __restrict__ A1a, const float* __restrict__ W1a,
    const float* __restrict__ Resa, const int* __restrict__ ridxa, int Ma,
    float* __restrict__ Ca,
    const float* __restrict__ A1b, const float* __restrict__ W1b,
    const float* __restrict__ Resb, const int* __restrict__ ridxb, int Mb,
    float* __restrict__ Cb)
{
  const bool sB = (int)blockIdx.x >= split;
  const float* A1 = sB ? A1b : A1a;  const float* W1 = sB ? W1b : W1a;
  const float* Res = sB ? Resb : Resa;
  const int* ridx = sB ? ridxb : ridxa;
  const int M = sB ? Mb : Ma;  float* C = sB ? Cb : Ca;
  const int bid = sB ? ((int)blockIdx.x - split) : (int)blockIdx.x;

  constexpr int RT = BM / 16;
  constexpr int CW = NC / 16;
  constexpr int KB = 64;
  constexpr int CPP = KD / KB;
  constexpr int F4PR = KB / 4;
  constexpr int NAF4 = BM * KB / 4 / 256;
  constexpr int NWF4 = KB * NC / 4 / 256;
  __shared__ float sA[BM][KB + 4];
  __shared__ float sW[KB][NC];
  const int t  = threadIdx.x;
  const int ty = t >> 4, tx = t & 15;
  const int row0 = bid * BM;

  float acc[RT][CW];
  #pragma unroll
  for (int i = 0; i < RT; ++i)
    #pragma unroll
    for (int j = 0; j < CW; ++j) acc[i][j] = 0.f;

  for (int cc = 0; cc < CPP; ++cc) {
    const int kc = cc;
    if (cc) __syncthreads();
    {
      const float4* Wp = reinterpret_cast<const float4*>(W1) + (long)kc * (KB * NC / 4);
      #pragma unroll
      for (int q = 0; q < NWF4; ++q)
        reinterpret_cast<float4*>(&sW[0][0])[t + 256 * q] = Wp[t + 256 * q];
    }
    #pragma unroll
    for (int q = 0; q < NAF4; ++q) {
      int p  = t + 256 * q;
      int r  = p / F4PR, c4 = p % F4PR;
      float4 v = make_float4(0.f, 0.f, 0.f, 0.f);
      int gr = row0 + r;
      if (gr < M) {
        v = reinterpret_cast<const float4*>(A1 + (long)gr * KD)[kc * F4PR + c4];
      }
      *reinterpret_cast<float4*>(&sA[r][c4 * 4]) = v;
    }
    __syncthreads();
    #pragma unroll 4
    for (int k4 = 0; k4 < KB; k4 += 4) {
      float4 a4[RT];
      #pragma unroll
      for (int i = 0; i < RT; ++i)
        a4[i] = *reinterpret_cast<const float4*>(&sA[ty + 16 * i][k4]);
      #pragma unroll
      for (int kk = 0; kk < 4; ++kk) {
        float wv[CW];
        #pragma unroll
        for (int h = 0; h < CW / 4; ++h) {
          float4 w4 = *reinterpret_cast<const float4*>(&sW[k4 + kk][tx * 4 + 64 * h]);
          wv[h*4+0] = w4.x; wv[h*4+1] = w4.y; wv[h*4+2] = w4.z; wv[h*4+3] = w4.w;
        }
        #pragma unroll
        for (int i = 0; i < RT; ++i) {
          float a = (kk == 0) ? a4[i].x : (kk == 1) ? a4[i].y : (kk == 2) ? a4[i].z : a4[i].w;
          #pragma unroll
          for (int j = 0; j < CW; ++j)
            acc[i][j] = fmaf(a, wv[j], acc[i][j]);
        }
      }
    }
  }
  #pragma unroll
  for (int i = 0; i < RT; ++i) {
    int gr = row0 + ty + 16 * i;
    if (gr >= M) continue;
    long rrow = (long)ridx[gr];
    #pragma unroll
    for (int h = 0; h < CW / 4; ++h) {
      int c = tx * 4 + 64 * h;
      float4 v = make_float4(acc[i][h*4+0], acc[i][h*4+1], acc[i][h*4+2], acc[i][h*4+3]);
      v.x = (v.x > 0.f) ? v.x : (__expf(v.x) - 1.f);
      v.y = (v.y > 0.f) ? v.y : (__expf(v.y) - 1.f);
      v.z = (v.z > 0.f) ? v.z : (__expf(v.z) - 1.f);
      v.w = (v.w > 0.f) ? v.w : (__expf(v.w) - 1.f);
      float4 rv = *reinterpret_cast<const float4*>(Res + rrow * NC + c);
      v.x += rv.x; v.y += rv.y; v.z += rv.z; v.w += rv.w;
      *reinterpret_cast<float4*>(C + (long)gr * NC + c) = v;
    }
  }
}

// ---------------- needed-dst flags: byte array + 1-bit mask (L1-resident gate) ----------
__global__ void flags_kernel(const int* __restrict__ ui, const int* __restrict__ ii, int B,
                             unsigned char* __restrict__ nfu, unsigned char* __restrict__ nfb,
                             unsigned* __restrict__ mku, unsigned* __restrict__ mkb)
{
  int i = blockIdx.x * blockDim.x + threadIdx.x;
  if (i < B) {
    int u = ui[i], v = ii[i];
    nfu[u] = 1; nfb[v] = 1;
    atomicOr(&mku[u >> 5], 1u << (u & 31));
    atomicOr(&mkb[v >> 5], 1u << (v & 31));
  }
}

// ---------------- dual pass 1: 16 edges/thread; bitmask gate; item rel from sorted segs ----
__global__ __launch_bounds__(256) void edge_prep_dual(
    int split,
    const int* __restrict__ srcA, const int* __restrict__ dstA,
    const float* __restrict__ asA, const float* __restrict__ anA,
    const unsigned* __restrict__ mkA, const int* __restrict__ ssA,
    int* __restrict__ degA, int4* __restrict__ cmpA, int* __restrict__ bcA, int EA,
    const int* __restrict__ srcB, const int* __restrict__ dstB,
    const float* __restrict__ asB, const float* __restrict__ anB,
    const unsigned* __restrict__ mkB, const int* __restrict__ ssB,
    const float* __restrict__ gc, const float* __restrict__ omega,
    int* __restrict__ degB, int4* __restrict__ cmpB, int* __restrict__ bcB, int EB_)
{
  const bool sB = (int)blockIdx.x >= split;
  const int* src = sB ? srcB : srcA;  const int* dst = sB ? dstB : dstA;
  const float* as_ = sB ? asB : asA;  const float* an_ = sB ? anB : anA;
  const unsigned* mk = sB ? mkB : mkA;
  const int* ss = sB ? ssB : ssA;      // sorted-dst segment starts (item side only)
  int* deg = sB ? degB : degA;  int4* cmp = sB ? cmpB : cmpA;
  int* blkcnt = sB ? bcB : bcA;
  const int E = sB ? EB_ : EA;
  const float* gcp = sB ? gc : nullptr;
  const int bid = sB ? ((int)blockIdx.x - split) : (int)blockIdx.x;

  __shared__ int lcnt;
  if (threadIdx.x == 0) lcnt = 0;
  __syncthreads();
  const int lane = threadIdx.x & 63;
  const long base = (long)bid * 4096;
  const int e0 = (int)base + threadIdx.x * 16;

  int d[16], s[16];
  bool act[16];
  const bool full = (e0 + 15 < E);
  if (full) {
    #pragma unroll
    for (int q = 0; q < 4; ++q) {
      int4 d4 = *reinterpret_cast<const int4*>(dst + e0 + q * 4);
      int4 s4 = *reinterpret_cast<const int4*>(src + e0 + q * 4);
      d[q*4+0]=d4.x; d[q*4+1]=d4.y; d[q*4+2]=d4.z; d[q*4+3]=d4.w;
      s[q*4+0]=s4.x; s[q*4+1]=s4.y; s[q*4+2]=s4.z; s[q*4+3]=s4.w;
    }
    #pragma unroll
    for (int j = 0; j < 16; ++j) act[j] = true;
  } else {
    #pragma unroll
    for (int j = 0; j < 16; ++j) {
      act[j] = (e0 + j < E);
      d[j] = act[j] ? dst[e0 + j] : 0;
      s[j] = act[j] ? src[e0 + j] : 0;
    }
  }
  // 1-bit mask gate: random reads into a <13KB L1-resident table
  unsigned mw[16];
  #pragma unroll
  for (int j = 0; j < 16; ++j) mw[j] = mk[d[j] >> 5];
  #pragma unroll
  for (int j = 0; j < 16; ++j) act[j] = act[j] && ((mw[j] >> (d[j] & 31)) & 1u);

  float uw[16];
  if (gcp) {
    float o0 = omega[0], o1 = omega[1], o2 = omega[2];
    if (full) {
      float g[48];
      const float4* gp = reinterpret_cast<const float4*>(gcp + (long)e0 * 3);
      #pragma unroll
      for (int q = 0; q < 12; ++q) *reinterpret_cast<float4*>(&g[q*4]) = gp[q];
      #pragma unroll
      for (int j = 0; j < 16; ++j) uw[j] = g[j*3+0]*o0 + g[j*3+1]*o1 + g[j*3+2]*o2;
    } else {
      #pragma unroll
      for (int j = 0; j < 16; ++j) {
        uw[j] = 0.f;
        if (act[j]) {
          long e = e0 + j;
          uw[j] = gcp[e*3+0]*o0 + gcp[e*3+1]*o1 + gcp[e*3+2]*o2;
        }
      }
    }
  }
  // gated L2 gathers: only active edges touch as_/an_
  float vas[16], van[16];
  #pragma unroll
  for (int j = 0; j < 16; ++j) vas[j] = act[j] ? as_[d[j]] : 0.f;
  #pragma unroll
  for (int j = 0; j < 16; ++j) van[j] = act[j] ? an_[s[j]] : 0.f;
  // sorted-dst rel: gather segment start (cacheline-local since dst sorted)
  int ssv[16];
  if (ss) {
    #pragma unroll
    for (int j = 0; j < 16; ++j) ssv[j] = act[j] ? ss[d[j]] : 0;
  }
  float sc[16];
  #pragma unroll
  for (int j = 0; j < 16; ++j) {
    float v = vas[j] + van[j];
    if (gcp) v *= uw[j];
    v = (v >= 0.f) ? v : 0.2f * v;       // leaky_relu 0.2
    sc[j] = __expf(v);
  }
  int tot = 0;
  #pragma unroll
  for (int j = 0; j < 16; ++j) tot += __popcll(__ballot(act[j]));
  int wb = 0;
  if (lane == 0) wb = atomicAdd(&lcnt, tot);
  wb = __shfl(wb, 0, 64);
  #pragma unroll
  for (int j = 0; j < 16; ++j) {
    unsigned long long m = __ballot(act[j]);
    if (act[j]) {
      int pref = __popcll(m & ((1ull << lane) - 1ull));
      int rel = ss ? (e0 + j - ssv[j]) : atomicAdd(&deg[d[j]], 1);
      cmp[base + wb + pref] = make_int4(s[j], d[j], rel, __float_as_int(sc[j]));
    }
    wb += __popcll(m);
  }
  __syncthreads();
  if (threadIdx.x == 0) blkcnt[bid] = lcnt;
}

// ---------------- dual pass 2: 4 node-groups per wave, ONE atomic pair per wave ----------
// Per-wave logic identical to the proven round-24 form; batched x4 via register arrays.
__global__ __launch_bounds__(256) void offset_dual(
    int split,
    const unsigned char* __restrict__ flA, int* __restrict__ degA,
    int* __restrict__ offsA, int* __restrict__ dlA, int* __restrict__ g2cA,
    int* __restrict__ cntA, int NA,
    const unsigned char* __restrict__ flB, int* __restrict__ degB,
    const int* __restrict__ sstartB, const int* __restrict__ sendB,
    int* __restrict__ offsB, int* __restrict__ dlB, int* __restrict__ g2cB,
    int* __restrict__ cntB, int NB)
{
  const bool sB = (int)blockIdx.x >= split;
  const unsigned char* flag = sB ? flB : flA;
  int* deg = sB ? degB : degA;
  int* offs = sB ? offsB : offsA;  int* dlist = sB ? dlB : dlA;
  int* g2c = sB ? g2cB : g2cA;     int* cnt = sB ? cntB : cntA;
  const int N = sB ? NB : NA;
  const int bid = sB ? ((int)blockIdx.x - split) : (int)blockIdx.x;
  const int lane = threadIdx.x & 63;

  int idx[4], dg[4], exc[4], prf[4], nwq[4], tq[4];
  bool av[4];
  int wn = 0, wt = 0;
  #pragma unroll
  for (int q = 0; q < 4; ++q) {
    int i = bid * 1024 + q * 256 + (int)threadIdx.x;
    idx[q] = i;
    bool a = (i < N) && flag[i];
    int dgv = 0;
    if (a) {
      if (sB) { dgv = sendB[i] - sstartB[i]; deg[i] = dgv; }
      else dgv = deg[i];
    }
    av[q] = a; dg[q] = dgv;
    unsigned long long m = __ballot(a);
    nwq[q] = __popcll(m);
    prf[q] = __popcll(m & ((1ull << lane) - 1ull));
    int inc = dgv;
    #pragma unroll
    for (int o = 1; o < 64; o <<= 1) {
      int v = __shfl_up(inc, o, 64);
      if (lane >= o) inc += v;
    }
    tq[q] = __shfl(inc, 63, 64);
    exc[q] = inc - dgv;
    wn += nwq[q]; wt += tq[q];
  }
  int baseL = 0, baseE = 0;
  if (lane == 0) {
    baseL = wn ? atomicAdd(&cnt[1], wn) : 0;
    baseE = wt ? atomicAdd(&cnt[0], wt) : 0;
  }
  baseL = __shfl(baseL, 0, 64);
  baseE = __shfl(baseE, 0, 64);
  int runN = 0, runE = 0;
  #pragma unroll
  for (int q = 0; q < 4; ++q) {
    if (av[q]) {
      int i = idx[q];
      int l = baseL + runN + prf[q];
      g2c[i] = l;
      dlist[l] = i;
      if (dg[q] > 0) offs[i] = baseE + runE + exc[q];
    }
    runN += nwq[q]; runE += tq[q];
  }
}

// ---------------- dual pass 3: place packed (src,p) — no atomics ----------
__global__ __launch_bounds__(256) void place_dual(
    int split,
    const int4* __restrict__ cmpA, const int* __restrict__ bcA,
    const int* __restrict__ offsA, int2* __restrict__ elA,
    const int4* __restrict__ cmpB, const int* __restrict__ bcB,
    const int* __restrict__ offsB, int2* __restrict__ elB)
{
  const bool sB = (int)blockIdx.x >= split;
  const int4* cmp = sB ? cmpB : cmpA;
  const int* blkcnt = sB ? bcB : bcA;
  const int* offs = sB ? offsB : offsA;
  int2* eline = sB ? elB : elA;
  const int bid = sB ? ((int)blockIdx.x - split) : (int)blockIdx.x;

  int nb = blkcnt[bid];
  const long base = (long)bid * 4096;
  for (int k = threadIdx.x; k < nb; k += 256) {
    int4 c = cmp[base + k];
    int pos = offs[c.y] + c.z;
    eline[pos] = make_int2(c.x, c.w);
  }
}

// ---------------- dual wave-per-dst softmax + aggregation (bf16 H1 reads) ----------
__global__ __launch_bounds__(256) void aggr_dual(
    int split,
    const int* __restrict__ dlA, const int* __restrict__ cntA,
    const int* __restrict__ offsA, const int* __restrict__ degA,
    const int2* __restrict__ elA, const unsigned short* __restrict__ H1A, float* __restrict__ HoA,
    const int* __restrict__ dlB, const int* __restrict__ cntB,
    const int* __restrict__ offsB, const int* __restrict__ degB,
    const int2* __restrict__ elB, const unsigned short* __restrict__ H1B, float* __restrict__ HoB)
{
  const bool sB = (int)blockIdx.x >= split;
  const int* dlist = sB ? dlB : dlA;  const int* cnt = sB ? cntB : cntA;
  const int* offs = sB ? offsB : offsA;  const int* deg = sB ? degB : degA;
  const int2* eline = sB ? elB : elA;
  const unsigned short* H1 = sB ? H1B : H1A;  float* Houtc = sB ? HoB : HoA;
  const int bid = sB ? ((int)blockIdx.x - split) : (int)blockIdx.x;

  int wid  = bid * 4 + (int)(threadIdx.x >> 6);
  int lane = threadIdx.x & 63;
  if (wid >= cnt[1]) return;
  int d = dlist[wid];
  int n = deg[d];
  float2* op = reinterpret_cast<float2*>(Houtc + (long)wid * KD) + lane;
  if (n == 0) { *op = make_float2(0.f, 0.f); return; }
  int st = offs[d];
  float ssum = 0.f;
  for (int i = lane; i < n; i += 64) ssum += __int_as_float(eline[st + i].y);
  #pragma unroll
  for (int o = 32; o; o >>= 1) ssum += __shfl_xor(ssum, o, 64);
  float inv = 1.f / ssum;
  float ax = 0.f, ay = 0.f;
  int i = 0;
  for (; i + 4 <= n; i += 4) {
    int2 e0 = eline[st + i], e1 = eline[st + i + 1], e2 = eline[st + i + 2], e3 = eline[st + i + 3];
    float a0 = __int_as_float(e0.y);
    float a1 = __int_as_float(e1.y);
    float a2 = __int_as_float(e2.y);
    float a3 = __int_as_float(e3.y);
    unsigned u0 = *reinterpret_cast<const unsigned*>(H1 + (long)e0.x * KD + lane * 2);
    unsigned u1 = *reinterpret_cast<const unsigned*>(H1 + (long)e1.x * KD + lane * 2);
    unsigned u2 = *reinterpret_cast<const unsigned*>(H1 + (long)e2.x * KD + lane * 2);
    unsigned u3 = *reinterpret_cast<const unsigned*>(H1 + (long)e3.x * KD + lane * 2);
    ax = fmaf(__uint_as_float(u0 << 16), a0, ax); ay = fmaf(__uint_as_float(u0 & 0xffff0000u), a0, ay);
    ax = fmaf(__uint_as_float(u1 << 16), a1, ax); ay = fmaf(__uint_as_float(u1 & 0xffff0000u), a1, ay);
    ax = fmaf(__uint_as_float(u2 << 16), a2, ax); ay = fmaf(__uint_as_float(u2 & 0xffff0000u), a2, ay);
    ax = fmaf(__uint_as_float(u3 << 16), a3, ax); ay = fmaf(__uint_as_float(u3 & 0xffff0000u), a3, ay);
  }
  for (; i < n; ++i) {
    int2 e0 = eline[st + i];
    float a0 = __int_as_float(e0.y);
    unsigned u0 = *reinterpret_cast<const unsigned*>(H1 + (long)e0.x * KD + lane * 2);
    ax = fmaf(__uint_as_float(u0 << 16), a0, ax); ay = fmaf(__uint_as_float(u0 & 0xffff0000u), a0, ay);
  }
  *op = make_float2(ax * inv, ay * inv);
}

// ---------------- final: dot + biases + sigmoid -------------
__global__ __launch_bounds__(256) void final_kernel(
    const float* __restrict__ Ug, const float* __restrict__ Bg,
    const int* __restrict__ ui, const int* __restrict__ ii,
    const float* __restrict__ bias_u, const float* __restrict__ bias_b,
    const float* __restrict__ bx, float* __restrict__ out, int B)
{
  int wid  = (int)((blockIdx.x * 256 + threadIdx.x) >> 6);
  int lane = threadIdx.x & 63;
  if (wid >= B) return;
  float v = Ug[(long)wid * 64 + lane] * Bg[(long)wid * 64 + lane];
  #pragma unroll
  for (int o = 32; o > 0; o >>= 1) v += __shfl_xor(v, o, 64);
  if (lane == 0) {
    float raw = v + bias_u[ui[wid]] + bias_b[ii[wid]] + bx[0];
    out[wid] = 4.f / (1.f + __expf(-raw)) + 1.f;
  }
}

extern "C" void kernel_launch(void* const* d_in, const int* in_sizes, int n_in,
                              void* d_out, int out_size, void* d_ws, size_t ws_size,
                              hipStream_t stream)
{
  const int*   ui    = (const int*)  d_in[0];
  const int*   ii    = (const int*)  d_in[1];
  const float* S_u   = (const float*)d_in[2];
  const float* S_b   = (const float*)d_in[3];
  const int*   eu    = (const int*)  d_in[4];
  const int*   eb    = (const int*)  d_in[5];
  const float* gc    = (const float*)d_in[6];
  const float* W1_u  = (const float*)d_in[7];
  const float* a_s_u = (const float*)d_in[8];
  const float* a_n_u = (const float*)d_in[9];
  const float* W1_b  = (const float*)d_in[10];
  const float* a_s_b = (const float*)d_in[11];
  const float* a_n_b = (const float*)d_in[12];
  const float* omega = (const float*)d_in[13];
  const float* W_u2  = (const float*)d_in[14];
  const float* W_us2w= (const float*)d_in[15];
  const float* W_us2b= (const float*)d_in[16];
  const float* W_b2  = (const float*)d_in[17];
  const float* W_bs2w= (const float*)d_in[18];
  const float* W_bs2b= (const float*)d_in[19];
  const float* W_u3  = (const float*)d_in[20];
  const float* W_b3  = (const float*)d_in[21];
  const float* H_u4  = (const float*)d_in[22];
  const float* H_b4  = (const float*)d_in[23];
  const float* bias_u= (const float*)d_in[24];
  const float* bias_b= (const float*)d_in[25];
  const float* b_x   = (const float*)d_in[26];
  float* out = (float*)d_out;

  const int B  = in_sizes[0];
  const int NU = in_sizes[2] / KD;
  const int NI = in_sizes[3] / KD;
  const int EU = in_sizes[4] / 2;
  const int EB = in_sizes[5] / 2;
  const int GPU_ = (EU + 4095) / 4096;
  const int GPB_ = (EB + 4095) / 4096;
  const int G1U = (NU + 63) / 64, G1I = (NI + 63) / 64;
  const int GO4U = (NU + 1023) / 1024, GO4I = (NI + 1023) / 1024;   // offset: 1024 nodes/block
  const int GAG = (B + 3) / 4;
  const int GB  = (B + 63) / 64;

  char* w = (char*)d_ws;
  auto alloc = [&](size_t bytes) -> void* {
    void* r = (void*)w;
    w += (bytes + 255) & ~(size_t)255;
    return r;
  };
  // ---- zero-initialized region (one small memset per call) ----
  int* deg_u = (int*)alloc((size_t)NU * 4);
  int* deg_b = (int*)alloc((size_t)NI * 4);
  unsigned char* nfu = (unsigned char*)alloc((size_t)NU);
  unsigned char* nfb = (unsigned char*)alloc((size_t)NI);
  unsigned* mku = (unsigned*)alloc((size_t)((NU + 31) / 32) * 4);
  unsigned* mkb = (unsigned*)alloc((size_t)((NI + 31) / 32) * 4);
  int* sst_b = (int*)alloc((size_t)NI * 4);
  int* snd_b = (int*)alloc((size_t)NI * 4);
  int* cnt   = (int*)alloc(16 * 4);
  size_t zbytes = (size_t)(w - (char*)d_ws);
  // ---- scratch ----
  unsigned short* wt = (unsigned short*)alloc((size_t)6 * 16384 * 2);
  int*   offs_u = (int*)  alloc((size_t)NU * 4);
  int*   offs_b = (int*)  alloc((size_t)NI * 4);
  int*   g2c_u  = (int*)  alloc((size_t)NU * 4);
  int*   g2c_b  = (int*)  alloc((size_t)NI * 4);
  int*   dl_u   = (int*)  alloc((size_t)B * 4);
  int*   dl_b   = (int*)  alloc((size_t)B * 4);
  int*   bc_u   = (int*)  alloc((size_t)GPU_ * 4);
  int*   bc_b   = (int*)  alloc((size_t)GPB_ * 4);
  int4*  cmp_u  = (int4*) alloc((size_t)GPU_ * 4096 * 16);
  int4*  cmp_b  = (int4*) alloc((size_t)GPB_ * 4096 * 16);
  int2*  el_u   = (int2*) alloc((size_t)EU * 8);
  int2*  el_b   = (int2*) alloc((size_t)EB * 8);
  unsigned short* H1u = (unsigned short*)alloc((size_t)NU * KD * 2);
  unsigned short* H1b = (unsigned short*)alloc((size_t)NI * KD * 2);
  float* Hu2c = (float*)alloc((size_t)B * KD * 4);
  float* Hb2c = (float*)alloc((size_t)B * KD * 4);
  float* asu  = (float*)alloc((size_t)NU * 4);
  float* anu  = (float*)alloc((size_t)NU * 4);
  float* asb  = (float*)alloc((size_t)NI * 4);
  float* anb  = (float*)alloc((size_t)NI * 4);
  float* Hu3g = (float*)alloc((size_t)B * KD * 4);
  float* Hb3g = (float*)alloc((size_t)B * KD * 4);
  float* Ug   = (float*)alloc((size_t)B * 64 * 4);
  float* Bg   = (float*)alloc((size_t)B * 64 * 4);
  (void)ws_size; (void)n_in; (void)out_size;

  hipMemsetAsync(d_ws, 0, zbytes, stream);

  wsplit6<<<384, 256, 0, stream>>>(W1_u, W1_b, W_u2, W_us2w, W_b2, W_bs2w, wt);
  flags_kernel<<<(B + 255) / 256, 256, 0, stream>>>(ui, ii, B, nfu, nfb, mku, mkb);
  segb_kernel<<<(EB + 255) / 256, 256, 0, stream>>>(eb + EB, EB, sst_b, snd_b);

  // H1 = S @ W1: bf16 MFMA, fused proj + NaN sentinel
  mfma1_dual<<<G1U + G1I, 256, 0, stream>>>(
      G1U,
      S_u, wt + 0 * 16384, NU, H1u, a_s_u, a_n_u, asu, anu, nfu,
      S_b, wt + 1 * 16384, NI, H1b, a_s_b, a_n_b, asb, anb, nfb);

  edge_prep_dual<<<GPU_ + GPB_, 256, 0, stream>>>(
      GPU_,
      eu, eu + EU, asu, anu, mku, nullptr, deg_u, cmp_u, bc_u, EU,
      eb, eb + EB, asb, anb, mkb, sst_b, gc, omega, deg_b, cmp_b, bc_b, EB);

  offset_dual<<<GO4U + GO4I, 256, 0, stream>>>(
      GO4U,
      nfu, deg_u, offs_u, dl_u, g2c_u, cnt + 0, NU,
      nfb, deg_b, sst_b, snd_b, offs_b, dl_b, g2c_b, cnt + 2, NI);

  place_dual<<<GPU_ + GPB_, 256, 0, stream>>>(
      GPU_,
      cmp_u, bc_u, offs_u, el_u,
      cmp_b, bc_b, offs_b, el_b);

  aggr_dual<<<GAG * 2, 256, 0, stream>>>(
      GAG,
      dl_u, cnt + 0, offs_u, deg_u, el_u, H1u, Hu2c,
      dl_b, cnt + 2, offs_b, deg_b, el_b, H1b, Hb2c);

  // H3 = elu(Hu2c[g2c[ui]]@W_u2 + S_u[ui]@W_us2w + b): bf16 MFMA, 2 passes
  mfma2_dual<<<GB * 2, 256, 0, stream>>>(
      GB,
      Hu2c, wt + 2 * 16384, S_u, wt + 3 * 16384, W_us2b, ui, g2c_u, B, Hu3g,
      Hb2c, wt + 4 * 16384, S_b, wt + 5 * 16384, W_bs2b, ii, g2c_b, B, Hb3g);

  // U = elu(H3 @ W3) + H4[idx]: fp32, NC=64 (absmax margin)
  gemm3_dual<64,64><<<GB * 2, 256, 0, stream>>>(
      GB,
      Hu3g, W_u3, H_u4, ui, B, Ug,
      Hb3g, W_b3, H_b4, ii, B, Bg);

  final_kernel<<<(B + 3) / 4, 256, 0, stream>>>(Ug, Bg, ui, ii, bias_u, bias_b, b_x, out, B);
}

// Round 27
// 191.065 us; speedup vs baseline: 1.3744x; 1.0478x over previous
//
#include <hip/hip_runtime.h>
#include <hip/hip_bf16.h>

#define KD 128
#define NANF __int_as_float(0x7fc00000)

typedef __attribute__((ext_vector_type(8))) short bf16x8;
typedef __attribute__((ext_vector_type(4))) float f32x4;

__device__ __forceinline__ unsigned short f2b(float x) {  // fp32 -> bf16 RNE
  unsigned u = __float_as_uint(x);
  return (unsigned short)((u + 0x7fffu + ((u >> 16) & 1u)) >> 16);
}
__device__ __forceinline__ int swz(int row, int kbyte) {  // LDS byte addr, G4 XOR swizzle
  return (row * 256 + kbyte) ^ ((row & 7) << 4);
}

// ---------------- one-shot: transpose+convert six 128x128 W to bf16 Wt[n][k] ----------------
__global__ __launch_bounds__(256) void wsplit6(
    const float* __restrict__ w0, const float* __restrict__ w1,
    const float* __restrict__ w2, const float* __restrict__ w3,
    const float* __restrict__ w4, const float* __restrict__ w5,
    unsigned short* __restrict__ oh)
{
  int m = blockIdx.x >> 6;
  int idx = (blockIdx.x & 63) * 256 + threadIdx.x;   // n*128 + k
  const float* ws;
  switch (m) { case 0: ws = w0; break; case 1: ws = w1; break; case 2: ws = w2; break;
               case 3: ws = w3; break; case 4: ws = w4; break; default: ws = w5; }
  int n = idx >> 7, k = idx & 127;
  oh[(long)m * 16384 + idx] = f2b(ws[k * 128 + n]);
}

// ---------------- item-graph segment boundaries (dst is sorted ascending) ----------------
__global__ __launch_bounds__(256) void segb_kernel(
    const int* __restrict__ dst, int E,
    int* __restrict__ sstart, int* __restrict__ send)
{
  int e = blockIdx.x * 256 + threadIdx.x;
  if (e >= E) return;
  int d = dst[e];
  if (e == 0 || dst[e - 1] != d) sstart[d] = e;
  if (e == E - 1 || dst[e + 1] != d) send[d] = e + 1;
}

// ---------------- gemm1: dual-grid bf16 MFMA, both operands LDS (swizzled) ----------------
__global__ __launch_bounds__(256, 3) void mfma1_dual(
    int split,
    const float* __restrict__ Aa, const unsigned short* __restrict__ Wta, int Ma,
    unsigned short* __restrict__ Ca,
    const float* __restrict__ a_sa, const float* __restrict__ a_na,
    float* __restrict__ as_oa, float* __restrict__ an_oa, const unsigned char* __restrict__ fla,
    const float* __restrict__ Ab, const unsigned short* __restrict__ Wtb, int Mb,
    unsigned short* __restrict__ Cb,
    const float* __restrict__ a_sb, const float* __restrict__ a_nb,
    float* __restrict__ as_ob, float* __restrict__ an_ob, const unsigned char* __restrict__ flb)
{
  const bool sB = (int)blockIdx.x >= split;
  const float* A = sB ? Ab : Aa;
  const unsigned short* Wt = sB ? Wtb : Wta;
  const int M = sB ? Mb : Ma;
  unsigned short* C = sB ? Cb : Ca;
  const float* a_s = sB ? a_sb : a_sa;  const float* a_n = sB ? a_nb : a_na;
  float* as_o = sB ? as_ob : as_oa;     float* an_o = sB ? an_ob : an_oa;
  const unsigned char* fl = sB ? flb : fla;
  const int bid = sB ? ((int)blockIdx.x - split) : (int)blockIdx.x;

  __shared__ unsigned short sW[16384];   // 32KB
  __shared__ unsigned short sA[8192];    // 16KB
  __shared__ float pp[4][64][2];         // 2KB

  const int t = threadIdx.x;
  const int w = t >> 6, l = t & 63;
  const int lr = l & 15, lk = l >> 4;
  const int row0 = bid * 64;
  char* sWc = reinterpret_cast<char*>(sW);
  char* sAc = reinterpret_cast<char*>(sA);

  #pragma unroll
  for (int q = 0; q < 8; ++q) {
    int p = t + 256 * q;
    int n = p >> 4, c16 = p & 15;
    bf16x8 v = *reinterpret_cast<const bf16x8*>(Wt + n * 128 + c16 * 8);
    *reinterpret_cast<bf16x8*>(sWc + swz(n, c16 * 16)) = v;
  }
  #pragma unroll
  for (int q = 0; q < 4; ++q) {
    int p = t + 256 * q;
    int r = p >> 4, c16 = p & 15;
    int gr = row0 + r;
    bf16x8 hv;
    if (gr < M) {
      const float4* ap = reinterpret_cast<const float4*>(A + (long)gr * KD + c16 * 8);
      float4 v0 = ap[0], v1 = ap[1];
      hv[0]=(short)f2b(v0.x); hv[1]=(short)f2b(v0.y); hv[2]=(short)f2b(v0.z); hv[3]=(short)f2b(v0.w);
      hv[4]=(short)f2b(v1.x); hv[5]=(short)f2b(v1.y); hv[6]=(short)f2b(v1.z); hv[7]=(short)f2b(v1.w);
    } else {
      #pragma unroll
      for (int j = 0; j < 8; ++j) hv[j] = 0;
    }
    *reinterpret_cast<bf16x8*>(sAc + swz(r, c16 * 16)) = hv;
  }
  __syncthreads();

  f32x4 acc[4][2];
  #pragma unroll
  for (int i = 0; i < 4; ++i)
    #pragma unroll
    for (int tt = 0; tt < 2; ++tt) acc[i][tt] = (f32x4){0.f, 0.f, 0.f, 0.f};

  #pragma unroll
  for (int kc = 0; kc < 4; ++kc) {
    const int kb = (kc * 32 + lk * 8) * 2;
    bf16x8 af[4];
    #pragma unroll
    for (int i = 0; i < 4; ++i)
      af[i] = *reinterpret_cast<const bf16x8*>(sAc + swz(i * 16 + lr, kb));
    #pragma unroll
    for (int tt = 0; tt < 2; ++tt) {
      int n = (w * 2 + tt) * 16 + lr;
      bf16x8 bfr = *reinterpret_cast<const bf16x8*>(sWc + swz(n, kb));
      #pragma unroll
      for (int i = 0; i < 4; ++i)
        acc[i][tt] = __builtin_amdgcn_mfma_f32_16x16x32_bf16(af[i], bfr, acc[i][tt], 0, 0, 0);
    }
  }

  float asv[2], anv[2];
  #pragma unroll
  for (int tt = 0; tt < 2; ++tt) {
    int col = (w * 2 + tt) * 16 + lr;
    asv[tt] = a_s[col]; anv[tt] = a_n[col];
  }
  #pragma unroll
  for (int i = 0; i < 4; ++i) {
    #pragma unroll
    for (int r = 0; r < 4; ++r) {
      float ds = acc[i][0][r] * asv[0] + acc[i][1][r] * asv[1];
      float dn = acc[i][0][r] * anv[0] + acc[i][1][r] * anv[1];
      #pragma unroll
      for (int o = 1; o < 16; o <<= 1) { ds += __shfl_xor(ds, o, 64); dn += __shfl_xor(dn, o, 64); }
      if (lr == 0) {
        int row = i * 16 + lk * 4 + r;
        pp[w][row][0] = ds; pp[w][row][1] = dn;
      }
    }
  }
  #pragma unroll
  for (int i = 0; i < 4; ++i) {
    #pragma unroll
    for (int r = 0; r < 4; ++r) {
      int gr = row0 + i * 16 + lk * 4 + r;
      if (gr >= M) continue;
      #pragma unroll
      for (int tt = 0; tt < 2; ++tt) {
        int col = (w * 2 + tt) * 16 + lr;
        C[(long)gr * 128 + col] = f2b(acc[i][tt][r]);
      }
    }
  }
  __syncthreads();
  if (t < 64) {
    int gr = row0 + t;
    if (gr < M) {
      float ds = pp[0][t][0] + pp[1][t][0] + pp[2][t][0] + pp[3][t][0];
      float dn = pp[0][t][1] + pp[1][t][1] + pp[2][t][1] + pp[3][t][1];
      as_o[gr] = fl[gr] ? ds : NANF;
      an_o[gr] = dn;
    }
  }
}

// ---------------- gemm2: dual-grid bf16 MFMA, 2 accumulate passes, gathered A ----------------
__global__ __launch_bounds__(256, 3) void mfma2_dual(
    int split,
    const float* __restrict__ A1a, const unsigned short* __restrict__ W1ta,
    const float* __restrict__ A2a, const unsigned short* __restrict__ W2ta,
    const float* __restrict__ biasa, const int* __restrict__ aidxa,
    const int* __restrict__ map1a, int Ma, float* __restrict__ Ca,
    const float* __restrict__ A1b, const unsigned short* __restrict__ W1tb,
    const float* __restrict__ A2b, const unsigned short* __restrict__ W2tb,
    const float* __restrict__ biasb, const int* __restrict__ aidxb,
    const int* __restrict__ map1b, int Mb, float* __restrict__ Cb)
{
  const bool sB = (int)blockIdx.x >= split;
  const float* A1 = sB ? A1b : A1a;  const unsigned short* W1t = sB ? W1tb : W1ta;
  const float* A2 = sB ? A2b : A2a;  const unsigned short* W2t = sB ? W2tb : W2ta;
  const float* bias = sB ? biasb : biasa;
  const int* aidx = sB ? aidxb : aidxa;  const int* map1 = sB ? map1b : map1a;
  const int M = sB ? Mb : Ma;  float* C = sB ? Cb : Ca;
  const int bid = sB ? ((int)blockIdx.x - split) : (int)blockIdx.x;

  __shared__ unsigned short sW[16384];   // 32KB
  __shared__ unsigned short sA[8192];    // 16KB

  const int t = threadIdx.x;
  const int w = t >> 6, l = t & 63;
  const int lr = l & 15, lk = l >> 4;
  const int row0 = bid * 64;
  char* sWc = reinterpret_cast<char*>(sW);
  char* sAc = reinterpret_cast<char*>(sA);

  f32x4 acc[4][2];
  #pragma unroll
  for (int i = 0; i < 4; ++i)
    #pragma unroll
    for (int tt = 0; tt < 2; ++tt) acc[i][tt] = (f32x4){0.f, 0.f, 0.f, 0.f};

  #pragma unroll
  for (int pass = 0; pass < 2; ++pass) {
    const float* Am = pass ? A2 : A1;
    const unsigned short* Wt = pass ? W2t : W1t;
    if (pass) __syncthreads();
    #pragma unroll
    for (int q = 0; q < 8; ++q) {
      int p = t + 256 * q;
      int n = p >> 4, c16 = p & 15;
      bf16x8 v = *reinterpret_cast<const bf16x8*>(Wt + n * 128 + c16 * 8);
      *reinterpret_cast<bf16x8*>(sWc + swz(n, c16 * 16)) = v;
    }
    #pragma unroll
    for (int q = 0; q < 4; ++q) {
      int p = t + 256 * q;
      int r = p >> 4, c16 = p & 15;
      int gr = row0 + r;
      bf16x8 hv;
      if (gr < M) {
        long grow = (long)aidx[gr];
        if (pass == 0) grow = map1[grow];
        const float4* ap = reinterpret_cast<const float4*>(Am + grow * KD + c16 * 8);
        float4 v0 = ap[0], v1 = ap[1];
        hv[0]=(short)f2b(v0.x); hv[1]=(short)f2b(v0.y); hv[2]=(short)f2b(v0.z); hv[3]=(short)f2b(v0.w);
        hv[4]=(short)f2b(v1.x); hv[5]=(short)f2b(v1.y); hv[6]=(short)f2b(v1.z); hv[7]=(short)f2b(v1.w);
      } else {
        #pragma unroll
        for (int j = 0; j < 8; ++j) hv[j] = 0;
      }
      *reinterpret_cast<bf16x8*>(sAc + swz(r, c16 * 16)) = hv;
    }
    __syncthreads();
    #pragma unroll
    for (int kc = 0; kc < 4; ++kc) {
      const int kb = (kc * 32 + lk * 8) * 2;
      bf16x8 af[4];
      #pragma unroll
      for (int i = 0; i < 4; ++i)
        af[i] = *reinterpret_cast<const bf16x8*>(sAc + swz(i * 16 + lr, kb));
      #pragma unroll
      for (int tt = 0; tt < 2; ++tt) {
        int n = (w * 2 + tt) * 16 + lr;
        bf16x8 bfr = *reinterpret_cast<const bf16x8*>(sWc + swz(n, kb));
        #pragma unroll
        for (int i = 0; i < 4; ++i)
          acc[i][tt] = __builtin_amdgcn_mfma_f32_16x16x32_bf16(af[i], bfr, acc[i][tt], 0, 0, 0);
      }
    }
  }
  float bv[2];
  #pragma unroll
  for (int tt = 0; tt < 2; ++tt) bv[tt] = bias[(w * 2 + tt) * 16 + lr];
  #pragma unroll
  for (int i = 0; i < 4; ++i) {
    #pragma unroll
    for (int r = 0; r < 4; ++r) {
      int gr = row0 + i * 16 + lk * 4 + r;
      if (gr >= M) continue;
      #pragma unroll
      for (int tt = 0; tt < 2; ++tt) {
        int col = (w * 2 + tt) * 16 + lr;
        float v = acc[i][tt][r] + bv[tt];
        v = (v > 0.f) ? v : (__expf(v) - 1.f);
        C[(long)gr * 128 + col] = v;
      }
    }
  }
}

// ---------------- gemm3: dual-grid fp32, BM=64 NC=64, elu + gathered residual ----------
template<int BM, int NC>
__global__ __launch_bounds__(256, 3) void gemm3_dual(
    int split,
    const float* __restrict__ A1a, const float* __restrict__ W1a,
    const float* __restrict__ Resa, const int* __restrict__ ridxa, int Ma,
    float* __restrict__ Ca,
    const float* __restrict__ A1b, const float* __restrict__ W1b,
    const float* __restrict__ Resb, const int* __restrict__ ridxb, int Mb,
    float* __restrict__ Cb)
{
  const bool sB = (int)blockIdx.x >= split;
  const float* A1 = sB ? A1b : A1a;  const float* W1 = sB ? W1b : W1a;
  const float* Res = sB ? Resb : Resa;
  const int* ridx = sB ? ridxb : ridxa;
  const int M = sB ? Mb : Ma;  float* C = sB ? Cb : Ca;
  const int bid = sB ? ((int)blockIdx.x - split) : (int)blockIdx.x;

  constexpr int RT = BM / 16;
  constexpr int CW = NC / 16;
  constexpr int KB = 64;
  constexpr int CPP = KD / KB;
  constexpr int F4PR = KB / 4;
  constexpr int NAF4 = BM * KB / 4 / 256;
  constexpr int NWF4 = KB * NC / 4 / 256;
  __shared__ float sA[BM][KB + 4];
  __shared__ float sW[KB][NC];
  const int t  = threadIdx.x;
  const int ty = t >> 4, tx = t & 15;
  const int row0 = bid * BM;

  float acc[RT][CW];
  #pragma unroll
  for (int i = 0; i < RT; ++i)
    #pragma unroll
    for (int j = 0; j < CW; ++j) acc[i][j] = 0.f;

  for (int cc = 0; cc < CPP; ++cc) {
    const int kc = cc;
    if (cc) __syncthreads();
    {
      const float4* Wp = reinterpret_cast<const float4*>(W1) + (long)kc * (KB * NC / 4);
      #pragma unroll
      for (int q = 0; q < NWF4; ++q)
        reinterpret_cast<float4*>(&sW[0][0])[t + 256 * q] = Wp[t + 256 * q];
    }
    #pragma unroll
    for (int q = 0; q < NAF4; ++q) {
      int p  = t + 256 * q;
      int r  = p / F4PR, c4 = p % F4PR;
      float4 v = make_float4(0.f, 0.f, 0.f, 0.f);
      int gr = row0 + r;
      if (gr < M) {
        v = reinterpret_cast<const float4*>(A1 + (long)gr * KD)[kc * F4PR + c4];
      }
      *reinterpret_cast<float4*>(&sA[r][c4 * 4]) = v;
    }
    __syncthreads();
    #pragma unroll 4
    for (int k4 = 0; k4 < KB; k4 += 4) {
      float4 a4[RT];
      #pragma unroll
      for (int i = 0; i < RT; ++i)
        a4[i] = *reinterpret_cast<const float4*>(&sA[ty + 16 * i][k4]);
      #pragma unroll
      for (int kk = 0; kk < 4; ++kk) {
        float wv[CW];
        #pragma unroll
        for (int h = 0; h < CW / 4; ++h) {
          float4 w4 = *reinterpret_cast<const float4*>(&sW[k4 + kk][tx * 4 + 64 * h]);
          wv[h*4+0] = w4.x; wv[h*4+1] = w4.y; wv[h*4+2] = w4.z; wv[h*4+3] = w4.w;
        }
        #pragma unroll
        for (int i = 0; i < RT; ++i) {
          float a = (kk == 0) ? a4[i].x : (kk == 1) ? a4[i].y : (kk == 2) ? a4[i].z : a4[i].w;
          #pragma unroll
          for (int j = 0; j < CW; ++j)
            acc[i][j] = fmaf(a, wv[j], acc[i][j]);
        }
      }
    }
  }
  #pragma unroll
  for (int i = 0; i < RT; ++i) {
    int gr = row0 + ty + 16 * i;
    if (gr >= M) continue;
    long rrow = (long)ridx[gr];
    #pragma unroll
    for (int h = 0; h < CW / 4; ++h) {
      int c = tx * 4 + 64 * h;
      float4 v = make_float4(acc[i][h*4+0], acc[i][h*4+1], acc[i][h*4+2], acc[i][h*4+3]);
      v.x = (v.x > 0.f) ? v.x : (__expf(v.x) - 1.f);
      v.y = (v.y > 0.f) ? v.y : (__expf(v.y) - 1.f);
      v.z = (v.z > 0.f) ? v.z : (__expf(v.z) - 1.f);
      v.w = (v.w > 0.f) ? v.w : (__expf(v.w) - 1.f);
      float4 rv = *reinterpret_cast<const float4*>(Res + rrow * NC + c);
      v.x += rv.x; v.y += rv.y; v.z += rv.z; v.w += rv.w;
      *reinterpret_cast<float4*>(C + (long)gr * NC + c) = v;
    }
  }
}

// ---------------- needed-dst flags: byte array + 1-bit mask (user gate) ----------
__global__ void flags_kernel(const int* __restrict__ ui, const int* __restrict__ ii, int B,
                             unsigned char* __restrict__ nfu, unsigned char* __restrict__ nfb,
                             unsigned* __restrict__ mku)
{
  int i = blockIdx.x * blockDim.x + threadIdx.x;
  if (i < B) {
    int u = ui[i], v = ii[i];
    nfu[u] = 1; nfb[v] = 1;
    atomicOr(&mku[u >> 5], 1u << (u & 31));
  }
}

// ---------------- user pass 1: 16 edges/thread; bitmask gate; atomic rel ----------
__global__ __launch_bounds__(256) void edge_prep_u(
    const int* __restrict__ src, const int* __restrict__ dst,
    const float* __restrict__ as_, const float* __restrict__ an_,
    const unsigned* __restrict__ mk,
    int* __restrict__ deg, int4* __restrict__ cmp, int* __restrict__ blkcnt, int E)
{
  __shared__ int lcnt;
  if (threadIdx.x == 0) lcnt = 0;
  __syncthreads();
  const int lane = threadIdx.x & 63;
  const int bid = (int)blockIdx.x;
  const long base = (long)bid * 4096;
  const int e0 = (int)base + threadIdx.x * 16;

  int d[16], s[16];
  bool act[16];
  const bool full = (e0 + 15 < E);
  if (full) {
    #pragma unroll
    for (int q = 0; q < 4; ++q) {
      int4 d4 = *reinterpret_cast<const int4*>(dst + e0 + q * 4);
      int4 s4 = *reinterpret_cast<const int4*>(src + e0 + q * 4);
      d[q*4+0]=d4.x; d[q*4+1]=d4.y; d[q*4+2]=d4.z; d[q*4+3]=d4.w;
      s[q*4+0]=s4.x; s[q*4+1]=s4.y; s[q*4+2]=s4.z; s[q*4+3]=s4.w;
    }
    #pragma unroll
    for (int j = 0; j < 16; ++j) act[j] = true;
  } else {
    #pragma unroll
    for (int j = 0; j < 16; ++j) {
      act[j] = (e0 + j < E);
      d[j] = act[j] ? dst[e0 + j] : 0;
      s[j] = act[j] ? src[e0 + j] : 0;
    }
  }
  unsigned mw[16];
  #pragma unroll
  for (int j = 0; j < 16; ++j) mw[j] = mk[d[j] >> 5];
  #pragma unroll
  for (int j = 0; j < 16; ++j) act[j] = act[j] && ((mw[j] >> (d[j] & 31)) & 1u);

  float vas[16], van[16];
  #pragma unroll
  for (int j = 0; j < 16; ++j) vas[j] = act[j] ? as_[d[j]] : 0.f;
  #pragma unroll
  for (int j = 0; j < 16; ++j) van[j] = act[j] ? an_[s[j]] : 0.f;
  float sc[16];
  #pragma unroll
  for (int j = 0; j < 16; ++j) {
    float v = vas[j] + van[j];
    v = (v >= 0.f) ? v : 0.2f * v;       // leaky_relu 0.2
    sc[j] = __expf(v);
  }
  int tot = 0;
  #pragma unroll
  for (int j = 0; j < 16; ++j) tot += __popcll(__ballot(act[j]));
  int wb = 0;
  if (lane == 0) wb = atomicAdd(&lcnt, tot);
  wb = __shfl(wb, 0, 64);
  #pragma unroll
  for (int j = 0; j < 16; ++j) {
    unsigned long long m = __ballot(act[j]);
    if (act[j]) {
      int pref = __popcll(m & ((1ull << lane) - 1ull));
      int rel = atomicAdd(&deg[d[j]], 1);
      cmp[base + wb + pref] = make_int4(s[j], d[j], rel, __float_as_int(sc[j]));
    }
    wb += __popcll(m);
  }
  __syncthreads();
  if (threadIdx.x == 0) blkcnt[bid] = lcnt;
}

// ---------------- dual pass 2: 4 node-groups per wave, ONE atomic pair per wave ----------
// EXACT round-26 logic (proven).
__global__ __launch_bounds__(256) void offset_dual(
    int split,
    const unsigned char* __restrict__ flA, int* __restrict__ degA,
    int* __restrict__ offsA, int* __restrict__ dlA, int* __restrict__ g2cA,
    int* __restrict__ cntA, int NA,
    const unsigned char* __restrict__ flB, int* __restrict__ degB,
    const int* __restrict__ sstartB, const int* __restrict__ sendB,
    int* __restrict__ offsB, int* __restrict__ dlB, int* __restrict__ g2cB,
    int* __restrict__ cntB, int NB)
{
  const bool sB = (int)blockIdx.x >= split;
  const unsigned char* flag = sB ? flB : flA;
  int* deg = sB ? degB : degA;
  int* offs = sB ? offsB : offsA;  int* dlist = sB ? dlB : dlA;
  int* g2c = sB ? g2cB : g2cA;     int* cnt = sB ? cntB : cntA;
  const int N = sB ? NB : NA;
  const int bid = sB ? ((int)blockIdx.x - split) : (int)blockIdx.x;
  const int lane = threadIdx.x & 63;

  int idx[4], dg[4], exc[4], prf[4], nwq[4], tq[4];
  bool av[4];
  int wn = 0, wt = 0;
  #pragma unroll
  for (int q = 0; q < 4; ++q) {
    int i = bid * 1024 + q * 256 + (int)threadIdx.x;
    idx[q] = i;
    bool a = (i < N) && flag[i];
    int dgv = 0;
    if (a) {
      if (sB) { dgv = sendB[i] - sstartB[i]; deg[i] = dgv; }
      else dgv = deg[i];
    }
    av[q] = a; dg[q] = dgv;
    unsigned long long m = __ballot(a);
    nwq[q] = __popcll(m);
    prf[q] = __popcll(m & ((1ull << lane) - 1ull));
    int inc = dgv;
    #pragma unroll
    for (int o = 1; o < 64; o <<= 1) {
      int v = __shfl_up(inc, o, 64);
      if (lane >= o) inc += v;
    }
    tq[q] = __shfl(inc, 63, 64);
    exc[q] = inc - dgv;
    wn += nwq[q]; wt += tq[q];
  }
  int baseL = 0, baseE = 0;
  if (lane == 0) {
    baseL = wn ? atomicAdd(&cnt[1], wn) : 0;
    baseE = wt ? atomicAdd(&cnt[0], wt) : 0;
  }
  baseL = __shfl(baseL, 0, 64);
  baseE = __shfl(baseE, 0, 64);
  int runN = 0, runE = 0;
  #pragma unroll
  for (int q = 0; q < 4; ++q) {
    if (av[q]) {
      int i = idx[q];
      int l = baseL + runN + prf[q];
      g2c[i] = l;
      dlist[l] = i;
      if (dg[q] > 0) offs[i] = baseE + runE + exc[q];
    }
    runN += nwq[q]; runE += tq[q];
  }
}

// ---------------- user pass 3: place packed (src,p) — no atomics ----------
__global__ __launch_bounds__(256) void place_u(
    const int4* __restrict__ cmp, const int* __restrict__ blkcnt,
    const int* __restrict__ offs, int2* __restrict__ eline)
{
  int nb = blkcnt[blockIdx.x];
  const long base = (long)blockIdx.x * 4096;
  for (int k = threadIdx.x; k < nb; k += 256) {
    int4 c = cmp[base + k];
    int pos = offs[c.y] + c.z;
    eline[pos] = make_int2(c.x, c.w);
  }
}

// ---------------- item edge scoring: one wave per ACTIVE dst (sorted segments) ----------
// Writes el[offs[d] + (e - sstart[d])] = {src, exp(leaky((as+an)*uw))} — position/order
// identical to the previous cmp+place path, so aggregation is bit-identical.
__global__ __launch_bounds__(256) void edge_scoreb(
    const int* __restrict__ src, const float* __restrict__ as_, const float* __restrict__ an_,
    const float* __restrict__ gc, const float* __restrict__ omega,
    const int* __restrict__ dl, const int* __restrict__ cnt, const int* __restrict__ offs,
    const int* __restrict__ sstart, const int* __restrict__ send,
    int2* __restrict__ eline)
{
  int wid  = (int)blockIdx.x * 4 + (int)(threadIdx.x >> 6);
  int lane = threadIdx.x & 63;
  if (wid >= cnt[1]) return;
  int d = dl[wid];
  int st = sstart[d], en = send[d];
  int n = en - st;
  if (n <= 0) return;
  int ob = offs[d];
  float asd = as_[d];
  float o0 = omega[0], o1 = omega[1], o2 = omega[2];
  for (int i = lane; i < n; i += 64) {
    long e = st + i;
    int s = src[e];
    float uw = gc[e*3+0]*o0 + gc[e*3+1]*o1 + gc[e*3+2]*o2;
    float v = (asd + an_[s]) * uw;
    v = (v >= 0.f) ? v : 0.2f * v;       // leaky_relu 0.2
    eline[ob + i] = make_int2(s, __float_as_int(__expf(v)));
  }
}

// ---------------- dual wave-per-dst softmax + aggregation (bf16 H1 reads) ----------
__global__ __launch_bounds__(256) void aggr_dual(
    int split,
    const int* __restrict__ dlA, const int* __restrict__ cntA,
    const int* __restrict__ offsA, const int* __restrict__ degA,
    const int2* __restrict__ elA, const unsigned short* __restrict__ H1A, float* __restrict__ HoA,
    const int* __restrict__ dlB, const int* __restrict__ cntB,
    const int* __restrict__ offsB, const int* __restrict__ degB,
    const int2* __restrict__ elB, const unsigned short* __restrict__ H1B, float* __restrict__ HoB)
{
  const bool sB = (int)blockIdx.x >= split;
  const int* dlist = sB ? dlB : dlA;  const int* cnt = sB ? cntB : cntA;
  const int* offs = sB ? offsB : offsA;  const int* deg = sB ? degB : degA;
  const int2* eline = sB ? elB : elA;
  const unsigned short* H1 = sB ? H1B : H1A;  float* Houtc = sB ? HoB : HoA;
  const int bid = sB ? ((int)blockIdx.x - split) : (int)blockIdx.x;

  int wid  = bid * 4 + (int)(threadIdx.x >> 6);
  int lane = threadIdx.x & 63;
  if (wid >= cnt[1]) return;
  int d = dlist[wid];
  int n = deg[d];
  float2* op = reinterpret_cast<float2*>(Houtc + (long)wid * KD) + lane;
  if (n == 0) { *op = make_float2(0.f, 0.f); return; }
  int st = offs[d];
  float ssum = 0.f;
  for (int i = lane; i < n; i += 64) ssum += __int_as_float(eline[st + i].y);
  #pragma unroll
  for (int o = 32; o; o >>= 1) ssum += __shfl_xor(ssum, o, 64);
  float inv = 1.f / ssum;
  float ax = 0.f, ay = 0.f;
  int i = 0;
  for (; i + 4 <= n; i += 4) {
    int2 e0 = eline[st + i], e1 = eline[st + i + 1], e2 = eline[st + i + 2], e3 = eline[st + i + 3];
    float a0 = __int_as_float(e0.y);
    float a1 = __int_as_float(e1.y);
    float a2 = __int_as_float(e2.y);
    float a3 = __int_as_float(e3.y);
    unsigned u0 = *reinterpret_cast<const unsigned*>(H1 + (long)e0.x * KD + lane * 2);
    unsigned u1 = *reinterpret_cast<const unsigned*>(H1 + (long)e1.x * KD + lane * 2);
    unsigned u2 = *reinterpret_cast<const unsigned*>(H1 + (long)e2.x * KD + lane * 2);
    unsigned u3 = *reinterpret_cast<const unsigned*>(H1 + (long)e3.x * KD + lane * 2);
    ax = fmaf(__uint_as_float(u0 << 16), a0, ax); ay = fmaf(__uint_as_float(u0 & 0xffff0000u), a0, ay);
    ax = fmaf(__uint_as_float(u1 << 16), a1, ax); ay = fmaf(__uint_as_float(u1 & 0xffff0000u), a1, ay);
    ax = fmaf(__uint_as_float(u2 << 16), a2, ax); ay = fmaf(__uint_as_float(u2 & 0xffff0000u), a2, ay);
    ax = fmaf(__uint_as_float(u3 << 16), a3, ax); ay = fmaf(__uint_as_float(u3 & 0xffff0000u), a3, ay);
  }
  for (; i < n; ++i) {
    int2 e0 = eline[st + i];
    float a0 = __int_as_float(e0.y);
    unsigned u0 = *reinterpret_cast<const unsigned*>(H1 + (long)e0.x * KD + lane * 2);
    ax = fmaf(__uint_as_float(u0 << 16), a0, ax); ay = fmaf(__uint_as_float(u0 & 0xffff0000u), a0, ay);
  }
  *op = make_float2(ax * inv, ay * inv);
}

// ---------------- final: dot + biases + sigmoid -------------
__global__ __launch_bounds__(256) void final_kernel(
    const float* __restrict__ Ug, const float* __restrict__ Bg,
    const int* __restrict__ ui, const int* __restrict__ ii,
    const float* __restrict__ bias_u, const float* __restrict__ bias_b,
    const float* __restrict__ bx, float* __restrict__ out, int B)
{
  int wid  = (int)((blockIdx.x * 256 + threadIdx.x) >> 6);
  int lane = threadIdx.x & 63;
  if (wid >= B) return;
  float v = Ug[(long)wid * 64 + lane] * Bg[(long)wid * 64 + lane];
  #pragma unroll
  for (int o = 32; o > 0; o >>= 1) v += __shfl_xor(v, o, 64);
  if (lane == 0) {
    float raw = v + bias_u[ui[wid]] + bias_b[ii[wid]] + bx[0];
    out[wid] = 4.f / (1.f + __expf(-raw)) + 1.f;
  }
}

extern "C" void kernel_launch(void* const* d_in, const int* in_sizes, int n_in,
                              void* d_out, int out_size, void* d_ws, size_t ws_size,
                              hipStream_t stream)
{
  const int*   ui    = (const int*)  d_in[0];
  const int*   ii    = (const int*)  d_in[1];
  const float* S_u   = (const float*)d_in[2];
  const float* S_b   = (const float*)d_in[3];
  const int*   eu    = (const int*)  d_in[4];
  const int*   eb    = (const int*)  d_in[5];
  const float* gc    = (const float*)d_in[6];
  const float* W1_u  = (const float*)d_in[7];
  const float* a_s_u = (const float*)d_in[8];
  const float* a_n_u = (const float*)d_in[9];
  const float* W1_b  = (const float*)d_in[10];
  const float* a_s_b = (const float*)d_in[11];
  const float* a_n_b = (const float*)d_in[12];
  const float* omega = (const float*)d_in[13];
  const float* W_u2  = (const float*)d_in[14];
  const float* W_us2w= (const float*)d_in[15];
  const float* W_us2b= (const float*)d_in[16];
  const float* W_b2  = (const float*)d_in[17];
  const float* W_bs2w= (const float*)d_in[18];
  const float* W_bs2b= (const float*)d_in[19];
  const float* W_u3  = (const float*)d_in[20];
  const float* W_b3  = (const float*)d_in[21];
  const float* H_u4  = (const float*)d_in[22];
  const float* H_b4  = (const float*)d_in[23];
  const float* bias_u= (const float*)d_in[24];
  const float* bias_b= (const float*)d_in[25];
  const float* b_x   = (const float*)d_in[26];
  float* out = (float*)d_out;

  const int B  = in_sizes[0];
  const int NU = in_sizes[2] / KD;
  const int NI = in_sizes[3] / KD;
  const int EU = in_sizes[4] / 2;
  const int EB = in_sizes[5] / 2;
  const int GPU_ = (EU + 4095) / 4096;
  const int G1U = (NU + 63) / 64, G1I = (NI + 63) / 64;
  const int GO4U = (NU + 1023) / 1024, GO4I = (NI + 1023) / 1024;
  const int GAG = (B + 3) / 4;
  const int GB  = (B + 63) / 64;

  char* w = (char*)d_ws;
  auto alloc = [&](size_t bytes) -> void* {
    void* r = (void*)w;
    w += (bytes + 255) & ~(size_t)255;
    return r;
  };
  // ---- zero-initialized region (one small memset per call) ----
  int* deg_u = (int*)alloc((size_t)NU * 4);
  int* deg_b = (int*)alloc((size_t)NI * 4);
  unsigned char* nfu = (unsigned char*)alloc((size_t)NU);
  unsigned char* nfb = (unsigned char*)alloc((size_t)NI);
  unsigned* mku = (unsigned*)alloc((size_t)((NU + 31) / 32) * 4);
  int* sst_b = (int*)alloc((size_t)NI * 4);
  int* snd_b = (int*)alloc((size_t)NI * 4);
  int* cnt   = (int*)alloc(16 * 4);
  size_t zbytes = (size_t)(w - (char*)d_ws);
  // ---- scratch ----
  unsigned short* wt = (unsigned short*)alloc((size_t)6 * 16384 * 2);
  int*   offs_u = (int*)  alloc((size_t)NU * 4);
  int*   offs_b = (int*)  alloc((size_t)NI * 4);
  int*   g2c_u  = (int*)  alloc((size_t)NU * 4);
  int*   g2c_b  = (int*)  alloc((size_t)NI * 4);
  int*   dl_u   = (int*)  alloc((size_t)B * 4);
  int*   dl_b   = (int*)  alloc((size_t)B * 4);
  int*   bc_u   = (int*)  alloc((size_t)GPU_ * 4);
  int4*  cmp_u  = (int4*) alloc((size_t)GPU_ * 4096 * 16);
  int2*  el_u   = (int2*) alloc((size_t)EU * 8);
  int2*  el_b   = (int2*) alloc((size_t)EB * 8);
  unsigned short* H1u = (unsigned short*)alloc((size_t)NU * KD * 2);
  unsigned short* H1b = (unsigned short*)alloc((size_t)NI * KD * 2);
  float* Hu2c = (float*)alloc((size_t)B * KD * 4);
  float* Hb2c = (float*)alloc((size_t)B * KD * 4);
  float* asu  = (float*)alloc((size_t)NU * 4);
  float* anu  = (float*)alloc((size_t)NU * 4);
  float* asb  = (float*)alloc((size_t)NI * 4);
  float* anb  = (float*)alloc((size_t)NI * 4);
  float* Hu3g = (float*)alloc((size_t)B * KD * 4);
  float* Hb3g = (float*)alloc((size_t)B * KD * 4);
  float* Ug   = (float*)alloc((size_t)B * 64 * 4);
  float* Bg   = (float*)alloc((size_t)B * 64 * 4);
  (void)ws_size; (void)n_in; (void)out_size;

  hipMemsetAsync(d_ws, 0, zbytes, stream);

  wsplit6<<<384, 256, 0, stream>>>(W1_u, W1_b, W_u2, W_us2w, W_b2, W_bs2w, wt);
  flags_kernel<<<(B + 255) / 256, 256, 0, stream>>>(ui, ii, B, nfu, nfb, mku);
  segb_kernel<<<(EB + 255) / 256, 256, 0, stream>>>(eb + EB, EB, sst_b, snd_b);

  // H1 = S @ W1: bf16 MFMA, fused proj + NaN sentinel
  mfma1_dual<<<G1U + G1I, 256, 0, stream>>>(
      G1U,
      S_u, wt + 0 * 16384, NU, H1u, a_s_u, a_n_u, asu, anu, nfu,
      S_b, wt + 1 * 16384, NI, H1b, a_s_b, a_n_b, asb, anb, nfb);

  // user side: score+count (atomic counting-sort)
  edge_prep_u<<<GPU_, 256, 0, stream>>>(
      eu, eu + EU, asu, anu, mku, deg_u, cmp_u, bc_u, EU);

  // both sides: compact dst list + segment offsets (item deg from sorted segs)
  offset_dual<<<GO4U + GO4I, 256, 0, stream>>>(
      GO4U,
      nfu, deg_u, offs_u, dl_u, g2c_u, cnt + 0, NU,
      nfb, deg_b, sst_b, snd_b, offs_b, dl_b, g2c_b, cnt + 2, NI);

  // user side: place packed entries
  place_u<<<GPU_, 256, 0, stream>>>(cmp_u, bc_u, offs_u, el_u);

  // item side: score directly per active dst (contiguous segment reads)
  edge_scoreb<<<GAG, 256, 0, stream>>>(
      eb, asb, anb, gc, omega, dl_b, cnt + 2, offs_b, sst_b, snd_b, el_b);

  aggr_dual<<<GAG * 2, 256, 0, stream>>>(
      GAG,
      dl_u, cnt + 0, offs_u, deg_u, el_u, H1u, Hu2c,
      dl_b, cnt + 2, offs_b, deg_b, el_b, H1b, Hb2c);

  // H3 = elu(Hu2c[g2c[ui]]@W_u2 + S_u[ui]@W_us2w + b): bf16 MFMA, 2 passes
  mfma2_dual<<<GB * 2, 256, 0, stream>>>(
      GB,
      Hu2c, wt + 2 * 16384, S_u, wt + 3 * 16384, W_us2b, ui, g2c_u, B, Hu3g,
      Hb2c, wt + 4 * 16384, S_b, wt + 5 * 16384, W_bs2b, ii, g2c_b, B, Hb3g);

  // U = elu(H3 @ W3) + H4[idx]: fp32, NC=64 (absmax margin)
  gemm3_dual<64,64><<<GB * 2, 256, 0, stream>>>(
      GB,
      Hu3g, W_u3, H_u4, ui, B, Ug,
      Hb3g, W_b3, H_b4, ii, B, Bg);

  final_kernel<<<(B + 3) / 4, 256, 0, stream>>>(Ug, Bg, ui, ii, bias_u, bias_b, b_x, out, B);
}

// Round 28
// 185.751 us; speedup vs baseline: 1.4137x; 1.0286x over previous
//
#include <hip/hip_runtime.h>
#include <hip/hip_bf16.h>

#define KD 128
#define NANF __int_as_float(0x7fc00000)

typedef __attribute__((ext_vector_type(8))) short bf16x8;
typedef __attribute__((ext_vector_type(4))) float f32x4;

__device__ __forceinline__ unsigned short f2b(float x) {  // fp32 -> bf16 RNE
  unsigned u = __float_as_uint(x);
  return (unsigned short)((u + 0x7fffu + ((u >> 16) & 1u)) >> 16);
}
__device__ __forceinline__ int swz(int row, int kbyte) {  // LDS byte addr, G4 XOR swizzle
  return (row * 256 + kbyte) ^ ((row & 7) << 4);
}

// ---------------- one-shot: transpose+convert six 128x128 W to bf16 Wt[n][k] ----------------
__global__ __launch_bounds__(256) void wsplit6(
    const float* __restrict__ w0, const float* __restrict__ w1,
    const float* __restrict__ w2, const float* __restrict__ w3,
    const float* __restrict__ w4, const float* __restrict__ w5,
    unsigned short* __restrict__ oh)
{
  int m = blockIdx.x >> 6;
  int idx = (blockIdx.x & 63) * 256 + threadIdx.x;   // n*128 + k
  const float* ws;
  switch (m) { case 0: ws = w0; break; case 1: ws = w1; break; case 2: ws = w2; break;
               case 3: ws = w3; break; case 4: ws = w4; break; default: ws = w5; }
  int n = idx >> 7, k = idx & 127;
  oh[(long)m * 16384 + idx] = f2b(ws[k * 128 + n]);
}

// ---------------- item-graph segment boundaries (dst is sorted ascending) ----------------
__global__ __launch_bounds__(256) void segb_kernel(
    const int* __restrict__ dst, int E,
    int* __restrict__ sstart, int* __restrict__ send)
{
  int e = blockIdx.x * 256 + threadIdx.x;
  if (e >= E) return;
  int d = dst[e];
  if (e == 0 || dst[e - 1] != d) sstart[d] = e;
  if (e == E - 1 || dst[e + 1] != d) send[d] = e + 1;
}

// ---------------- gemm1: dual-grid bf16 MFMA; W fragments in registers (L2-hot), A in LDS ----
__global__ __launch_bounds__(256, 4) void mfma1_dual(
    int split,
    const float* __restrict__ Aa, const unsigned short* __restrict__ Wta, int Ma,
    unsigned short* __restrict__ Ca,
    const float* __restrict__ a_sa, const float* __restrict__ a_na,
    float* __restrict__ as_oa, float* __restrict__ an_oa, const unsigned char* __restrict__ fla,
    const float* __restrict__ Ab, const unsigned short* __restrict__ Wtb, int Mb,
    unsigned short* __restrict__ Cb,
    const float* __restrict__ a_sb, const float* __restrict__ a_nb,
    float* __restrict__ as_ob, float* __restrict__ an_ob, const unsigned char* __restrict__ flb)
{
  const bool sB = (int)blockIdx.x >= split;
  const float* A = sB ? Ab : Aa;
  const unsigned short* Wt = sB ? Wtb : Wta;
  const int M = sB ? Mb : Ma;
  unsigned short* C = sB ? Cb : Ca;
  const float* a_s = sB ? a_sb : a_sa;  const float* a_n = sB ? a_nb : a_na;
  float* as_o = sB ? as_ob : as_oa;     float* an_o = sB ? an_ob : an_oa;
  const unsigned char* fl = sB ? flb : fla;
  const int bid = sB ? ((int)blockIdx.x - split) : (int)blockIdx.x;

  __shared__ unsigned short sA[8192];    // 16KB
  __shared__ float pp[4][64][2];         // 2KB

  const int t = threadIdx.x;
  const int w = t >> 6, l = t & 63;
  const int lr = l & 15, lk = l >> 4;
  const int row0 = bid * 64;
  char* sAc = reinterpret_cast<char*>(sA);

  // B fragments direct global->register: every block reads the same 32KB W (L2/L3-hot).
  // Same elements the old sW path delivered: Wt[n][kc*32 + lk*8 .. +7], n = (w*2+tt)*16+lr.
  bf16x8 bw[4][2];
  #pragma unroll
  for (int kc = 0; kc < 4; ++kc)
    #pragma unroll
    for (int tt = 0; tt < 2; ++tt) {
      int n = (w * 2 + tt) * 16 + lr;
      bw[kc][tt] = *reinterpret_cast<const bf16x8*>(Wt + n * 128 + kc * 32 + lk * 8);
    }

  #pragma unroll
  for (int q = 0; q < 4; ++q) {
    int p = t + 256 * q;
    int r = p >> 4, c16 = p & 15;
    int gr = row0 + r;
    bf16x8 hv;
    if (gr < M) {
      const float4* ap = reinterpret_cast<const float4*>(A + (long)gr * KD + c16 * 8);
      float4 v0 = ap[0], v1 = ap[1];
      hv[0]=(short)f2b(v0.x); hv[1]=(short)f2b(v0.y); hv[2]=(short)f2b(v0.z); hv[3]=(short)f2b(v0.w);
      hv[4]=(short)f2b(v1.x); hv[5]=(short)f2b(v1.y); hv[6]=(short)f2b(v1.z); hv[7]=(short)f2b(v1.w);
    } else {
      #pragma unroll
      for (int j = 0; j < 8; ++j) hv[j] = 0;
    }
    *reinterpret_cast<bf16x8*>(sAc + swz(r, c16 * 16)) = hv;
  }
  __syncthreads();

  f32x4 acc[4][2];
  #pragma unroll
  for (int i = 0; i < 4; ++i)
    #pragma unroll
    for (int tt = 0; tt < 2; ++tt) acc[i][tt] = (f32x4){0.f, 0.f, 0.f, 0.f};

  #pragma unroll
  for (int kc = 0; kc < 4; ++kc) {
    const int kb = (kc * 32 + lk * 8) * 2;
    bf16x8 af[4];
    #pragma unroll
    for (int i = 0; i < 4; ++i)
      af[i] = *reinterpret_cast<const bf16x8*>(sAc + swz(i * 16 + lr, kb));
    #pragma unroll
    for (int tt = 0; tt < 2; ++tt) {
      #pragma unroll
      for (int i = 0; i < 4; ++i)
        acc[i][tt] = __builtin_amdgcn_mfma_f32_16x16x32_bf16(af[i], bw[kc][tt], acc[i][tt], 0, 0, 0);
    }
  }

  float asv[2], anv[2];
  #pragma unroll
  for (int tt = 0; tt < 2; ++tt) {
    int col = (w * 2 + tt) * 16 + lr;
    asv[tt] = a_s[col]; anv[tt] = a_n[col];
  }
  #pragma unroll
  for (int i = 0; i < 4; ++i) {
    #pragma unroll
    for (int r = 0; r < 4; ++r) {
      float ds = acc[i][0][r] * asv[0] + acc[i][1][r] * asv[1];
      float dn = acc[i][0][r] * anv[0] + acc[i][1][r] * anv[1];
      #pragma unroll
      for (int o = 1; o < 16; o <<= 1) { ds += __shfl_xor(ds, o, 64); dn += __shfl_xor(dn, o, 64); }
      if (lr == 0) {
        int row = i * 16 + lk * 4 + r;
        pp[w][row][0] = ds; pp[w][row][1] = dn;
      }
    }
  }
  #pragma unroll
  for (int i = 0; i < 4; ++i) {
    #pragma unroll
    for (int r = 0; r < 4; ++r) {
      int gr = row0 + i * 16 + lk * 4 + r;
      if (gr >= M) continue;
      #pragma unroll
      for (int tt = 0; tt < 2; ++tt) {
        int col = (w * 2 + tt) * 16 + lr;
        C[(long)gr * 128 + col] = f2b(acc[i][tt][r]);
      }
    }
  }
  __syncthreads();
  if (t < 64) {
    int gr = row0 + t;
    if (gr < M) {
      float ds = pp[0][t][0] + pp[1][t][0] + pp[2][t][0] + pp[3][t][0];
      float dn = pp[0][t][1] + pp[1][t][1] + pp[2][t][1] + pp[3][t][1];
      as_o[gr] = fl[gr] ? ds : NANF;
      an_o[gr] = dn;
    }
  }
}

// ---------------- gemm2: dual-grid bf16 MFMA, 2 accumulate passes, gathered A ----------------
__global__ __launch_bounds__(256, 3) void mfma2_dual(
    int split,
    const float* __restrict__ A1a, const unsigned short* __restrict__ W1ta,
    const float* __restrict__ A2a, const unsigned short* __restrict__ W2ta,
    const float* __restrict__ biasa, const int* __restrict__ aidxa,
    const int* __restrict__ map1a, int Ma, float* __restrict__ Ca,
    const float* __restrict__ A1b, const unsigned short* __restrict__ W1tb,
    const float* __restrict__ A2b, const unsigned short* __restrict__ W2tb,
    const float* __restrict__ biasb, const int* __restrict__ aidxb,
    const int* __restrict__ map1b, int Mb, float* __restrict__ Cb)
{
  const bool sB = (int)blockIdx.x >= split;
  const float* A1 = sB ? A1b : A1a;  const unsigned short* W1t = sB ? W1tb : W1ta;
  const float* A2 = sB ? A2b : A2a;  const unsigned short* W2t = sB ? W2tb : W2ta;
  const float* bias = sB ? biasb : biasa;
  const int* aidx = sB ? aidxb : aidxa;  const int* map1 = sB ? map1b : map1a;
  const int M = sB ? Mb : Ma;  float* C = sB ? Cb : Ca;
  const int bid = sB ? ((int)blockIdx.x - split) : (int)blockIdx.x;

  __shared__ unsigned short sW[16384];   // 32KB
  __shared__ unsigned short sA[8192];    // 16KB

  const int t = threadIdx.x;
  const int w = t >> 6, l = t & 63;
  const int lr = l & 15, lk = l >> 4;
  const int row0 = bid * 64;
  char* sWc = reinterpret_cast<char*>(sW);
  char* sAc = reinterpret_cast<char*>(sA);

  f32x4 acc[4][2];
  #pragma unroll
  for (int i = 0; i < 4; ++i)
    #pragma unroll
    for (int tt = 0; tt < 2; ++tt) acc[i][tt] = (f32x4){0.f, 0.f, 0.f, 0.f};

  #pragma unroll
  for (int pass = 0; pass < 2; ++pass) {
    const float* Am = pass ? A2 : A1;
    const unsigned short* Wt = pass ? W2t : W1t;
    if (pass) __syncthreads();
    #pragma unroll
    for (int q = 0; q < 8; ++q) {
      int p = t + 256 * q;
      int n = p >> 4, c16 = p & 15;
      bf16x8 v = *reinterpret_cast<const bf16x8*>(Wt + n * 128 + c16 * 8);
      *reinterpret_cast<bf16x8*>(sWc + swz(n, c16 * 16)) = v;
    }
    #pragma unroll
    for (int q = 0; q < 4; ++q) {
      int p = t + 256 * q;
      int r = p >> 4, c16 = p & 15;
      int gr = row0 + r;
      bf16x8 hv;
      if (gr < M) {
        long grow = (long)aidx[gr];
        if (pass == 0) grow = map1[grow];
        const float4* ap = reinterpret_cast<const float4*>(Am + grow * KD + c16 * 8);
        float4 v0 = ap[0], v1 = ap[1];
        hv[0]=(short)f2b(v0.x); hv[1]=(short)f2b(v0.y); hv[2]=(short)f2b(v0.z); hv[3]=(short)f2b(v0.w);
        hv[4]=(short)f2b(v1.x); hv[5]=(short)f2b(v1.y); hv[6]=(short)f2b(v1.z); hv[7]=(short)f2b(v1.w);
      } else {
        #pragma unroll
        for (int j = 0; j < 8; ++j) hv[j] = 0;
      }
      *reinterpret_cast<bf16x8*>(sAc + swz(r, c16 * 16)) = hv;
    }
    __syncthreads();
    #pragma unroll
    for (int kc = 0; kc < 4; ++kc) {
      const int kb = (kc * 32 + lk * 8) * 2;
      bf16x8 af[4];
      #pragma unroll
      for (int i = 0; i < 4; ++i)
        af[i] = *reinterpret_cast<const bf16x8*>(sAc + swz(i * 16 + lr, kb));
      #pragma unroll
      for (int tt = 0; tt < 2; ++tt) {
        int n = (w * 2 + tt) * 16 + lr;
        bf16x8 bfr = *reinterpret_cast<const bf16x8*>(sWc + swz(n, kb));
        #pragma unroll
        for (int i = 0; i < 4; ++i)
          acc[i][tt] = __builtin_amdgcn_mfma_f32_16x16x32_bf16(af[i], bfr, acc[i][tt], 0, 0, 0);
      }
    }
  }
  float bv[2];
  #pragma unroll
  for (int tt = 0; tt < 2; ++tt) bv[tt] = bias[(w * 2 + tt) * 16 + lr];
  #pragma unroll
  for (int i = 0; i < 4; ++i) {
    #pragma unroll
    for (int r = 0; r < 4; ++r) {
      int gr = row0 + i * 16 + lk * 4 + r;
      if (gr >= M) continue;
      #pragma unroll
      for (int tt = 0; tt < 2; ++tt) {
        int col = (w * 2 + tt) * 16 + lr;
        float v = acc[i][tt][r] + bv[tt];
        v = (v > 0.f) ? v : (__expf(v) - 1.f);
        C[(long)gr * 128 + col] = v;
      }
    }
  }
}

// ---------------- gemm3: dual-grid fp32, BM=64 NC=64, elu + gathered residual ----------
template<int BM, int NC>
__global__ __launch_bounds__(256, 3) void gemm3_dual(
    int split,
    const float* __restrict__ A1a, const float* __restrict__ W1a,
    const float* __restrict__ Resa, const int* __restrict__ ridxa, int Ma,
    float* __restrict__ Ca,
    const float* __restrict__ A1b, const float* __restrict__ W1b,
    const float* __restrict__ Resb, const int* __restrict__ ridxb, int Mb,
    float* __restrict__ Cb)
{
  const bool sB = (int)blockIdx.x >= split;
  const float* A1 = sB ? A1b : A1a;  const float* W1 = sB ? W1b : W1a;
  const float* Res = sB ? Resb : Resa;
  const int* ridx = sB ? ridxb : ridxa;
  const int M = sB ? Mb : Ma;  float* C = sB ? Cb : Ca;
  const int bid = sB ? ((int)blockIdx.x - split) : (int)blockIdx.x;

  constexpr int RT = BM / 16;
  constexpr int CW = NC / 16;
  constexpr int KB = 64;
  constexpr int CPP = KD / KB;
  constexpr int F4PR = KB / 4;
  constexpr int NAF4 = BM * KB / 4 / 256;
  constexpr int NWF4 = KB * NC / 4 / 256;
  __shared__ float sA[BM][KB + 4];
  __shared__ float sW[KB][NC];
  const int t  = threadIdx.x;
  const int ty = t >> 4, tx = t & 15;
  const int row0 = bid * BM;

  float acc[RT][CW];
  #pragma unroll
  for (int i = 0; i < RT; ++i)
    #pragma unroll
    for (int j = 0; j < CW; ++j) acc[i][j] = 0.f;

  for (int cc = 0; cc < CPP; ++cc) {
    const int kc = cc;
    if (cc) __syncthreads();
    {
      const float4* Wp = reinterpret_cast<const float4*>(W1) + (long)kc * (KB * NC / 4);
      #pragma unroll
      for (int q = 0; q < NWF4; ++q)
        reinterpret_cast<float4*>(&sW[0][0])[t + 256 * q] = Wp[t + 256 * q];
    }
    #pragma unroll
    for (int q = 0; q < NAF4; ++q) {
      int p  = t + 256 * q;
      int r  = p / F4PR, c4 = p % F4PR;
      float4 v = make_float4(0.f, 0.f, 0.f, 0.f);
      int gr = row0 + r;
      if (gr < M) {
        v = reinterpret_cast<const float4*>(A1 + (long)gr * KD)[kc * F4PR + c4];
      }
      *reinterpret_cast<float4*>(&sA[r][c4 * 4]) = v;
    }
    __syncthreads();
    #pragma unroll 4
    for (int k4 = 0; k4 < KB; k4 += 4) {
      float4 a4[RT];
      #pragma unroll
      for (int i = 0; i < RT; ++i)
        a4[i] = *reinterpret_cast<const float4*>(&sA[ty + 16 * i][k4]);
      #pragma unroll
      for (int kk = 0; kk < 4; ++kk) {
        float wv[CW];
        #pragma unroll
        for (int h = 0; h < CW / 4; ++h) {
          float4 w4 = *reinterpret_cast<const float4*>(&sW[k4 + kk][tx * 4 + 64 * h]);
          wv[h*4+0] = w4.x; wv[h*4+1] = w4.y; wv[h*4+2] = w4.z; wv[h*4+3] = w4.w;
        }
        #pragma unroll
        for (int i = 0; i < RT; ++i) {
          float a = (kk == 0) ? a4[i].x : (kk == 1) ? a4[i].y : (kk == 2) ? a4[i].z : a4[i].w;
          #pragma unroll
          for (int j = 0; j < CW; ++j)
            acc[i][j] = fmaf(a, wv[j], acc[i][j]);
        }
      }
    }
  }
  #pragma unroll
  for (int i = 0; i < RT; ++i) {
    int gr = row0 + ty + 16 * i;
    if (gr >= M) continue;
    long rrow = (long)ridx[gr];
    #pragma unroll
    for (int h = 0; h < CW / 4; ++h) {
      int c = tx * 4 + 64 * h;
      float4 v = make_float4(acc[i][h*4+0], acc[i][h*4+1], acc[i][h*4+2], acc[i][h*4+3]);
      v.x = (v.x > 0.f) ? v.x : (__expf(v.x) - 1.f);
      v.y = (v.y > 0.f) ? v.y : (__expf(v.y) - 1.f);
      v.z = (v.z > 0.f) ? v.z : (__expf(v.z) - 1.f);
      v.w = (v.w > 0.f) ? v.w : (__expf(v.w) - 1.f);
      float4 rv = *reinterpret_cast<const float4*>(Res + rrow * NC + c);
      v.x += rv.x; v.y += rv.y; v.z += rv.z; v.w += rv.w;
      *reinterpret_cast<float4*>(C + (long)gr * NC + c) = v;
    }
  }
}

// ---------------- needed-dst flags: byte array + 1-bit mask (user gate) ----------
__global__ void flags_kernel(const int* __restrict__ ui, const int* __restrict__ ii, int B,
                             unsigned char* __restrict__ nfu, unsigned char* __restrict__ nfb,
                             unsigned* __restrict__ mku)
{
  int i = blockIdx.x * blockDim.x + threadIdx.x;
  if (i < B) {
    int u = ui[i], v = ii[i];
    nfu[u] = 1; nfb[v] = 1;
    atomicOr(&mku[u >> 5], 1u << (u & 31));
  }
}

// ---------------- user pass 1: 16 edges/thread; bitmask gate; atomic rel ----------
__global__ __launch_bounds__(256) void edge_prep_u(
    const int* __restrict__ src, const int* __restrict__ dst,
    const float* __restrict__ as_, const float* __restrict__ an_,
    const unsigned* __restrict__ mk,
    int* __restrict__ deg, int4* __restrict__ cmp, int* __restrict__ blkcnt, int E)
{
  __shared__ int lcnt;
  if (threadIdx.x == 0) lcnt = 0;
  __syncthreads();
  const int lane = threadIdx.x & 63;
  const int bid = (int)blockIdx.x;
  const long base = (long)bid * 4096;
  const int e0 = (int)base + threadIdx.x * 16;

  int d[16], s[16];
  bool act[16];
  const bool full = (e0 + 15 < E);
  if (full) {
    #pragma unroll
    for (int q = 0; q < 4; ++q) {
      int4 d4 = *reinterpret_cast<const int4*>(dst + e0 + q * 4);
      int4 s4 = *reinterpret_cast<const int4*>(src + e0 + q * 4);
      d[q*4+0]=d4.x; d[q*4+1]=d4.y; d[q*4+2]=d4.z; d[q*4+3]=d4.w;
      s[q*4+0]=s4.x; s[q*4+1]=s4.y; s[q*4+2]=s4.z; s[q*4+3]=s4.w;
    }
    #pragma unroll
    for (int j = 0; j < 16; ++j) act[j] = true;
  } else {
    #pragma unroll
    for (int j = 0; j < 16; ++j) {
      act[j] = (e0 + j < E);
      d[j] = act[j] ? dst[e0 + j] : 0;
      s[j] = act[j] ? src[e0 + j] : 0;
    }
  }
  unsigned mw[16];
  #pragma unroll
  for (int j = 0; j < 16; ++j) mw[j] = mk[d[j] >> 5];
  #pragma unroll
  for (int j = 0; j < 16; ++j) act[j] = act[j] && ((mw[j] >> (d[j] & 31)) & 1u);

  float vas[16], van[16];
  #pragma unroll
  for (int j = 0; j < 16; ++j) vas[j] = act[j] ? as_[d[j]] : 0.f;
  #pragma unroll
  for (int j = 0; j < 16; ++j) van[j] = act[j] ? an_[s[j]] : 0.f;
  float sc[16];
  #pragma unroll
  for (int j = 0; j < 16; ++j) {
    float v = vas[j] + van[j];
    v = (v >= 0.f) ? v : 0.2f * v;       // leaky_relu 0.2
    sc[j] = __expf(v);
  }
  int tot = 0;
  #pragma unroll
  for (int j = 0; j < 16; ++j) tot += __popcll(__ballot(act[j]));
  int wb = 0;
  if (lane == 0) wb = atomicAdd(&lcnt, tot);
  wb = __shfl(wb, 0, 64);
  #pragma unroll
  for (int j = 0; j < 16; ++j) {
    unsigned long long m = __ballot(act[j]);
    if (act[j]) {
      int pref = __popcll(m & ((1ull << lane) - 1ull));
      int rel = atomicAdd(&deg[d[j]], 1);
      cmp[base + wb + pref] = make_int4(s[j], d[j], rel, __float_as_int(sc[j]));
    }
    wb += __popcll(m);
  }
  __syncthreads();
  if (threadIdx.x == 0) blkcnt[bid] = lcnt;
}

// ---------------- dual pass 2: 4 node-groups per wave, ONE atomic pair per wave ----------
// EXACT round-26 logic (proven).
__global__ __launch_bounds__(256) void offset_dual(
    int split,
    const unsigned char* __restrict__ flA, int* __restrict__ degA,
    int* __restrict__ offsA, int* __restrict__ dlA, int* __restrict__ g2cA,
    int* __restrict__ cntA, int NA,
    const unsigned char* __restrict__ flB, int* __restrict__ degB,
    const int* __restrict__ sstartB, const int* __restrict__ sendB,
    int* __restrict__ offsB, int* __restrict__ dlB, int* __restrict__ g2cB,
    int* __restrict__ cntB, int NB)
{
  const bool sB = (int)blockIdx.x >= split;
  const unsigned char* flag = sB ? flB : flA;
  int* deg = sB ? degB : degA;
  int* offs = sB ? offsB : offsA;  int* dlist = sB ? dlB : dlA;
  int* g2c = sB ? g2cB : g2cA;     int* cnt = sB ? cntB : cntA;
  const int N = sB ? NB : NA;
  const int bid = sB ? ((int)blockIdx.x - split) : (int)blockIdx.x;
  const int lane = threadIdx.x & 63;

  int idx[4], dg[4], exc[4], prf[4], nwq[4], tq[4];
  bool av[4];
  int wn = 0, wt = 0;
  #pragma unroll
  for (int q = 0; q < 4; ++q) {
    int i = bid * 1024 + q * 256 + (int)threadIdx.x;
    idx[q] = i;
    bool a = (i < N) && flag[i];
    int dgv = 0;
    if (a) {
      if (sB) { dgv = sendB[i] - sstartB[i]; deg[i] = dgv; }
      else dgv = deg[i];
    }
    av[q] = a; dg[q] = dgv;
    unsigned long long m = __ballot(a);
    nwq[q] = __popcll(m);
    prf[q] = __popcll(m & ((1ull << lane) - 1ull));
    int inc = dgv;
    #pragma unroll
    for (int o = 1; o < 64; o <<= 1) {
      int v = __shfl_up(inc, o, 64);
      if (lane >= o) inc += v;
    }
    tq[q] = __shfl(inc, 63, 64);
    exc[q] = inc - dgv;
    wn += nwq[q]; wt += tq[q];
  }
  int baseL = 0, baseE = 0;
  if (lane == 0) {
    baseL = wn ? atomicAdd(&cnt[1], wn) : 0;
    baseE = wt ? atomicAdd(&cnt[0], wt) : 0;
  }
  baseL = __shfl(baseL, 0, 64);
  baseE = __shfl(baseE, 0, 64);
  int runN = 0, runE = 0;
  #pragma unroll
  for (int q = 0; q < 4; ++q) {
    if (av[q]) {
      int i = idx[q];
      int l = baseL + runN + prf[q];
      g2c[i] = l;
      dlist[l] = i;
      if (dg[q] > 0) offs[i] = baseE + runE + exc[q];
    }
    runN += nwq[q]; runE += tq[q];
  }
}

// ---------------- user pass 3: place packed (src,p) — no atomics ----------
__global__ __launch_bounds__(256) void place_u(
    const int4* __restrict__ cmp, const int* __restrict__ blkcnt,
    const int* __restrict__ offs, int2* __restrict__ eline)
{
  int nb = blkcnt[blockIdx.x];
  const long base = (long)blockIdx.x * 4096;
  for (int k = threadIdx.x; k < nb; k += 256) {
    int4 c = cmp[base + k];
    int pos = offs[c.y] + c.z;
    eline[pos] = make_int2(c.x, c.w);
  }
}

// ---------------- item edge scoring: one wave per ACTIVE dst (sorted segments) ----------
__global__ __launch_bounds__(256) void edge_scoreb(
    const int* __restrict__ src, const float* __restrict__ as_, const float* __restrict__ an_,
    const float* __restrict__ gc, const float* __restrict__ omega,
    const int* __restrict__ dl, const int* __restrict__ cnt, const int* __restrict__ offs,
    const int* __restrict__ sstart, const int* __restrict__ send,
    int2* __restrict__ eline)
{
  int wid  = (int)blockIdx.x * 4 + (int)(threadIdx.x >> 6);
  int lane = threadIdx.x & 63;
  if (wid >= cnt[1]) return;
  int d = dl[wid];
  int st = sstart[d], en = send[d];
  int n = en - st;
  if (n <= 0) return;
  int ob = offs[d];
  float asd = as_[d];
  float o0 = omega[0], o1 = omega[1], o2 = omega[2];
  for (int i = lane; i < n; i += 64) {
    long e = st + i;
    int s = src[e];
    float uw = gc[e*3+0]*o0 + gc[e*3+1]*o1 + gc[e*3+2]*o2;
    float v = (asd + an_[s]) * uw;
    v = (v >= 0.f) ? v : 0.2f * v;       // leaky_relu 0.2
    eline[ob + i] = make_int2(s, __float_as_int(__expf(v)));
  }
}

// ---------------- dual wave-per-dst softmax + aggregation (bf16 H1 reads) ----------
__global__ __launch_bounds__(256) void aggr_dual(
    int split,
    const int* __restrict__ dlA, const int* __restrict__ cntA,
    const int* __restrict__ offsA, const int* __restrict__ degA,
    const int2* __restrict__ elA, const unsigned short* __restrict__ H1A, float* __restrict__ HoA,
    const int* __restrict__ dlB, const int* __restrict__ cntB,
    const int* __restrict__ offsB, const int* __restrict__ degB,
    const int2* __restrict__ elB, const unsigned short* __restrict__ H1B, float* __restrict__ HoB)
{
  const bool sB = (int)blockIdx.x >= split;
  const int* dlist = sB ? dlB : dlA;  const int* cnt = sB ? cntB : cntA;
  const int* offs = sB ? offsB : offsA;  const int* deg = sB ? degB : degA;
  const int2* eline = sB ? elB : elA;
  const unsigned short* H1 = sB ? H1B : H1A;  float* Houtc = sB ? HoB : HoA;
  const int bid = sB ? ((int)blockIdx.x - split) : (int)blockIdx.x;

  int wid  = bid * 4 + (int)(threadIdx.x >> 6);
  int lane = threadIdx.x & 63;
  if (wid >= cnt[1]) return;
  int d = dlist[wid];
  int n = deg[d];
  float2* op = reinterpret_cast<float2*>(Houtc + (long)wid * KD) + lane;
  if (n == 0) { *op = make_float2(0.f, 0.f); return; }
  int st = offs[d];
  float ssum = 0.f;
  for (int i = lane; i < n; i += 64) ssum += __int_as_float(eline[st + i].y);
  #pragma unroll
  for (int o = 32; o; o >>= 1) ssum += __shfl_xor(ssum, o, 64);
  float inv = 1.f / ssum;
  float ax = 0.f, ay = 0.f;
  int i = 0;
  for (; i + 4 <= n; i += 4) {
    int2 e0 = eline[st + i], e1 = eline[st + i + 1], e2 = eline[st + i + 2], e3 = eline[st + i + 3];
    float a0 = __int_as_float(e0.y);
    float a1 = __int_as_float(e1.y);
    float a2 = __int_as_float(e2.y);
    float a3 = __int_as_float(e3.y);
    unsigned u0 = *reinterpret_cast<const unsigned*>(H1 + (long)e0.x * KD + lane * 2);
    unsigned u1 = *reinterpret_cast<const unsigned*>(H1 + (long)e1.x * KD + lane * 2);
    unsigned u2 = *reinterpret_cast<const unsigned*>(H1 + (long)e2.x * KD + lane * 2);
    unsigned u3 = *reinterpret_cast<const unsigned*>(H1 + (long)e3.x * KD + lane * 2);
    ax = fmaf(__uint_as_float(u0 << 16), a0, ax); ay = fmaf(__uint_as_float(u0 & 0xffff0000u), a0, ay);
    ax = fmaf(__uint_as_float(u1 << 16), a1, ax); ay = fmaf(__uint_as_float(u1 & 0xffff0000u), a1, ay);
    ax = fmaf(__uint_as_float(u2 << 16), a2, ax); ay = fmaf(__uint_as_float(u2 & 0xffff0000u), a2, ay);
    ax = fmaf(__uint_as_float(u3 << 16), a3, ax); ay = fmaf(__uint_as_float(u3 & 0xffff0000u), a3, ay);
  }
  for (; i < n; ++i) {
    int2 e0 = eline[st + i];
    float a0 = __int_as_float(e0.y);
    unsigned u0 = *reinterpret_cast<const unsigned*>(H1 + (long)e0.x * KD + lane * 2);
    ax = fmaf(__uint_as_float(u0 << 16), a0, ax); ay = fmaf(__uint_as_float(u0 & 0xffff0000u), a0, ay);
  }
  *op = make_float2(ax * inv, ay * inv);
}

// ---------------- final: dot + biases + sigmoid -------------
__global__ __launch_bounds__(256) void final_kernel(
    const float* __restrict__ Ug, const float* __restrict__ Bg,
    const int* __restrict__ ui, const int* __restrict__ ii,
    const float* __restrict__ bias_u, const float* __restrict__ bias_b,
    const float* __restrict__ bx, float* __restrict__ out, int B)
{
  int wid  = (int)((blockIdx.x * 256 + threadIdx.x) >> 6);
  int lane = threadIdx.x & 63;
  if (wid >= B) return;
  float v = Ug[(long)wid * 64 + lane] * Bg[(long)wid * 64 + lane];
  #pragma unroll
  for (int o = 32; o > 0; o >>= 1) v += __shfl_xor(v, o, 64);
  if (lane == 0) {
    float raw = v + bias_u[ui[wid]] + bias_b[ii[wid]] + bx[0];
    out[wid] = 4.f / (1.f + __expf(-raw)) + 1.f;
  }
}

extern "C" void kernel_launch(void* const* d_in, const int* in_sizes, int n_in,
                              void* d_out, int out_size, void* d_ws, size_t ws_size,
                              hipStream_t stream)
{
  const int*   ui    = (const int*)  d_in[0];
  const int*   ii    = (const int*)  d_in[1];
  const float* S_u   = (const float*)d_in[2];
  const float* S_b   = (const float*)d_in[3];
  const int*   eu    = (const int*)  d_in[4];
  const int*   eb    = (const int*)  d_in[5];
  const float* gc    = (const float*)d_in[6];
  const float* W1_u  = (const float*)d_in[7];
  const float* a_s_u = (const float*)d_in[8];
  const float* a_n_u = (const float*)d_in[9];
  const float* W1_b  = (const float*)d_in[10];
  const float* a_s_b = (const float*)d_in[11];
  const float* a_n_b = (const float*)d_in[12];
  const float* omega = (const float*)d_in[13];
  const float* W_u2  = (const float*)d_in[14];
  const float* W_us2w= (const float*)d_in[15];
  const float* W_us2b= (const float*)d_in[16];
  const float* W_b2  = (const float*)d_in[17];
  const float* W_bs2w= (const float*)d_in[18];
  const float* W_bs2b= (const float*)d_in[19];
  const float* W_u3  = (const float*)d_in[20];
  const float* W_b3  = (const float*)d_in[21];
  const float* H_u4  = (const float*)d_in[22];
  const float* H_b4  = (const float*)d_in[23];
  const float* bias_u= (const float*)d_in[24];
  const float* bias_b= (const float*)d_in[25];
  const float* b_x   = (const float*)d_in[26];
  float* out = (float*)d_out;

  const int B  = in_sizes[0];
  const int NU = in_sizes[2] / KD;
  const int NI = in_sizes[3] / KD;
  const int EU = in_sizes[4] / 2;
  const int EB = in_sizes[5] / 2;
  const int GPU_ = (EU + 4095) / 4096;
  const int G1U = (NU + 63) / 64, G1I = (NI + 63) / 64;
  const int GO4U = (NU + 1023) / 1024, GO4I = (NI + 1023) / 1024;
  const int GAG = (B + 3) / 4;
  const int GB  = (B + 63) / 64;

  char* w = (char*)d_ws;
  auto alloc = [&](size_t bytes) -> void* {
    void* r = (void*)w;
    w += (bytes + 255) & ~(size_t)255;
    return r;
  };
  // ---- zero-initialized region (one small memset per call) ----
  int* deg_u = (int*)alloc((size_t)NU * 4);
  int* deg_b = (int*)alloc((size_t)NI * 4);
  unsigned char* nfu = (unsigned char*)alloc((size_t)NU);
  unsigned char* nfb = (unsigned char*)alloc((size_t)NI);
  unsigned* mku = (unsigned*)alloc((size_t)((NU + 31) / 32) * 4);
  int* sst_b = (int*)alloc((size_t)NI * 4);
  int* snd_b = (int*)alloc((size_t)NI * 4);
  int* cnt   = (int*)alloc(16 * 4);
  size_t zbytes = (size_t)(w - (char*)d_ws);
  // ---- scratch ----
  unsigned short* wt = (unsigned short*)alloc((size_t)6 * 16384 * 2);
  int*   offs_u = (int*)  alloc((size_t)NU * 4);
  int*   offs_b = (int*)  alloc((size_t)NI * 4);
  int*   g2c_u  = (int*)  alloc((size_t)NU * 4);
  int*   g2c_b  = (int*)  alloc((size_t)NI * 4);
  int*   dl_u   = (int*)  alloc((size_t)B * 4);
  int*   dl_b   = (int*)  alloc((size_t)B * 4);
  int*   bc_u   = (int*)  alloc((size_t)GPU_ * 4);
  int4*  cmp_u  = (int4*) alloc((size_t)GPU_ * 4096 * 16);
  int2*  el_u   = (int2*) alloc((size_t)EU * 8);
  int2*  el_b   = (int2*) alloc((size_t)EB * 8);
  unsigned short* H1u = (unsigned short*)alloc((size_t)NU * KD * 2);
  unsigned short* H1b = (unsigned short*)alloc((size_t)NI * KD * 2);
  float* Hu2c = (float*)alloc((size_t)B * KD * 4);
  float* Hb2c = (float*)alloc((size_t)B * KD * 4);
  float* asu  = (float*)alloc((size_t)NU * 4);
  float* anu  = (float*)alloc((size_t)NU * 4);
  float* asb  = (float*)alloc((size_t)NI * 4);
  float* anb  = (float*)alloc((size_t)NI * 4);
  float* Hu3g = (float*)alloc((size_t)B * KD * 4);
  float* Hb3g = (float*)alloc((size_t)B * KD * 4);
  float* Ug   = (float*)alloc((size_t)B * 64 * 4);
  float* Bg   = (float*)alloc((size_t)B * 64 * 4);
  (void)ws_size; (void)n_in; (void)out_size;

  hipMemsetAsync(d_ws, 0, zbytes, stream);

  wsplit6<<<384, 256, 0, stream>>>(W1_u, W1_b, W_u2, W_us2w, W_b2, W_bs2w, wt);
  flags_kernel<<<(B + 255) / 256, 256, 0, stream>>>(ui, ii, B, nfu, nfb, mku);
  segb_kernel<<<(EB + 255) / 256, 256, 0, stream>>>(eb + EB, EB, sst_b, snd_b);

  // H1 = S @ W1: bf16 MFMA, fused proj + NaN sentinel
  mfma1_dual<<<G1U + G1I, 256, 0, stream>>>(
      G1U,
      S_u, wt + 0 * 16384, NU, H1u, a_s_u, a_n_u, asu, anu, nfu,
      S_b, wt + 1 * 16384, NI, H1b, a_s_b, a_n_b, asb, anb, nfb);

  // user side: score+count (atomic counting-sort)
  edge_prep_u<<<GPU_, 256, 0, stream>>>(
      eu, eu + EU, asu, anu, mku, deg_u, cmp_u, bc_u, EU);

  // both sides: compact dst list + segment offsets (item deg from sorted segs)
  offset_dual<<<GO4U + GO4I, 256, 0, stream>>>(
      GO4U,
      nfu, deg_u, offs_u, dl_u, g2c_u, cnt + 0, NU,
      nfb, deg_b, sst_b, snd_b, offs_b, dl_b, g2c_b, cnt + 2, NI);

  // user side: place packed entries
  place_u<<<GPU_, 256, 0, stream>>>(cmp_u, bc_u, offs_u, el_u);

  // item side: score directly per active dst (contiguous segment reads)
  edge_scoreb<<<GAG, 256, 0, stream>>>(
      eb, asb, anb, gc, omega, dl_b, cnt + 2, offs_b, sst_b, snd_b, el_b);

  aggr_dual<<<GAG * 2, 256, 0, stream>>>(
      GAG,
      dl_u, cnt + 0, offs_u, deg_u, el_u, H1u, Hu2c,
      dl_b, cnt + 2, offs_b, deg_b, el_b, H1b, Hb2c);

  // H3 = elu(Hu2c[g2c[ui]]@W_u2 + S_u[ui]@W_us2w + b): bf16 MFMA, 2 passes
  mfma2_dual<<<GB * 2, 256, 0, stream>>>(
      GB,
      Hu2c, wt + 2 * 16384, S_u, wt + 3 * 16384, W_us2b, ui, g2c_u, B, Hu3g,
      Hb2c, wt + 4 * 16384, S_b, wt + 5 * 16384, W_bs2b, ii, g2c_b, B, Hb3g);

  // U = elu(H3 @ W3) + H4[idx]: fp32, NC=64 (absmax margin)
  gemm3_dual<64,64><<<GB * 2, 256, 0, stream>>>(
      GB,
      Hu3g, W_u3, H_u4, ui, B, Ug,
      Hb3g, W_b3, H_b4, ii, B, Bg);

  final_kernel<<<(B + 3) / 4, 256, 0, stream>>>(Ug, Bg, ui, ii, bias_u, bias_b, b_x, out, B);
}

// Round 29
// 177.937 us; speedup vs baseline: 1.4758x; 1.0439x over previous
//
#include <hip/hip_runtime.h>
#include <hip/hip_bf16.h>

#define KD 128
#define NANF __int_as_float(0x7fc00000)

typedef __attribute__((ext_vector_type(8))) short bf16x8;
typedef __attribute__((ext_vector_type(4))) float f32x4;

__device__ __forceinline__ unsigned short f2b(float x) {  // fp32 -> bf16 RNE
  unsigned u = __float_as_uint(x);
  return (unsigned short)((u + 0x7fffu + ((u >> 16) & 1u)) >> 16);
}
__device__ __forceinline__ int swz(int row, int kbyte) {  // LDS byte addr, G4 XOR swizzle
  return (row * 256 + kbyte) ^ ((row & 7) << 4);
}

// ---------------- one-shot: transpose+convert six 128x128 W to bf16 Wt[n][k] ----------------
__global__ __launch_bounds__(256) void wsplit6(
    const float* __restrict__ w0, const float* __restrict__ w1,
    const float* __restrict__ w2, const float* __restrict__ w3,
    const float* __restrict__ w4, const float* __restrict__ w5,
    unsigned short* __restrict__ oh)
{
  int m = blockIdx.x >> 6;
  int idx = (blockIdx.x & 63) * 256 + threadIdx.x;   // n*128 + k
  const float* ws;
  switch (m) { case 0: ws = w0; break; case 1: ws = w1; break; case 2: ws = w2; break;
               case 3: ws = w3; break; case 4: ws = w4; break; default: ws = w5; }
  int n = idx >> 7, k = idx & 127;
  oh[(long)m * 16384 + idx] = f2b(ws[k * 128 + n]);
}

// ---------------- item-graph segment boundaries (dst is sorted ascending) ----------------
__global__ __launch_bounds__(256) void segb_kernel(
    const int* __restrict__ dst, int E,
    int* __restrict__ sstart, int* __restrict__ send)
{
  int e = blockIdx.x * 256 + threadIdx.x;
  if (e >= E) return;
  int d = dst[e];
  if (e == 0 || dst[e - 1] != d) sstart[d] = e;
  if (e == E - 1 || dst[e + 1] != d) send[d] = e + 1;
}

// ---------------- gemm1: dual-grid bf16 MFMA; W fragments in registers (L2-hot), A in LDS ----
__global__ __launch_bounds__(256, 4) void mfma1_dual(
    int split,
    const float* __restrict__ Aa, const unsigned short* __restrict__ Wta, int Ma,
    unsigned short* __restrict__ Ca,
    const float* __restrict__ a_sa, const float* __restrict__ a_na,
    float* __restrict__ as_oa, float* __restrict__ an_oa, const unsigned char* __restrict__ fla,
    const float* __restrict__ Ab, const unsigned short* __restrict__ Wtb, int Mb,
    unsigned short* __restrict__ Cb,
    const float* __restrict__ a_sb, const float* __restrict__ a_nb,
    float* __restrict__ as_ob, float* __restrict__ an_ob, const unsigned char* __restrict__ flb)
{
  const bool sB = (int)blockIdx.x >= split;
  const float* A = sB ? Ab : Aa;
  const unsigned short* Wt = sB ? Wtb : Wta;
  const int M = sB ? Mb : Ma;
  unsigned short* C = sB ? Cb : Ca;
  const float* a_s = sB ? a_sb : a_sa;  const float* a_n = sB ? a_nb : a_na;
  float* as_o = sB ? as_ob : as_oa;     float* an_o = sB ? an_ob : an_oa;
  const unsigned char* fl = sB ? flb : fla;
  const int bid = sB ? ((int)blockIdx.x - split) : (int)blockIdx.x;

  __shared__ unsigned short sA[8192];    // 16KB
  __shared__ float pp[4][64][2];         // 2KB

  const int t = threadIdx.x;
  const int w = t >> 6, l = t & 63;
  const int lr = l & 15, lk = l >> 4;
  const int row0 = bid * 64;
  char* sAc = reinterpret_cast<char*>(sA);

  // B fragments direct global->register: every block reads the same 32KB W (L2/L3-hot).
  bf16x8 bw[4][2];
  #pragma unroll
  for (int kc = 0; kc < 4; ++kc)
    #pragma unroll
    for (int tt = 0; tt < 2; ++tt) {
      int n = (w * 2 + tt) * 16 + lr;
      bw[kc][tt] = *reinterpret_cast<const bf16x8*>(Wt + n * 128 + kc * 32 + lk * 8);
    }

  #pragma unroll
  for (int q = 0; q < 4; ++q) {
    int p = t + 256 * q;
    int r = p >> 4, c16 = p & 15;
    int gr = row0 + r;
    bf16x8 hv;
    if (gr < M) {
      const float4* ap = reinterpret_cast<const float4*>(A + (long)gr * KD + c16 * 8);
      float4 v0 = ap[0], v1 = ap[1];
      hv[0]=(short)f2b(v0.x); hv[1]=(short)f2b(v0.y); hv[2]=(short)f2b(v0.z); hv[3]=(short)f2b(v0.w);
      hv[4]=(short)f2b(v1.x); hv[5]=(short)f2b(v1.y); hv[6]=(short)f2b(v1.z); hv[7]=(short)f2b(v1.w);
    } else {
      #pragma unroll
      for (int j = 0; j < 8; ++j) hv[j] = 0;
    }
    *reinterpret_cast<bf16x8*>(sAc + swz(r, c16 * 16)) = hv;
  }
  __syncthreads();

  f32x4 acc[4][2];
  #pragma unroll
  for (int i = 0; i < 4; ++i)
    #pragma unroll
    for (int tt = 0; tt < 2; ++tt) acc[i][tt] = (f32x4){0.f, 0.f, 0.f, 0.f};

  #pragma unroll
  for (int kc = 0; kc < 4; ++kc) {
    const int kb = (kc * 32 + lk * 8) * 2;
    bf16x8 af[4];
    #pragma unroll
    for (int i = 0; i < 4; ++i)
      af[i] = *reinterpret_cast<const bf16x8*>(sAc + swz(i * 16 + lr, kb));
    #pragma unroll
    for (int tt = 0; tt < 2; ++tt) {
      #pragma unroll
      for (int i = 0; i < 4; ++i)
        acc[i][tt] = __builtin_amdgcn_mfma_f32_16x16x32_bf16(af[i], bw[kc][tt], acc[i][tt], 0, 0, 0);
    }
  }

  float asv[2], anv[2];
  #pragma unroll
  for (int tt = 0; tt < 2; ++tt) {
    int col = (w * 2 + tt) * 16 + lr;
    asv[tt] = a_s[col]; anv[tt] = a_n[col];
  }
  #pragma unroll
  for (int i = 0; i < 4; ++i) {
    #pragma unroll
    for (int r = 0; r < 4; ++r) {
      float ds = acc[i][0][r] * asv[0] + acc[i][1][r] * asv[1];
      float dn = acc[i][0][r] * anv[0] + acc[i][1][r] * anv[1];
      #pragma unroll
      for (int o = 1; o < 16; o <<= 1) { ds += __shfl_xor(ds, o, 64); dn += __shfl_xor(dn, o, 64); }
      if (lr == 0) {
        int row = i * 16 + lk * 4 + r;
        pp[w][row][0] = ds; pp[w][row][1] = dn;
      }
    }
  }
  #pragma unroll
  for (int i = 0; i < 4; ++i) {
    #pragma unroll
    for (int r = 0; r < 4; ++r) {
      int gr = row0 + i * 16 + lk * 4 + r;
      if (gr >= M) continue;
      #pragma unroll
      for (int tt = 0; tt < 2; ++tt) {
        int col = (w * 2 + tt) * 16 + lr;
        C[(long)gr * 128 + col] = f2b(acc[i][tt][r]);
      }
    }
  }
  __syncthreads();
  if (t < 64) {
    int gr = row0 + t;
    if (gr < M) {
      float ds = pp[0][t][0] + pp[1][t][0] + pp[2][t][0] + pp[3][t][0];
      float dn = pp[0][t][1] + pp[1][t][1] + pp[2][t][1] + pp[3][t][1];
      as_o[gr] = fl[gr] ? ds : NANF;
      an_o[gr] = dn;
    }
  }
}

// ---------------- gemm2: dual-grid bf16 MFMA, 2 accumulate passes, gathered A ----------------
__global__ __launch_bounds__(256, 3) void mfma2_dual(
    int split,
    const float* __restrict__ A1a, const unsigned short* __restrict__ W1ta,
    const float* __restrict__ A2a, const unsigned short* __restrict__ W2ta,
    const float* __restrict__ biasa, const int* __restrict__ aidxa,
    const int* __restrict__ map1a, int Ma, float* __restrict__ Ca,
    const float* __restrict__ A1b, const unsigned short* __restrict__ W1tb,
    const float* __restrict__ A2b, const unsigned short* __restrict__ W2tb,
    const float* __restrict__ biasb, const int* __restrict__ aidxb,
    const int* __restrict__ map1b, int Mb, float* __restrict__ Cb)
{
  const bool sB = (int)blockIdx.x >= split;
  const float* A1 = sB ? A1b : A1a;  const unsigned short* W1t = sB ? W1tb : W1ta;
  const float* A2 = sB ? A2b : A2a;  const unsigned short* W2t = sB ? W2tb : W2ta;
  const float* bias = sB ? biasb : biasa;
  const int* aidx = sB ? aidxb : aidxa;  const int* map1 = sB ? map1b : map1a;
  const int M = sB ? Mb : Ma;  float* C = sB ? Cb : Ca;
  const int bid = sB ? ((int)blockIdx.x - split) : (int)blockIdx.x;

  __shared__ unsigned short sW[16384];   // 32KB
  __shared__ unsigned short sA[8192];    // 16KB

  const int t = threadIdx.x;
  const int w = t >> 6, l = t & 63;
  const int lr = l & 15, lk = l >> 4;
  const int row0 = bid * 64;
  char* sWc = reinterpret_cast<char*>(sW);
  char* sAc = reinterpret_cast<char*>(sA);

  f32x4 acc[4][2];
  #pragma unroll
  for (int i = 0; i < 4; ++i)
    #pragma unroll
    for (int tt = 0; tt < 2; ++tt) acc[i][tt] = (f32x4){0.f, 0.f, 0.f, 0.f};

  #pragma unroll
  for (int pass = 0; pass < 2; ++pass) {
    const float* Am = pass ? A2 : A1;
    const unsigned short* Wt = pass ? W2t : W1t;
    if (pass) __syncthreads();
    #pragma unroll
    for (int q = 0; q < 8; ++q) {
      int p = t + 256 * q;
      int n = p >> 4, c16 = p & 15;
      bf16x8 v = *reinterpret_cast<const bf16x8*>(Wt + n * 128 + c16 * 8);
      *reinterpret_cast<bf16x8*>(sWc + swz(n, c16 * 16)) = v;
    }
    #pragma unroll
    for (int q = 0; q < 4; ++q) {
      int p = t + 256 * q;
      int r = p >> 4, c16 = p & 15;
      int gr = row0 + r;
      bf16x8 hv;
      if (gr < M) {
        long grow = (long)aidx[gr];
        if (pass == 0) grow = map1[grow];
        const float4* ap = reinterpret_cast<const float4*>(Am + grow * KD + c16 * 8);
        float4 v0 = ap[0], v1 = ap[1];
        hv[0]=(short)f2b(v0.x); hv[1]=(short)f2b(v0.y); hv[2]=(short)f2b(v0.z); hv[3]=(short)f2b(v0.w);
        hv[4]=(short)f2b(v1.x); hv[5]=(short)f2b(v1.y); hv[6]=(short)f2b(v1.z); hv[7]=(short)f2b(v1.w);
      } else {
        #pragma unroll
        for (int j = 0; j < 8; ++j) hv[j] = 0;
      }
      *reinterpret_cast<bf16x8*>(sAc + swz(r, c16 * 16)) = hv;
    }
    __syncthreads();
    #pragma unroll
    for (int kc = 0; kc < 4; ++kc) {
      const int kb = (kc * 32 + lk * 8) * 2;
      bf16x8 af[4];
      #pragma unroll
      for (int i = 0; i < 4; ++i)
        af[i] = *reinterpret_cast<const bf16x8*>(sAc + swz(i * 16 + lr, kb));
      #pragma unroll
      for (int tt = 0; tt < 2; ++tt) {
        int n = (w * 2 + tt) * 16 + lr;
        bf16x8 bfr = *reinterpret_cast<const bf16x8*>(sWc + swz(n, kb));
        #pragma unroll
        for (int i = 0; i < 4; ++i)
          acc[i][tt] = __builtin_amdgcn_mfma_f32_16x16x32_bf16(af[i], bfr, acc[i][tt], 0, 0, 0);
      }
    }
  }
  float bv[2];
  #pragma unroll
  for (int tt = 0; tt < 2; ++tt) bv[tt] = bias[(w * 2 + tt) * 16 + lr];
  #pragma unroll
  for (int i = 0; i < 4; ++i) {
    #pragma unroll
    for (int r = 0; r < 4; ++r) {
      int gr = row0 + i * 16 + lk * 4 + r;
      if (gr >= M) continue;
      #pragma unroll
      for (int tt = 0; tt < 2; ++tt) {
        int col = (w * 2 + tt) * 16 + lr;
        float v = acc[i][tt][r] + bv[tt];
        v = (v > 0.f) ? v : (__expf(v) - 1.f);
        C[(long)gr * 128 + col] = v;
      }
    }
  }
}

// ---------------- gemm3: dual-grid fp32, BM=64 NC=64, elu + gathered residual ----------
template<int BM, int NC>
__global__ __launch_bounds__(256, 3) void gemm3_dual(
    int split,
    const float* __restrict__ A1a, const float* __restrict__ W1a,
    const float* __restrict__ Resa, const int* __restrict__ ridxa, int Ma,
    float* __restrict__ Ca,
    const float* __restrict__ A1b, const float* __restrict__ W1b,
    const float* __restrict__ Resb, const int* __restrict__ ridxb, int Mb,
    float* __restrict__ Cb)
{
  const bool sB = (int)blockIdx.x >= split;
  const float* A1 = sB ? A1b : A1a;  const float* W1 = sB ? W1b : W1a;
  const float* Res = sB ? Resb : Resa;
  const int* ridx = sB ? ridxb : ridxa;
  const int M = sB ? Mb : Ma;  float* C = sB ? Cb : Ca;
  const int bid = sB ? ((int)blockIdx.x - split) : (int)blockIdx.x;

  constexpr int RT = BM / 16;
  constexpr int CW = NC / 16;
  constexpr int KB = 64;
  constexpr int CPP = KD / KB;
  constexpr int F4PR = KB / 4;
  constexpr int NAF4 = BM * KB / 4 / 256;
  constexpr int NWF4 = KB * NC / 4 / 256;
  __shared__ float sA[BM][KB + 4];
  __shared__ float sW[KB][NC];
  const int t  = threadIdx.x;
  const int ty = t >> 4, tx = t & 15;
  const int row0 = bid * BM;

  float acc[RT][CW];
  #pragma unroll
  for (int i = 0; i < RT; ++i)
    #pragma unroll
    for (int j = 0; j < CW; ++j) acc[i][j] = 0.f;

  for (int cc = 0; cc < CPP; ++cc) {
    const int kc = cc;
    if (cc) __syncthreads();
    {
      const float4* Wp = reinterpret_cast<const float4*>(W1) + (long)kc * (KB * NC / 4);
      #pragma unroll
      for (int q = 0; q < NWF4; ++q)
        reinterpret_cast<float4*>(&sW[0][0])[t + 256 * q] = Wp[t + 256 * q];
    }
    #pragma unroll
    for (int q = 0; q < NAF4; ++q) {
      int p  = t + 256 * q;
      int r  = p / F4PR, c4 = p % F4PR;
      float4 v = make_float4(0.f, 0.f, 0.f, 0.f);
      int gr = row0 + r;
      if (gr < M) {
        v = reinterpret_cast<const float4*>(A1 + (long)gr * KD)[kc * F4PR + c4];
      }
      *reinterpret_cast<float4*>(&sA[r][c4 * 4]) = v;
    }
    __syncthreads();
    #pragma unroll 4
    for (int k4 = 0; k4 < KB; k4 += 4) {
      float4 a4[RT];
      #pragma unroll
      for (int i = 0; i < RT; ++i)
        a4[i] = *reinterpret_cast<const float4*>(&sA[ty + 16 * i][k4]);
      #pragma unroll
      for (int kk = 0; kk < 4; ++kk) {
        float wv[CW];
        #pragma unroll
        for (int h = 0; h < CW / 4; ++h) {
          float4 w4 = *reinterpret_cast<const float4*>(&sW[k4 + kk][tx * 4 + 64 * h]);
          wv[h*4+0] = w4.x; wv[h*4+1] = w4.y; wv[h*4+2] = w4.z; wv[h*4+3] = w4.w;
        }
        #pragma unroll
        for (int i = 0; i < RT; ++i) {
          float a = (kk == 0) ? a4[i].x : (kk == 1) ? a4[i].y : (kk == 2) ? a4[i].z : a4[i].w;
          #pragma unroll
          for (int j = 0; j < CW; ++j)
            acc[i][j] = fmaf(a, wv[j], acc[i][j]);
        }
      }
    }
  }
  #pragma unroll
  for (int i = 0; i < RT; ++i) {
    int gr = row0 + ty + 16 * i;
    if (gr >= M) continue;
    long rrow = (long)ridx[gr];
    #pragma unroll
    for (int h = 0; h < CW / 4; ++h) {
      int c = tx * 4 + 64 * h;
      float4 v = make_float4(acc[i][h*4+0], acc[i][h*4+1], acc[i][h*4+2], acc[i][h*4+3]);
      v.x = (v.x > 0.f) ? v.x : (__expf(v.x) - 1.f);
      v.y = (v.y > 0.f) ? v.y : (__expf(v.y) - 1.f);
      v.z = (v.z > 0.f) ? v.z : (__expf(v.z) - 1.f);
      v.w = (v.w > 0.f) ? v.w : (__expf(v.w) - 1.f);
      float4 rv = *reinterpret_cast<const float4*>(Res + rrow * NC + c);
      v.x += rv.x; v.y += rv.y; v.z += rv.z; v.w += rv.w;
      *reinterpret_cast<float4*>(C + (long)gr * NC + c) = v;
    }
  }
}

// ---------------- needed-dst flags: byte array + 1-bit mask (user gate) ----------
__global__ void flags_kernel(const int* __restrict__ ui, const int* __restrict__ ii, int B,
                             unsigned char* __restrict__ nfu, unsigned char* __restrict__ nfb,
                             unsigned* __restrict__ mku)
{
  int i = blockIdx.x * blockDim.x + threadIdx.x;
  if (i < B) {
    int u = ui[i], v = ii[i];
    nfu[u] = 1; nfb[v] = 1;
    atomicOr(&mku[u >> 5], 1u << (u & 31));
  }
}

// ---------------- user pass 1: 16 edges/thread; bitmask gate; atomic rel ----------
__global__ __launch_bounds__(256) void edge_prep_u(
    const int* __restrict__ src, const int* __restrict__ dst,
    const float* __restrict__ as_, const float* __restrict__ an_,
    const unsigned* __restrict__ mk,
    int* __restrict__ deg, int4* __restrict__ cmp, int* __restrict__ blkcnt, int E)
{
  __shared__ int lcnt;
  if (threadIdx.x == 0) lcnt = 0;
  __syncthreads();
  const int lane = threadIdx.x & 63;
  const int bid = (int)blockIdx.x;
  const long base = (long)bid * 4096;
  const int e0 = (int)base + threadIdx.x * 16;

  int d[16], s[16];
  bool act[16];
  const bool full = (e0 + 15 < E);
  if (full) {
    #pragma unroll
    for (int q = 0; q < 4; ++q) {
      int4 d4 = *reinterpret_cast<const int4*>(dst + e0 + q * 4);
      int4 s4 = *reinterpret_cast<const int4*>(src + e0 + q * 4);
      d[q*4+0]=d4.x; d[q*4+1]=d4.y; d[q*4+2]=d4.z; d[q*4+3]=d4.w;
      s[q*4+0]=s4.x; s[q*4+1]=s4.y; s[q*4+2]=s4.z; s[q*4+3]=s4.w;
    }
    #pragma unroll
    for (int j = 0; j < 16; ++j) act[j] = true;
  } else {
    #pragma unroll
    for (int j = 0; j < 16; ++j) {
      act[j] = (e0 + j < E);
      d[j] = act[j] ? dst[e0 + j] : 0;
      s[j] = act[j] ? src[e0 + j] : 0;
    }
  }
  unsigned mw[16];
  #pragma unroll
  for (int j = 0; j < 16; ++j) mw[j] = mk[d[j] >> 5];
  #pragma unroll
  for (int j = 0; j < 16; ++j) act[j] = act[j] && ((mw[j] >> (d[j] & 31)) & 1u);

  float vas[16], van[16];
  #pragma unroll
  for (int j = 0; j < 16; ++j) vas[j] = act[j] ? as_[d[j]] : 0.f;
  #pragma unroll
  for (int j = 0; j < 16; ++j) van[j] = act[j] ? an_[s[j]] : 0.f;
  float sc[16];
  #pragma unroll
  for (int j = 0; j < 16; ++j) {
    float v = vas[j] + van[j];
    v = (v >= 0.f) ? v : 0.2f * v;       // leaky_relu 0.2
    sc[j] = __expf(v);
  }
  int tot = 0;
  #pragma unroll
  for (int j = 0; j < 16; ++j) tot += __popcll(__ballot(act[j]));
  int wb = 0;
  if (lane == 0) wb = atomicAdd(&lcnt, tot);
  wb = __shfl(wb, 0, 64);
  #pragma unroll
  for (int j = 0; j < 16; ++j) {
    unsigned long long m = __ballot(act[j]);
    if (act[j]) {
      int pref = __popcll(m & ((1ull << lane) - 1ull));
      int rel = atomicAdd(&deg[d[j]], 1);
      cmp[base + wb + pref] = make_int4(s[j], d[j], rel, __float_as_int(sc[j]));
    }
    wb += __popcll(m);
  }
  __syncthreads();
  if (threadIdx.x == 0) blkcnt[bid] = lcnt;
}

// ---------------- dual pass 2: 4 node-groups per wave, ONE atomic pair per wave ----------
// EXACT round-26 logic (proven).
__global__ __launch_bounds__(256) void offset_dual(
    int split,
    const unsigned char* __restrict__ flA, int* __restrict__ degA,
    int* __restrict__ offsA, int* __restrict__ dlA, int* __restrict__ g2cA,
    int* __restrict__ cntA, int NA,
    const unsigned char* __restrict__ flB, int* __restrict__ degB,
    const int* __restrict__ sstartB, const int* __restrict__ sendB,
    int* __restrict__ offsB, int* __restrict__ dlB, int* __restrict__ g2cB,
    int* __restrict__ cntB, int NB)
{
  const bool sB = (int)blockIdx.x >= split;
  const unsigned char* flag = sB ? flB : flA;
  int* deg = sB ? degB : degA;
  int* offs = sB ? offsB : offsA;  int* dlist = sB ? dlB : dlA;
  int* g2c = sB ? g2cB : g2cA;     int* cnt = sB ? cntB : cntA;
  const int N = sB ? NB : NA;
  const int bid = sB ? ((int)blockIdx.x - split) : (int)blockIdx.x;
  const int lane = threadIdx.x & 63;

  int idx[4], dg[4], exc[4], prf[4], nwq[4], tq[4];
  bool av[4];
  int wn = 0, wt = 0;
  #pragma unroll
  for (int q = 0; q < 4; ++q) {
    int i = bid * 1024 + q * 256 + (int)threadIdx.x;
    idx[q] = i;
    bool a = (i < N) && flag[i];
    int dgv = 0;
    if (a) {
      if (sB) { dgv = sendB[i] - sstartB[i]; deg[i] = dgv; }
      else dgv = deg[i];
    }
    av[q] = a; dg[q] = dgv;
    unsigned long long m = __ballot(a);
    nwq[q] = __popcll(m);
    prf[q] = __popcll(m & ((1ull << lane) - 1ull));
    int inc = dgv;
    #pragma unroll
    for (int o = 1; o < 64; o <<= 1) {
      int v = __shfl_up(inc, o, 64);
      if (lane >= o) inc += v;
    }
    tq[q] = __shfl(inc, 63, 64);
    exc[q] = inc - dgv;
    wn += nwq[q]; wt += tq[q];
  }
  int baseL = 0, baseE = 0;
  if (lane == 0) {
    baseL = wn ? atomicAdd(&cnt[1], wn) : 0;
    baseE = wt ? atomicAdd(&cnt[0], wt) : 0;
  }
  baseL = __shfl(baseL, 0, 64);
  baseE = __shfl(baseE, 0, 64);
  int runN = 0, runE = 0;
  #pragma unroll
  for (int q = 0; q < 4; ++q) {
    if (av[q]) {
      int i = idx[q];
      int l = baseL + runN + prf[q];
      g2c[i] = l;
      dlist[l] = i;
      if (dg[q] > 0) offs[i] = baseE + runE + exc[q];
    }
    runN += nwq[q]; runE += tq[q];
  }
}

// ---------------- user pass 3: place packed (src,p) — no atomics ----------
__global__ __launch_bounds__(256) void place_u(
    const int4* __restrict__ cmp, const int* __restrict__ blkcnt,
    const int* __restrict__ offs, int2* __restrict__ eline)
{
  int nb = blkcnt[blockIdx.x];
  const long base = (long)blockIdx.x * 4096;
  for (int k = threadIdx.x; k < nb; k += 256) {
    int4 c = cmp[base + k];
    int pos = offs[c.y] + c.z;
    eline[pos] = make_int2(c.x, c.w);
  }
}

// ---------------- item edge scoring: one wave per ACTIVE dst (sorted segments) ----------
__global__ __launch_bounds__(256) void edge_scoreb(
    const int* __restrict__ src, const float* __restrict__ as_, const float* __restrict__ an_,
    const float* __restrict__ gc, const float* __restrict__ omega,
    const int* __restrict__ dl, const int* __restrict__ cnt, const int* __restrict__ offs,
    const int* __restrict__ sstart, const int* __restrict__ send,
    int2* __restrict__ eline)
{
  int wid  = (int)blockIdx.x * 4 + (int)(threadIdx.x >> 6);
  int lane = threadIdx.x & 63;
  if (wid >= cnt[1]) return;
  int d = dl[wid];
  int st = sstart[d], en = send[d];
  int n = en - st;
  if (n <= 0) return;
  int ob = offs[d];
  float asd = as_[d];
  float o0 = omega[0], o1 = omega[1], o2 = omega[2];
  for (int i = lane; i < n; i += 64) {
    long e = st + i;
    int s = src[e];
    float uw = gc[e*3+0]*o0 + gc[e*3+1]*o1 + gc[e*3+2]*o2;
    float v = (asd + an_[s]) * uw;
    v = (v >= 0.f) ? v : 0.2f * v;       // leaky_relu 0.2
    eline[ob + i] = make_int2(s, __float_as_int(__expf(v)));
  }
}

// ---------------- dual wave-per-dst softmax + aggregation -------------------
// Lane-parallel eline prefetch (64 edges per coalesced load) + shfl broadcast:
// removes the eline->H1 dependent-load chain; H1 gathers unroll 8-deep.
// Summation order identical to previous version (ssum lane-strided; ax/ay in
// edge order 0..n-1 per lane) -> bit-identical output.
__global__ __launch_bounds__(256) void aggr_dual(
    int split,
    const int* __restrict__ dlA, const int* __restrict__ cntA,
    const int* __restrict__ offsA, const int* __restrict__ degA,
    const int2* __restrict__ elA, const unsigned short* __restrict__ H1A, float* __restrict__ HoA,
    const int* __restrict__ dlB, const int* __restrict__ cntB,
    const int* __restrict__ offsB, const int* __restrict__ degB,
    const int2* __restrict__ elB, const unsigned short* __restrict__ H1B, float* __restrict__ HoB)
{
  const bool sB = (int)blockIdx.x >= split;
  const int* dlist = sB ? dlB : dlA;  const int* cnt = sB ? cntB : cntA;
  const int* offs = sB ? offsB : offsA;  const int* deg = sB ? degB : degA;
  const int2* eline = sB ? elB : elA;
  const unsigned short* H1 = sB ? H1B : H1A;  float* Houtc = sB ? HoB : HoA;
  const int bid = sB ? ((int)blockIdx.x - split) : (int)blockIdx.x;

  int wid  = bid * 4 + (int)(threadIdx.x >> 6);
  int lane = threadIdx.x & 63;
  if (wid >= cnt[1]) return;
  int d = dlist[wid];
  int n = deg[d];
  float2* op = reinterpret_cast<float2*>(Houtc + (long)wid * KD) + lane;
  if (n == 0) { *op = make_float2(0.f, 0.f); return; }
  int st = offs[d];
  const unsigned* h1u = reinterpret_cast<const unsigned*>(H1) + lane;  // +s*64 per row

  float ssum = 0.f, ax = 0.f, ay = 0.f;
  for (int c = 0; c < n; c += 64) {
    int m = n - c; if (m > 64) m = 64;
    int2 ev = (lane < m) ? eline[st + c + lane] : make_int2(0, 0);
    ssum += __int_as_float(ev.y);        // lanes >= m add 0.0f (bit pattern 0)
    int i = 0;
    for (; i + 8 <= m; i += 8) {
      int   s0 = __shfl(ev.x, i + 0, 64), s1 = __shfl(ev.x, i + 1, 64);
      int   s2 = __shfl(ev.x, i + 2, 64), s3 = __shfl(ev.x, i + 3, 64);
      int   s4 = __shfl(ev.x, i + 4, 64), s5 = __shfl(ev.x, i + 5, 64);
      int   s6 = __shfl(ev.x, i + 6, 64), s7 = __shfl(ev.x, i + 7, 64);
      float a0 = __int_as_float(__shfl(ev.y, i + 0, 64));
      float a1 = __int_as_float(__shfl(ev.y, i + 1, 64));
      float a2 = __int_as_float(__shfl(ev.y, i + 2, 64));
      float a3 = __int_as_float(__shfl(ev.y, i + 3, 64));
      float a4 = __int_as_float(__shfl(ev.y, i + 4, 64));
      float a5 = __int_as_float(__shfl(ev.y, i + 5, 64));
      float a6 = __int_as_float(__shfl(ev.y, i + 6, 64));
      float a7 = __int_as_float(__shfl(ev.y, i + 7, 64));
      unsigned u0 = h1u[(long)s0 * 64], u1 = h1u[(long)s1 * 64];
      unsigned u2 = h1u[(long)s2 * 64], u3 = h1u[(long)s3 * 64];
      unsigned u4 = h1u[(long)s4 * 64], u5 = h1u[(long)s5 * 64];
      unsigned u6 = h1u[(long)s6 * 64], u7 = h1u[(long)s7 * 64];
      ax = fmaf(__uint_as_float(u0 << 16), a0, ax); ay = fmaf(__uint_as_float(u0 & 0xffff0000u), a0, ay);
      ax = fmaf(__uint_as_float(u1 << 16), a1, ax); ay = fmaf(__uint_as_float(u1 & 0xffff0000u), a1, ay);
      ax = fmaf(__uint_as_float(u2 << 16), a2, ax); ay = fmaf(__uint_as_float(u2 & 0xffff0000u), a2, ay);
      ax = fmaf(__uint_as_float(u3 << 16), a3, ax); ay = fmaf(__uint_as_float(u3 & 0xffff0000u), a3, ay);
      ax = fmaf(__uint_as_float(u4 << 16), a4, ax); ay = fmaf(__uint_as_float(u4 & 0xffff0000u), a4, ay);
      ax = fmaf(__uint_as_float(u5 << 16), a5, ax); ay = fmaf(__uint_as_float(u5 & 0xffff0000u), a5, ay);
      ax = fmaf(__uint_as_float(u6 << 16), a6, ax); ay = fmaf(__uint_as_float(u6 & 0xffff0000u), a6, ay);
      ax = fmaf(__uint_as_float(u7 << 16), a7, ax); ay = fmaf(__uint_as_float(u7 & 0xffff0000u), a7, ay);
    }
    for (; i < m; ++i) {
      int   s0 = __shfl(ev.x, i, 64);
      float a0 = __int_as_float(__shfl(ev.y, i, 64));
      unsigned u0 = h1u[(long)s0 * 64];
      ax = fmaf(__uint_as_float(u0 << 16), a0, ax); ay = fmaf(__uint_as_float(u0 & 0xffff0000u), a0, ay);
    }
  }
  #pragma unroll
  for (int o = 32; o; o >>= 1) ssum += __shfl_xor(ssum, o, 64);
  float inv = 1.f / ssum;
  *op = make_float2(ax * inv, ay * inv);
}

// ---------------- final: dot + biases + sigmoid -------------
__global__ __launch_bounds__(256) void final_kernel(
    const float* __restrict__ Ug, const float* __restrict__ Bg,
    const int* __restrict__ ui, const int* __restrict__ ii,
    const float* __restrict__ bias_u, const float* __restrict__ bias_b,
    const float* __restrict__ bx, float* __restrict__ out, int B)
{
  int wid  = (int)((blockIdx.x * 256 + threadIdx.x) >> 6);
  int lane = threadIdx.x & 63;
  if (wid >= B) return;
  float v = Ug[(long)wid * 64 + lane] * Bg[(long)wid * 64 + lane];
  #pragma unroll
  for (int o = 32; o > 0; o >>= 1) v += __shfl_xor(v, o, 64);
  if (lane == 0) {
    float raw = v + bias_u[ui[wid]] + bias_b[ii[wid]] + bx[0];
    out[wid] = 4.f / (1.f + __expf(-raw)) + 1.f;
  }
}

extern "C" void kernel_launch(void* const* d_in, const int* in_sizes, int n_in,
                              void* d_out, int out_size, void* d_ws, size_t ws_size,
                              hipStream_t stream)
{
  const int*   ui    = (const int*)  d_in[0];
  const int*   ii    = (const int*)  d_in[1];
  const float* S_u   = (const float*)d_in[2];
  const float* S_b   = (const float*)d_in[3];
  const int*   eu    = (const int*)  d_in[4];
  const int*   eb    = (const int*)  d_in[5];
  const float* gc    = (const float*)d_in[6];
  const float* W1_u  = (const float*)d_in[7];
  const float* a_s_u = (const float*)d_in[8];
  const float* a_n_u = (const float*)d_in[9];
  const float* W1_b  = (const float*)d_in[10];
  const float* a_s_b = (const float*)d_in[11];
  const float* a_n_b = (const float*)d_in[12];
  const float* omega = (const float*)d_in[13];
  const float* W_u2  = (const float*)d_in[14];
  const float* W_us2w= (const float*)d_in[15];
  const float* W_us2b= (const float*)d_in[16];
  const float* W_b2  = (const float*)d_in[17];
  const float* W_bs2w= (const float*)d_in[18];
  const float* W_bs2b= (const float*)d_in[19];
  const float* W_u3  = (const float*)d_in[20];
  const float* W_b3  = (const float*)d_in[21];
  const float* H_u4  = (const float*)d_in[22];
  const float* H_b4  = (const float*)d_in[23];
  const float* bias_u= (const float*)d_in[24];
  const float* bias_b= (const float*)d_in[25];
  const float* b_x   = (const float*)d_in[26];
  float* out = (float*)d_out;

  const int B  = in_sizes[0];
  const int NU = in_sizes[2] / KD;
  const int NI = in_sizes[3] / KD;
  const int EU = in_sizes[4] / 2;
  const int EB = in_sizes[5] / 2;
  const int GPU_ = (EU + 4095) / 4096;
  const int G1U = (NU + 63) / 64, G1I = (NI + 63) / 64;
  const int GO4U = (NU + 1023) / 1024, GO4I = (NI + 1023) / 1024;
  const int GAG = (B + 3) / 4;
  const int GB  = (B + 63) / 64;

  char* w = (char*)d_ws;
  auto alloc = [&](size_t bytes) -> void* {
    void* r = (void*)w;
    w += (bytes + 255) & ~(size_t)255;
    return r;
  };
  // ---- zero-initialized region (one small memset per call) ----
  int* deg_u = (int*)alloc((size_t)NU * 4);
  int* deg_b = (int*)alloc((size_t)NI * 4);
  unsigned char* nfu = (unsigned char*)alloc((size_t)NU);
  unsigned char* nfb = (unsigned char*)alloc((size_t)NI);
  unsigned* mku = (unsigned*)alloc((size_t)((NU + 31) / 32) * 4);
  int* sst_b = (int*)alloc((size_t)NI * 4);
  int* snd_b = (int*)alloc((size_t)NI * 4);
  int* cnt   = (int*)alloc(16 * 4);
  size_t zbytes = (size_t)(w - (char*)d_ws);
  // ---- scratch ----
  unsigned short* wt = (unsigned short*)alloc((size_t)6 * 16384 * 2);
  int*   offs_u = (int*)  alloc((size_t)NU * 4);
  int*   offs_b = (int*)  alloc((size_t)NI * 4);
  int*   g2c_u  = (int*)  alloc((size_t)NU * 4);
  int*   g2c_b  = (int*)  alloc((size_t)NI * 4);
  int*   dl_u   = (int*)  alloc((size_t)B * 4);
  int*   dl_b   = (int*)  alloc((size_t)B * 4);
  int*   bc_u   = (int*)  alloc((size_t)GPU_ * 4);
  int4*  cmp_u  = (int4*) alloc((size_t)GPU_ * 4096 * 16);
  int2*  el_u   = (int2*) alloc((size_t)EU * 8);
  int2*  el_b   = (int2*) alloc((size_t)EB * 8);
  unsigned short* H1u = (unsigned short*)alloc((size_t)NU * KD * 2);
  unsigned short* H1b = (unsigned short*)alloc((size_t)NI * KD * 2);
  float* Hu2c = (float*)alloc((size_t)B * KD * 4);
  float* Hb2c = (float*)alloc((size_t)B * KD * 4);
  float* asu  = (float*)alloc((size_t)NU * 4);
  float* anu  = (float*)alloc((size_t)NU * 4);
  float* asb  = (float*)alloc((size_t)NI * 4);
  float* anb  = (float*)alloc((size_t)NI * 4);
  float* Hu3g = (float*)alloc((size_t)B * KD * 4);
  float* Hb3g = (float*)alloc((size_t)B * KD * 4);
  float* Ug   = (float*)alloc((size_t)B * 64 * 4);
  float* Bg   = (float*)alloc((size_t)B * 64 * 4);
  (void)ws_size; (void)n_in; (void)out_size;

  hipMemsetAsync(d_ws, 0, zbytes, stream);

  wsplit6<<<384, 256, 0, stream>>>(W1_u, W1_b, W_u2, W_us2w, W_b2, W_bs2w, wt);
  flags_kernel<<<(B + 255) / 256, 256, 0, stream>>>(ui, ii, B, nfu, nfb, mku);
  segb_kernel<<<(EB + 255) / 256, 256, 0, stream>>>(eb + EB, EB, sst_b, snd_b);

  // H1 = S @ W1: bf16 MFMA, fused proj + NaN sentinel
  mfma1_dual<<<G1U + G1I, 256, 0, stream>>>(
      G1U,
      S_u, wt + 0 * 16384, NU, H1u, a_s_u, a_n_u, asu, anu, nfu,
      S_b, wt + 1 * 16384, NI, H1b, a_s_b, a_n_b, asb, anb, nfb);

  // user side: score+count (atomic counting-sort)
  edge_prep_u<<<GPU_, 256, 0, stream>>>(
      eu, eu + EU, asu, anu, mku, deg_u, cmp_u, bc_u, EU);

  // both sides: compact dst list + segment offsets (item deg from sorted segs)
  offset_dual<<<GO4U + GO4I, 256, 0, stream>>>(
      GO4U,
      nfu, deg_u, offs_u, dl_u, g2c_u, cnt + 0, NU,
      nfb, deg_b, sst_b, snd_b, offs_b, dl_b, g2c_b, cnt + 2, NI);

  // user side: place packed entries
  place_u<<<GPU_, 256, 0, stream>>>(cmp_u, bc_u, offs_u, el_u);

  // item side: score directly per active dst (contiguous segment reads)
  edge_scoreb<<<GAG, 256, 0, stream>>>(
      eb, asb, anb, gc, omega, dl_b, cnt + 2, offs_b, sst_b, snd_b, el_b);

  aggr_dual<<<GAG * 2, 256, 0, stream>>>(
      GAG,
      dl_u, cnt + 0, offs_u, deg_u, el_u, H1u, Hu2c,
      dl_b, cnt + 2, offs_b, deg_b, el_b, H1b, Hb2c);

  // H3 = elu(Hu2c[g2c[ui]]@W_u2 + S_u[ui]@W_us2w + b): bf16 MFMA, 2 passes
  mfma2_dual<<<GB * 2, 256, 0, stream>>>(
      GB,
      Hu2c, wt + 2 * 16384, S_u, wt + 3 * 16384, W_us2b, ui, g2c_u, B, Hu3g,
      Hb2c, wt + 4 * 16384, S_b, wt + 5 * 16384, W_bs2b, ii, g2c_b, B, Hb3g);

  // U = elu(H3 @ W3) + H4[idx]: fp32, NC=64 (absmax margin)
  gemm3_dual<64,64><<<GB * 2, 256, 0, stream>>>(
      GB,
      Hu3g, W_u3, H_u4, ui, B, Ug,
      Hb3g, W_b3, H_b4, ii, B, Bg);

  final_kernel<<<(B + 3) / 4, 256, 0, stream>>>(Ug, Bg, ui, ii, bias_u, bias_b, b_x, out, B);
}